// Round 8
// baseline (948.405 us; speedup 1.0000x reference)
//
#include <hip/hip_runtime.h>
#include <hip/hip_bf16.h>

typedef __hip_bfloat16 bf16;
typedef __bf16 v8bf __attribute__((ext_vector_type(8)));
typedef float f32x4 __attribute__((ext_vector_type(4)));

#define N_AG 24576
#define N3 8192

struct __align__(8) bf4 { bf16 x, y, z, w; };
__device__ __forceinline__ bf4 mk4(float a, float b, float c, float d) {
  bf4 r{__float2bfloat16(a), __float2bfloat16(b), __float2bfloat16(c), __float2bfloat16(d)};
  return r;
}

// ---------------- epilogue modes ----------------
enum {
  EPI_RELU_BIAS = 0,  // Cout(bf16) = relu(v + bias)
  EPI_BIAS      = 1,  // Cout(bf16) = v + bias
  EPI_ACC_INIT  = 2,  // accbuf(f32) = v + bias
  EPI_ACC_ADD   = 3,  // accbuf(f32) += v + bias
  EPI_FINAL     = 4,  // CoutF(f32) = accbuf + v + bias + resid
  EPI_SILU      = 5,  // Cout(bf16) = silu(v + bias)
  EPI_MUL       = 6,  // Cout(bf16) = (v + bias) * gin[idx]
  EPI_GLU       = 7   // interleaved g/u tiles: Cout(bf16) = silu(g+bg) * (u+bu)
};

// async 16B/lane global->LDS DMA; LDS dest = wave-uniform base + lane*16
__device__ __forceinline__ void gl_lds16(const bf16* g, short* l) {
  __builtin_amdgcn_global_load_lds(
      (const __attribute__((address_space(1))) unsigned int*)g,
      (__attribute__((address_space(3))) unsigned int*)l, 16, 0, 0);
}

// counted-vmcnt leading barrier: wait until only N of this wave's global loads
// remain in flight (tile being computed is landed), then block barrier.
__device__ __forceinline__ void wait_vm_barrier(int pending) {
  if (pending == 8)      asm volatile("s_waitcnt vmcnt(8)\ns_barrier" ::: "memory");
  else if (pending == 4) asm volatile("s_waitcnt vmcnt(4)\ns_barrier" ::: "memory");
  else if (pending == 2) asm volatile("s_waitcnt vmcnt(2)\ns_barrier" ::: "memory");
  else                   asm volatile("s_waitcnt vmcnt(0)\ns_barrier" ::: "memory");
}
// trailing barrier: this wave's ds_reads complete before signaling, so the
// next iteration's DMA may safely overwrite the buffer just read.
__device__ __forceinline__ void lgkm_barrier() {
  asm volatile("s_waitcnt lgkmcnt(0)\ns_barrier" ::: "memory");
}

// ---------------- 128-tile GEMM core (Tier C only; R6 structure) ----------------
template<int EPI, int K, int LDA, int LDB>
__device__ __forceinline__
void gemm_body(const bf16* __restrict__ A,
               const bf16* __restrict__ Bt,
               const float* __restrict__ bias,
               float* __restrict__ accbuf,
               bf16* __restrict__ Cout, int ldc,
               const float* __restrict__ resid,
               float* __restrict__ CoutF,
               int Nc, int row0, int col0)
{
  __shared__ __align__(16) short As[3][128 * 32];
  __shared__ __align__(16) short Bs[3][128 * 32];

  const int tid  = threadIdx.x;
  const int lane = tid & 63;
  const int w    = tid >> 6;
  const int quad = lane >> 4;
  const int l15  = lane & 15;

  f32x4 acc[4][4];
  const f32x4 zero = {0.f, 0.f, 0.f, 0.f};
#pragma unroll
  for (int i = 0; i < 4; ++i)
#pragma unroll
    for (int j = 0; j < 4; ++j) acc[i][j] = zero;

  const int srow = (w << 5) + (lane >> 2);
  const int ss   = ((lane >> 2) & 3) ^ ((lane >> 4) & 1);
  const int sc   = ((lane & 3) ^ ss) << 3;
  const bf16* aG  = A  + (long)(row0 + srow) * LDA + sc;
  const bf16* aG2 = aG + (long)16 * LDA;
  const bf16* bG  = Bt + (long)(col0 + srow) * LDB + sc;
  const bf16* bG2 = bG + (long)16 * LDB;
  const int ldsOff = w * 1024;

  const int wr = (w >> 1) * 64;
  const int wc = (w & 1) * 64;
  const int fs = (l15 & 3) ^ ((l15 >> 2) & 1);

  constexpr int NT = K / 32;

  gl_lds16(aG,       As[0] + ldsOff);
  gl_lds16(aG2,      As[0] + ldsOff + 512);
  gl_lds16(bG,       Bs[0] + ldsOff);
  gl_lds16(bG2,      Bs[0] + ldsOff + 512);
  gl_lds16(aG + 32,  As[1] + ldsOff);
  gl_lds16(aG2 + 32, As[1] + ldsOff + 512);
  gl_lds16(bG + 32,  Bs[1] + ldsOff);
  gl_lds16(bG2 + 32, Bs[1] + ldsOff + 512);

#pragma unroll
  for (int t = 0; t < NT; ++t) {
    const int nk = (t + 2) * 32;
    if (t + 2 < NT) {
      short* An = As[(t + 2) % 3] + ldsOff;
      short* Bn = Bs[(t + 2) % 3] + ldsOff;
      gl_lds16(aG + nk,  An);
      gl_lds16(aG2 + nk, An + 512);
      gl_lds16(bG + nk,  Bn);
      gl_lds16(bG2 + nk, Bn + 512);
    }
    wait_vm_barrier((t + 2 < NT) ? 8 : ((t + 1 < NT) ? 4 : 0));

    const short* Ac = As[t % 3];
    const short* Bc = Bs[t % 3];
    const int pc = (quad ^ fs) * 8;
    v8bf af[4], bfm[4];
#pragma unroll
    for (int i = 0; i < 4; ++i) {
      af[i]  = *(const v8bf*)&Ac[(wr + i * 16 + l15) * 32 + pc];
      bfm[i] = *(const v8bf*)&Bc[(wc + i * 16 + l15) * 32 + pc];
    }
#pragma unroll
    for (int i = 0; i < 4; ++i)
#pragma unroll
      for (int j = 0; j < 4; ++j)
        acc[i][j] = __builtin_amdgcn_mfma_f32_16x16x32_bf16(af[i], bfm[j], acc[i][j], 0, 0, 0);
    lgkm_barrier();
  }

#pragma unroll
  for (int ct = 0; ct < 4; ++ct) {
    const int col = col0 + wc + ct * 16 + l15;
    const float bv = bias ? bias[col] : 0.f;
#pragma unroll
    for (int rt = 0; rt < 4; ++rt) {
#pragma unroll
      for (int i = 0; i < 4; ++i) {
        const int row = row0 + wr + rt * 16 + quad * 4 + i;
        float v = acc[rt][ct][i] + bv;
        if constexpr (EPI == EPI_RELU_BIAS) {
          Cout[(long)row * ldc + col] = __float2bfloat16(v > 0.f ? v : 0.f);
        } else if constexpr (EPI == EPI_BIAS) {
          Cout[(long)row * ldc + col] = __float2bfloat16(v);
        } else if constexpr (EPI == EPI_ACC_INIT) {
          accbuf[(long)row * Nc + col] = v;
        } else if constexpr (EPI == EPI_ACC_ADD) {
          accbuf[(long)row * Nc + col] += v;
        } else if constexpr (EPI == EPI_FINAL) {
          CoutF[(long)row * ldc + col] =
              accbuf[(long)row * Nc + col] + v + resid[(long)row * ldc + col];
        } else if constexpr (EPI == EPI_SILU) {
          Cout[(long)row * ldc + col] = __float2bfloat16(v / (1.f + expf(-v)));
        }
      }
    }
  }
}

// ---------------- 64x64-tile GEMM core: ALL Tier-A GEMMs (R7) ----------------
// 4 waves, each 32x32 (2x2 16x16 frags). 3-buffer counted-vmcnt pipeline,
// LDS 24 KB/block -> ~5-6 blocks/CU resident; latency hidden by cross-block
// TLP + 2-deep prefetch. Proven R6 differential: 64-tile+counted-vmcnt improved
// while 128-tile+3buf regressed (occupancy cliff at 48KB).
template<int EPI, int K, int LDA, int LDB>
__device__ __forceinline__
void gemm64_body(const bf16* __restrict__ A,
                 const bf16* __restrict__ Bt,
                 const float* __restrict__ bias,
                 float* __restrict__ accbuf,
                 bf16* __restrict__ Cout, int ldc,
                 const float* __restrict__ resid,
                 float* __restrict__ CoutF,
                 int Nc, int row0, int col0)
{
  __shared__ __align__(16) short As[3][64 * 32];
  __shared__ __align__(16) short Bs[3][64 * 32];

  const int tid  = threadIdx.x;
  const int lane = tid & 63;
  const int w    = tid >> 6;
  const int quad = lane >> 4;
  const int l15  = lane & 15;

  f32x4 acc[2][2];
  const f32x4 zero = {0.f, 0.f, 0.f, 0.f};
#pragma unroll
  for (int i = 0; i < 2; ++i)
#pragma unroll
    for (int j = 0; j < 2; ++j) acc[i][j] = zero;

  const int srow = (w << 4) + (lane >> 2);
  const int ss   = ((lane >> 2) & 3) ^ ((lane >> 4) & 1);
  const int sc   = ((lane & 3) ^ ss) << 3;
  const bf16* aG = A  + (long)(row0 + srow) * LDA + sc;
  const bf16* bG = Bt + (long)(col0 + srow) * LDB + sc;
  const int ldsOff = w * 512;

  const int wr = (w >> 1) * 32;
  const int wc = (w & 1) * 32;
  const int fs = (l15 & 3) ^ ((l15 >> 2) & 1);

  constexpr int NT = K / 32;

  gl_lds16(aG,      As[0] + ldsOff);
  gl_lds16(bG,      Bs[0] + ldsOff);
  gl_lds16(aG + 32, As[1] + ldsOff);
  gl_lds16(bG + 32, Bs[1] + ldsOff);

#pragma unroll
  for (int t = 0; t < NT; ++t) {
    const int nk = (t + 2) * 32;
    if (t + 2 < NT) {
      gl_lds16(aG + nk, As[(t + 2) % 3] + ldsOff);
      gl_lds16(bG + nk, Bs[(t + 2) % 3] + ldsOff);
    }
    wait_vm_barrier((t + 2 < NT) ? 4 : ((t + 1 < NT) ? 2 : 0));

    const short* Ac = As[t % 3];
    const short* Bc = Bs[t % 3];
    const int pc = (quad ^ fs) * 8;
    v8bf af[2], bfm[2];
#pragma unroll
    for (int i = 0; i < 2; ++i) {
      af[i]  = *(const v8bf*)&Ac[(wr + i * 16 + l15) * 32 + pc];
      bfm[i] = *(const v8bf*)&Bc[(wc + i * 16 + l15) * 32 + pc];
    }
#pragma unroll
    for (int i = 0; i < 2; ++i)
#pragma unroll
      for (int j = 0; j < 2; ++j)
        acc[i][j] = __builtin_amdgcn_mfma_f32_16x16x32_bf16(af[i], bfm[j], acc[i][j], 0, 0, 0);
    lgkm_barrier();
  }

  if constexpr (EPI == EPI_GLU) {
    // interleaved: 32-col groups [16 g | 16 u]; ct=0 tile = g-cols, ct=1 = u.
    const int colg = col0 + wc + l15;
    const int hcol = ((colg >> 5) << 4) + (colg & 15);
    const float bg = bias[colg];
    const float bu = bias[colg + 16];
#pragma unroll
    for (int rt = 0; rt < 2; ++rt) {
#pragma unroll
      for (int i = 0; i < 4; ++i) {
        const int row = row0 + wr + rt * 16 + quad * 4 + i;
        const float vg = acc[rt][0][i] + bg;
        const float vu = acc[rt][1][i] + bu;
        Cout[(long)row * ldc + hcol] =
            __float2bfloat16(vg / (1.f + expf(-vg)) * vu);
      }
    }
  } else {
#pragma unroll
    for (int ct = 0; ct < 2; ++ct) {
      const int col = col0 + wc + ct * 16 + l15;
      const float bv = bias ? bias[col] : 0.f;
#pragma unroll
      for (int rt = 0; rt < 2; ++rt) {
#pragma unroll
        for (int i = 0; i < 4; ++i) {
          const int row = row0 + wr + rt * 16 + quad * 4 + i;
          float v = acc[rt][ct][i] + bv;
          if constexpr (EPI == EPI_RELU_BIAS) {
            Cout[(long)row * ldc + col] = __float2bfloat16(v > 0.f ? v : 0.f);
          } else if constexpr (EPI == EPI_BIAS) {
            Cout[(long)row * ldc + col] = __float2bfloat16(v);
          } else if constexpr (EPI == EPI_ACC_INIT) {
            accbuf[(long)row * Nc + col] = v;
          } else if constexpr (EPI == EPI_ACC_ADD) {
            accbuf[(long)row * Nc + col] += v;
          } else if constexpr (EPI == EPI_FINAL) {
            CoutF[(long)row * ldc + col] =
                accbuf[(long)row * Nc + col] + v + resid[(long)row * ldc + col];
          }
        }
      }
    }
  }
}

// 128-tile wrapper (Tier C)
template<int EPI, int K, int LDA, int LDB>
__global__ __launch_bounds__(256)
void gemm_k(const bf16* __restrict__ A,
            const bf16* __restrict__ Bt, long bTs,
            const float* __restrict__ bias, long biasTs,
            float* __restrict__ accbuf,
            bf16* __restrict__ Cout, int ldc,
            const float* __restrict__ resid,
            float* __restrict__ CoutF,
            int Nc)
{
  const int row0 = blockIdx.x * 128;
  const int col0 = blockIdx.y * 128;
  const int t    = row0 >> 13;
  gemm_body<EPI, K, LDA, LDB>(A, Bt + (long)t * bTs,
                              bias ? bias + (long)t * biasTs : nullptr,
                              accbuf, Cout, ldc, resid, CoutF, Nc, row0, col0);
}

// 64-tile wrapper: grid (M/64, Nc/64)
template<int EPI, int K, int LDA, int LDB>
__global__ __launch_bounds__(256)
void gemm64_k(const bf16* __restrict__ A,
              const bf16* __restrict__ Bt, long bTs,
              const float* __restrict__ bias, long biasTs,
              float* __restrict__ accbuf,
              bf16* __restrict__ Cout, int ldc,
              const float* __restrict__ resid,
              float* __restrict__ CoutF,
              int Nc)
{
  const int row0 = blockIdx.x * 64;
  const int col0 = blockIdx.y * 64;
  const int t    = row0 >> 13;
  gemm64_body<EPI, K, LDA, LDB>(A, Bt + (long)t * bTs,
                                bias ? bias + (long)t * biasTs : nullptr,
                                accbuf, Cout, ldc, resid, CoutF, Nc, row0, col0);
}

// z-batched merged-W2 precompute (64-tile): W2'^T[b][t] = outW_slice(j(b))^T @ w2_b^T
__global__ __launch_bounds__(256)
void w2m_k(const bf16* __restrict__ outwT, const bf16* __restrict__ w2c,
           bf16* __restrict__ w2m)
{
  const int z = blockIdx.z, b = z / 3, t = z % 3;
  const int j = (b == 0) ? 1 : (b == 1) ? 2 : 3;
  gemm64_body<EPI_BIAS, 256, 1024, 256>(
      outwT + (long)t * 262144 + j * 256,
      w2c + (long)b * 262144,
      nullptr, nullptr, w2m + (long)z * 262144, 1024,
      nullptr, nullptr, 1024,
      blockIdx.x * 64, blockIdx.y * 64);
}

// ---------------- weight transpose+cast: src f32 [K,Nc] -> dst bf16 [Nc,K], batched z ----------------
__global__ __launch_bounds__(256)
void transpose_k(const float* __restrict__ src, bf16* __restrict__ dst,
                 int K, int Nc, long sB, long dB)
{
  __shared__ bf16 tile[32][33];
  const int b = blockIdx.z;
  const float* s = src + (long)b * sB;
  bf16* d = dst + (long)b * dB;
  const int kb = blockIdx.y * 32, nb = blockIdx.x * 32;
  const int tx = threadIdx.x & 31, ty = threadIdx.x >> 5;
#pragma unroll
  for (int i = 0; i < 32; i += 8)
    tile[ty + i][tx] = __float2bfloat16(s[(long)(kb + ty + i) * Nc + nb + tx]);
  __syncthreads();
#pragma unroll
  for (int i = 0; i < 32; i += 8)
    d[(long)(nb + ty + i) * K + kb + tx] = tile[tx][ty + i];
}

// ---------------- interleaved FFN w1/w3 transpose: dst bf16 [3][2048,256] ----------------
__global__ __launch_bounds__(256)
void transpose13_k(const float* __restrict__ w1, const float* __restrict__ w3,
                   bf16* __restrict__ dst)
{
  __shared__ bf16 tile[32][33];
  const int t  = blockIdx.z;
  const int n0 = blockIdx.x * 32;
  const int k0 = blockIdx.y * 32;
  const int gi = n0 >> 5;
  const int tx = threadIdx.x & 31, ty = threadIdx.x >> 5;
  const float* src = ((tx & 16) ? w3 : w1) + (long)t * 262144;
  const int c = 16 * gi + (tx & 15);
#pragma unroll
  for (int i = 0; i < 32; i += 8)
    tile[ty + i][tx] = __float2bfloat16(src[(long)(k0 + ty + i) * 1024 + c]);
  __syncthreads();
#pragma unroll
  for (int i = 0; i < 32; i += 8)
    dst[((long)t * 2048 + n0 + ty + i) * 256 + k0 + tx] = tile[tx][ty + i];
}

// ---------------- LN-folded w1: dst[b] (bf16 [1024,512]) from w1 f32 [Kin,1024] ----------------
struct FoldP { const float* w1[5]; const float* ls[5]; };
__global__ __launch_bounds__(256)
void fold_w1_k(FoldP p, bf16* __restrict__ dst)
{
  __shared__ float tile[32][33];
  const int z = blockIdx.z;
  const float* w1 = p.w1[z];
  const float* ls = p.ls[z];
  bf16* d = dst + (long)z * 524288;
  const int n0 = blockIdx.x * 32, i0 = blockIdx.y * 32;
  const int tx = threadIdx.x & 31, ty = threadIdx.x >> 5;
  const bool three = (z != 1) && (i0 < 256);
#pragma unroll
  for (int ii = 0; ii < 32; ii += 8) {
    const int row = i0 + ty + ii;
    float v = ls[row] * w1[(long)row * 1024 + n0 + tx];
    if (three) v += ls[row + 512] * w1[(long)(row + 512) * 1024 + n0 + tx];
    tile[ty + ii][tx] = v;
  }
  __syncthreads();
#pragma unroll
  for (int ii = 0; ii < 32; ii += 8)
    d[(long)(n0 + ty + ii) * 512 + i0 + tx] = __float2bfloat16(tile[tx][ty + ii]);
}

// ---------------- bias-fold precompute (parallelized) ----------------
struct BInitP { const float* b1[5]; const float* fb1; const float* fb3; };
__global__ __launch_bounds__(256)
void binit_k(BInitP p, float* __restrict__ B1F,
             const float* __restrict__ out_b, float* __restrict__ TB,
             float* __restrict__ B13)
{
  const int i = blockIdx.x * 256 + threadIdx.x;
  if (i < 5120) {
    B1F[i] = p.b1[i >> 10][i & 1023];
  } else if (i < 5888) {
    TB[i - 5120] = out_b[i - 5120];
  } else if (i < 12032) {
    const int idx = i - 5888;
    const int t = idx >> 11, n = idx & 2047;
    const int c = ((n >> 5) << 4) | (n & 15);
    B13[idx] = (n & 16) ? p.fb3[t * 1024 + c] : p.fb1[t * 1024 + c];
  }
}

// B1F[z][n] += sum_k lb[k]*w1[k,n]; grid (z=5, ksplit=32)
struct B1P { const float* w1[5]; const float* lb[5]; int kin[5]; };
__global__ __launch_bounds__(256)
void b1f_add_k(B1P p, float* __restrict__ dst)
{
  const int z   = blockIdx.x;
  const int kin = p.kin[z];
  const int kpb = (kin + 31) >> 5;
  const int k0  = blockIdx.y * kpb;
  const int k1  = min(k0 + kpb, kin);
  const float* w1 = p.w1[z];
  const float* lb = p.lb[z];
  const int n = threadIdx.x;
  float a0 = 0.f, a1 = 0.f, a2 = 0.f, a3 = 0.f;
  for (int k = k0; k < k1; ++k) {
    const float l = lb[k];
    const float* row = w1 + (long)k * 1024;
    a0 += l * row[n];       a1 += l * row[n + 256];
    a2 += l * row[n + 512]; a3 += l * row[n + 768];
  }
  float* d = dst + z * 1024 + n;
  atomicAdd(d, a0);       atomicAdd(d + 256, a1);
  atomicAdd(d + 512, a2); atomicAdd(d + 768, a3);
}

// TB[t][h] += b2-vectors through outW slices; grid (t=3, csplit=8)
__global__ __launch_bounds__(256)
void tbias_add_k(const float* __restrict__ outW,
                 const float* __restrict__ l2a_b2, const float* __restrict__ g2a_b2,
                 const float* __restrict__ oth_b2, float* __restrict__ dst)
{
  const int t = blockIdx.x, h = threadIdx.x;
  const float* W = outW + (long)t * 262144;
  const int c0 = blockIdx.y * 32;
  float acc = 0.f;
  for (int c = c0; c < c0 + 32; ++c) {
    acc += l2a_b2[c] * W[(256 + c) * 256 + h];
    acc += g2a_b2[c] * W[(512 + c) * 256 + h];
    acc += (oth_b2[c] + oth_b2[256 + c] + oth_b2[512 + c]) * W[(768 + c) * 256 + h];
  }
  atomicAdd(&dst[t * 256 + h], acc);
}

// ---------------- f32 -> bf16 cast, 4 elems/thread ----------------
__global__ __launch_bounds__(256)
void cast_k(const float* __restrict__ src, bf16* __restrict__ dst)
{
  const long i = (long)blockIdx.x * 256 + threadIdx.x;
  const float4 v = ((const float4*)src)[i];
  ((bf4*)dst)[i] = mk4(v.x, v.y, v.z, v.w);
}

// ---------------- wave-wide reduce (all lanes get totals) ----------------
__device__ __forceinline__ void wave_reduce2(float& s, float& q) {
#pragma unroll
  for (int off = 32; off > 0; off >>= 1) {
    s += __shfl_xor(s, off, 64);
    q += __shfl_xor(q, off, 64);
  }
}

// ---------------- normalized-only LN: writes [fn, xn] (512 bf16) ----------------
template<int THREE>
__global__ __launch_bounds__(256)
void ln_norm_k(const float* __restrict__ feat, const float* __restrict__ x,
               const int* __restrict__ srcIdx, bf16* __restrict__ out)
{
  const int w = threadIdx.x >> 6, lane = threadIdx.x & 63;
  const int r = blockIdx.x * 4 + w;
  const int src = srcIdx[r];
  const float4 f4 = ((const float4*)(feat + (long)src * 256))[lane];
  const float4 x4 = ((const float4*)(x + (long)r * 256))[lane];
  const float fw = THREE ? 2.f : 1.f;
  float s = fw * (f4.x + f4.y + f4.z + f4.w) + (x4.x + x4.y + x4.z + x4.w);
  float q = fw * (f4.x * f4.x + f4.y * f4.y + f4.z * f4.z + f4.w * f4.w) +
            (x4.x * x4.x + x4.y * x4.y + x4.z * x4.z + x4.w * x4.w);
  wave_reduce2(s, q);
  const float rD  = THREE ? (1.f / 768.f) : (1.f / 512.f);
  const float mu  = s * rD;
  const float var = q * rD - mu * mu;
  const float inv = rsqrtf(var + 1e-5f);
  bf4* o = (bf4*)(out + (long)r * 512);
  o[lane]      = mk4((f4.x - mu) * inv, (f4.y - mu) * inv,
                     (f4.z - mu) * inv, (f4.w - mu) * inv);
  o[64 + lane] = mk4((x4.x - mu) * inv, (x4.y - mu) * inv,
                     (x4.z - mu) * inv, (x4.w - mu) * inv);
}

// ---------------- legacy LN kernels (Tier C path) ----------------
__global__ __launch_bounds__(256)
void ln_cat3_k(const float* __restrict__ feat, const float* __restrict__ x,
               const int* __restrict__ srcIdx,
               const float* __restrict__ ls, const float* __restrict__ lb,
               bf16* __restrict__ out)
{
  const int w = threadIdx.x >> 6, lane = threadIdx.x & 63;
  const int r = blockIdx.x * 4 + w;
  const int src = srcIdx[r];
  const float4 f4 = ((const float4*)(feat + (long)src * 256))[lane];
  const float4 x4 = ((const float4*)(x + (long)r * 256))[lane];
  float s = 2.f * (f4.x + f4.y + f4.z + f4.w) + (x4.x + x4.y + x4.z + x4.w);
  float q = 2.f * (f4.x * f4.x + f4.y * f4.y + f4.z * f4.z + f4.w * f4.w) +
            (x4.x * x4.x + x4.y * x4.y + x4.z * x4.z + x4.w * x4.w);
  wave_reduce2(s, q);
  const float mu  = s * (1.f / 768.f);
  const float var = q * (1.f / 768.f) - mu * mu;
  const float inv = rsqrtf(var + 1e-5f);
  const float4 s0 = ((const float4*)ls)[lane],         b0 = ((const float4*)lb)[lane];
  const float4 s1 = ((const float4*)(ls + 256))[lane], b1 = ((const float4*)(lb + 256))[lane];
  const float4 s2 = ((const float4*)(ls + 512))[lane], b2 = ((const float4*)(lb + 512))[lane];
  bf4* o = (bf4*)(out + (long)r * 768);
  o[lane] = mk4((f4.x - mu) * inv * s0.x + b0.x, (f4.y - mu) * inv * s0.y + b0.y,
                (f4.z - mu) * inv * s0.z + b0.z, (f4.w - mu) * inv * s0.w + b0.w);
  o[64 + lane] = mk4((x4.x - mu) * inv * s1.x + b1.x, (x4.y - mu) * inv * s1.y + b1.y,
                     (x4.z - mu) * inv * s1.z + b1.z, (x4.w - mu) * inv * s1.w + b1.w);
  o[128 + lane] = mk4((f4.x - mu) * inv * s2.x + b2.x, (f4.y - mu) * inv * s2.y + b2.y,
                      (f4.z - mu) * inv * s2.z + b2.z, (f4.w - mu) * inv * s2.w + b2.w);
}

__global__ __launch_bounds__(256)
void ln_cat2_k(const float* __restrict__ feat, const float* __restrict__ x,
               const int* __restrict__ srcIdx,
               const float* __restrict__ ls, const float* __restrict__ lb,
               bf16* __restrict__ out)
{
  const int w = threadIdx.x >> 6, lane = threadIdx.x & 63;
  const int r = blockIdx.x * 4 + w;
  const int src = srcIdx[r];
  const float4 f4 = ((const float4*)(feat + (long)src * 256))[lane];
  const float4 x4 = ((const float4*)(x + (long)r * 256))[lane];
  float s = (f4.x + f4.y + f4.z + f4.w) + (x4.x + x4.y + x4.z + x4.w);
  float q = (f4.x * f4.x + f4.y * f4.y + f4.z * f4.z + f4.w * f4.w) +
            (x4.x * x4.x + x4.y * x4.y + x4.z * x4.z + x4.w * x4.w);
  wave_reduce2(s, q);
  const float mu  = s * (1.f / 512.f);
  const float var = q * (1.f / 512.f) - mu * mu;
  const float inv = rsqrtf(var + 1e-5f);
  const float4 s0 = ((const float4*)ls)[lane],         b0 = ((const float4*)lb)[lane];
  const float4 s1 = ((const float4*)(ls + 256))[lane], b1 = ((const float4*)(lb + 256))[lane];
  bf4* o = (bf4*)(out + (long)r * 512);
  o[lane] = mk4((f4.x - mu) * inv * s0.x + b0.x, (f4.y - mu) * inv * s0.y + b0.y,
                (f4.z - mu) * inv * s0.z + b0.z, (f4.w - mu) * inv * s0.w + b0.w);
  o[64 + lane] = mk4((x4.x - mu) * inv * s1.x + b1.x, (x4.y - mu) * inv * s1.y + b1.y,
                     (x4.z - mu) * inv * s1.z + b1.z, (x4.w - mu) * inv * s1.w + b1.w);
}

// ---------------- FFN layernorm width 256: f32 in, bf16 out; one wave per row ----------------
__global__ __launch_bounds__(256)
void ln_ffn_k(const float* __restrict__ ob, const float* __restrict__ ls,
              const float* __restrict__ lb, bf16* __restrict__ y, long lsStride)
{
  const int w = threadIdx.x >> 6, lane = threadIdx.x & 63;
  const int r = blockIdx.x * 4 + w;
  const long po = (long)(r >> 13) * lsStride;
  const float4 v4 = ((const float4*)(ob + (long)r * 256))[lane];
  float s = v4.x + v4.y + v4.z + v4.w;
  float q = v4.x * v4.x + v4.y * v4.y + v4.z * v4.z + v4.w * v4.w;
  wave_reduce2(s, q);
  const float mu  = s * (1.f / 256.f);
  const float var = q * (1.f / 256.f) - mu * mu;
  const float inv = rsqrtf(var + 1e-5f);
  const float4 s0 = ((const float4*)(ls + po))[lane];
  const float4 b0 = ((const float4*)(lb + po))[lane];
  ((bf4*)(y + (long)r * 256))[lane] =
      mk4((v4.x - mu) * inv * s0.x + b0.x, (v4.y - mu) * inv * s0.y + b0.y,
          (v4.z - mu) * inv * s0.z + b0.z, (v4.w - mu) * inv * s0.w + b0.w);
}

// ---------------- g = silu(g) * u, 4 elems/thread (Tier C path) ----------------
__global__ __launch_bounds__(256)
void silu_mul_k(bf16* __restrict__ g, const bf16* __restrict__ u)
{
  const long i = (long)blockIdx.x * 256 + threadIdx.x;
  const bf4 g4 = ((const bf4*)g)[i];
  const bf4 u4 = ((const bf4*)u)[i];
  float a = __bfloat162float(g4.x), b = __bfloat162float(g4.y);
  float c = __bfloat162float(g4.z), d = __bfloat162float(g4.w);
  a = a / (1.f + expf(-a)) * __bfloat162float(u4.x);
  b = b / (1.f + expf(-b)) * __bfloat162float(u4.y);
  c = c / (1.f + expf(-c)) * __bfloat162float(u4.z);
  d = d / (1.f + expf(-d)) * __bfloat162float(u4.w);
  ((bf4*)g)[i] = mk4(a, b, c, d);
}

// ---------------- sentinel fill (diagnostic) ----------------
__global__ __launch_bounds__(256)
void fill_k(float* __restrict__ p, int n)
{
  const int i = blockIdx.x * 256 + threadIdx.x;
  if (i < n) p[i] = 2.0f;
}

// ---------------- host ----------------
extern "C" void kernel_launch(void* const* d_in, const int* in_sizes, int n_in,
                              void* d_out, int out_size, void* d_ws, size_t ws_size,
                              hipStream_t stream)
{
  const float* agent_x  = (const float*)d_in[0];
  const float* lane_x   = (const float*)d_in[1];
  const float* poly_x   = (const float*)d_in[2];
  const int*   l2a_src  = (const int*)d_in[3];
  const int*   g2a_src  = (const int*)d_in[4];
  const int*   other_src= (const int*)d_in[5];
  const float* self_W   = (const float*)d_in[6];
  const float* self_b   = (const float*)d_in[7];
  const float* out_W    = (const float*)d_in[8];
  const float* out_b    = (const float*)d_in[9];
  const float* ffn_ln_s = (const float*)d_in[10];
  const float* ffn_ln_b = (const float*)d_in[11];
  const float* ffn_w1   = (const float*)d_in[12];
  const float* ffn_b1   = (const float*)d_in[13];
  const float* ffn_w2   = (const float*)d_in[14];
  const float* ffn_b2   = (const float*)d_in[15];
  const float* ffn_w3   = (const float*)d_in[16];
  const float* ffn_b3   = (const float*)d_in[17];
  const float* l2a_ln_s = (const float*)d_in[18];
  const float* l2a_ln_b = (const float*)d_in[19];
  const float* l2a_w1   = (const float*)d_in[20];
  const float* l2a_b1   = (const float*)d_in[21];
  const float* l2a_w2   = (const float*)d_in[22];
  const float* l2a_b2   = (const float*)d_in[23];
  const float* g2a_ln_s = (const float*)d_in[24];
  const float* g2a_ln_b = (const float*)d_in[25];
  const float* g2a_w1   = (const float*)d_in[26];
  const float* g2a_b1   = (const float*)d_in[27];
  const float* g2a_w2   = (const float*)d_in[28];
  const float* g2a_b2   = (const float*)d_in[29];
  const float* oth_ln_s = (const float*)d_in[30];
  const float* oth_ln_b = (const float*)d_in[31];
  const float* oth_w1   = (const float*)d_in[32];
  const float* oth_b1   = (const float*)d_in[33];
  const float* oth_w2   = (const float*)d_in[34];
  const float* oth_b2   = (const float*)d_in[35];

  float* outp = (float*)d_out;
  const dim3 B256(256);

  const size_t TIER_A = 135707648;  // full-N layout (fits inside proven 155 MB grant)
  const size_t TIER_C = 12058624;   // chunked fallback

  if (ws_size >= TIER_A) {
    // ============ Tier A: full-N, LN-folded K=512, merged w2@outW, fused GLU, all-64-tile GEMMs ============
    char* base = (char*)d_ws;
    bf16* wT = (bf16*)base;
    const long SELF_WT = 0,       OUT_WT  = 196608,  FFN_W13T = 983040;  // [3][2048,256]
    const long FFN_W2T = 2555904;
    const long W2C = 3342336,     W1F     = 4653056, W2M      = 7274496;
    float* B1F  = (float*)(base + 22413312L);   // [5][1024] folded w1 bias
    float* TB   = (float*)(base + 22433792L);   // [3][256]  fused out-bias
    float* B13  = (float*)(base + 22436864L);   // [3][2048] interleaved ffn bias
    bf16*  nbuf = (bf16*)(base + 22461440L);    // [N,512]  LN output
    bf16*  h1   = (bf16*)(base + 47627264L);    // [N,1024] w1 out / FFN g*u
    float* oF   = (float*)(base + 97958912L);   // [N,256]  branch accumulator
    bf16*  ybuf = (bf16*)(base + 123124736L);   // [N,256]  self_out / FFN y
    bf16*  xbf  = h1;  // bf16 cast of agent_x (dead before h1 written)

    // ---- weight precompute ----
    auto TRB = [&](const float* s, long dOff, int K, int Nc, long sB, long dB, int b) {
      transpose_k<<<dim3(Nc / 32, K / 32, b), B256, 0, stream>>>(s, wT + dOff, K, Nc, sB, dB);
    };
    TRB(self_W, SELF_WT, 256, 256,  65536, 65536, 3);
    TRB(out_W,  OUT_WT,  1024, 256, 262144, 262144, 3);
    TRB(ffn_w2, FFN_W2T, 1024, 256, 262144, 262144, 3);
    transpose13_k<<<dim3(64, 8, 3), B256, 0, stream>>>(ffn_w1, ffn_w3, wT + FFN_W13T);
    cast_k<<<256, B256, 0, stream>>>(l2a_w2, wT + W2C);
    cast_k<<<256, B256, 0, stream>>>(g2a_w2, wT + W2C + 262144);
    cast_k<<<768, B256, 0, stream>>>(oth_w2, wT + W2C + 524288);

    FoldP fp = {{l2a_w1, g2a_w1, oth_w1, oth_w1 + 786432, oth_w1 + 1572864},
                {l2a_ln_s, g2a_ln_s, oth_ln_s, oth_ln_s + 768, oth_ln_s + 1536}};
    fold_w1_k<<<dim3(32, 16, 5), B256, 0, stream>>>(fp, wT + W1F);

    BInitP ip = {{l2a_b1, g2a_b1, oth_b1, oth_b1 + 1024, oth_b1 + 2048}, ffn_b1, ffn_b3};
    binit_k<<<47, B256, 0, stream>>>(ip, B1F, out_b, TB, B13);
    B1P bp = {{l2a_w1, g2a_w1, oth_w1, oth_w1 + 786432, oth_w1 + 1572864},
              {l2a_ln_b, g2a_ln_b, oth_ln_b, oth_ln_b + 768, oth_ln_b + 1536},
              {768, 512, 768, 768, 768}};
    b1f_add_k<<<dim3(5, 32), B256, 0, stream>>>(bp, B1F);
    tbias_add_k<<<dim3(3, 8), B256, 0, stream>>>(out_W, l2a_b2, g2a_b2, oth_b2, TB);
    w2m_k<<<dim3(4, 16, 15), B256, 0, stream>>>(wT + OUT_WT, wT + W2C, wT + W2M);

    const dim3 G64n2(N_AG / 64, 4);    // N=256 GEMMs:  1536 blocks
    const dim3 G64w1(N_AG / 64, 16);   // N=1024 GEMMs: 6144 blocks
    const dim3 G64gl(N_AG / 64, 32);   // N=2048 GLU:  12288 blocks

    // ---- self branch (ACC_INIT carries all fused biases) ----
    cast_k<<<N_AG / 4, B256, 0, stream>>>(agent_x, xbf);
    gemm64_k<EPI_RELU_BIAS, 256, 256, 256><<<G64n2, B256, 0, stream>>>(
        xbf, wT + SELF_WT, 65536, self_b, 256,
        nullptr, ybuf, 256, nullptr, nullptr, 256);
    gemm64_k<EPI_ACC_INIT, 256, 256, 1024><<<G64n2, B256, 0, stream>>>(
        ybuf, wT + OUT_WT, 262144, TB, 256,
        oF, nullptr, 0, nullptr, nullptr, 256);

    // ---- edge branches: LN(normalize only) -> w1' (K=512, 64-tile) -> merged-w2' ACC ----
    for (int b = 0; b < 5; ++b) {
      const int* src = (b == 0) ? l2a_src : (b == 1) ? g2a_src
                                          : other_src + (long)(b - 2) * N_AG;
      const float* feat = (b == 0) ? lane_x : (b == 1) ? poly_x : agent_x;
      if (b == 1) ln_norm_k<0><<<N_AG / 4, B256, 0, stream>>>(feat, agent_x, src, nbuf);
      else        ln_norm_k<1><<<N_AG / 4, B256, 0, stream>>>(feat, agent_x, src, nbuf);
      gemm64_k<EPI_RELU_BIAS, 512, 512, 512><<<G64w1, B256, 0, stream>>>(
          nbuf, wT + W1F + (long)b * 524288, 0, B1F + b * 1024, 0,
          nullptr, h1, 1024, nullptr, nullptr, 1024);
      gemm64_k<EPI_ACC_ADD, 1024, 1024, 1024><<<G64n2, B256, 0, stream>>>(
          h1, wT + W2M + (long)b * 786432, 262144, nullptr, 0,
          oF, nullptr, 0, nullptr, nullptr, 256);
    }

    // ---- FFN: interleaved GLU GEMM (64-tile), then w2 with fused FINAL epilogue ----
    ln_ffn_k<<<N_AG / 4, B256, 0, stream>>>(oF, ffn_ln_s, ffn_ln_b, ybuf, 256);
    gemm64_k<EPI_GLU, 256, 256, 256><<<G64gl, B256, 0, stream>>>(
        ybuf, wT + FFN_W13T, 524288, B13, 2048,
        nullptr, h1, 1024, nullptr, nullptr, 2048);
    gemm64_k<EPI_FINAL, 1024, 1024, 1024><<<G64n2, B256, 0, stream>>>(
        h1, wT + FFN_W2T, 262144, ffn_b2, 256,
        oF, nullptr, 256, agent_x, outp, 256);
    return;
  }

  if (ws_size < TIER_C) {
    fill_k<<<(out_size + 255) / 256, B256, 0, stream>>>(outp, out_size);
    return;
  }

  // ================= Tier C: chunked path (11.5 MiB) =================
  const int CH = 2048;
  char* base = (char*)d_ws;
  bf16*  wt     = (bf16*)base;
  bf16*  nbuf   = (bf16*)(base + 1572864L);
  bf16*  bbuf   = (bf16*)(base + 4718592L);
  bf16*  h1     = (bf16*)(base + 5767168L);
  float* outF32 = (float*)(base + 9961472L);
  bf16*  ybuf   = (bf16*)(base + 524288L);
  bf16*  xbf    = h1;
  bf16*  g_pre  = h1;
  bf16*  u_pre  = nbuf;

  const dim3 Gw1(CH / 128, 8), Gw2(CH / 128, 2);
  auto TR = [&](const float* s, int K, int Nc) {
    transpose_k<<<dim3(Nc / 32, K / 32), B256, 0, stream>>>(s, wt, K, Nc, 0, 0);
  };

  for (int t = 0; t < 3; ++t) {
    for (int c = 0; c < N3 / CH; ++c) {
      const long r0 = (long)t * N3 + (long)c * CH;
      const float* xC   = agent_x + r0 * 256;
      float*       outC = outp + r0 * 256;

      cast_k<<<CH / 4, B256, 0, stream>>>(xC, xbf);
      TR(self_W + (long)t * 65536, 256, 256);
      gemm_k<EPI_RELU_BIAS, 256, 256, 256><<<Gw2, B256, 0, stream>>>(
          xbf, wt, 0, self_b + t * 256, 0, nullptr, bbuf, 256,
          nullptr, nullptr, 256);
      TR(out_W + (long)t * 262144 + 0 * 65536, 256, 256);
      gemm_k<EPI_ACC_INIT, 256, 256, 256><<<Gw2, B256, 0, stream>>>(
          bbuf, wt, 0, out_b + t * 256, 0, outF32, nullptr, 0,
          nullptr, nullptr, 256);

      ln_cat3_k<<<CH / 4, B256, 0, stream>>>(lane_x, xC, l2a_src + r0,
                                             l2a_ln_s, l2a_ln_b, nbuf);
      TR(l2a_w1, 768, 1024);
      gemm_k<EPI_RELU_BIAS, 768, 768, 768><<<Gw1, B256, 0, stream>>>(
          nbuf, wt, 0, l2a_b1, 0, nullptr, h1, 1024,
          nullptr, nullptr, 1024);
      TR(l2a_w2, 1024, 256);
      gemm_k<EPI_BIAS, 1024, 1024, 1024><<<Gw2, B256, 0, stream>>>(
          h1, wt, 0, l2a_b2, 0, nullptr, bbuf, 256,
          nullptr, nullptr, 256);
      TR(out_W + (long)t * 262144 + 1 * 65536, 256, 256);
      gemm_k<EPI_ACC_ADD, 256, 256, 256><<<Gw2, B256, 0, stream>>>(
          bbuf, wt, 0, nullptr, 0, outF32, nullptr, 0,
          nullptr, nullptr, 256);

      ln_cat2_k<<<CH / 4, B256, 0, stream>>>(poly_x, xC, g2a_src + r0,
                                             g2a_ln_s, g2a_ln_b, nbuf);
      TR(g2a_w1, 512, 1024);
      gemm_k<EPI_RELU_BIAS, 512, 512, 512><<<Gw1, B256, 0, stream>>>(
          nbuf, wt, 0, g2a_b1, 0, nullptr, h1, 1024,
          nullptr, nullptr, 1024);
      TR(g2a_w2, 1024, 256);
      gemm_k<EPI_BIAS, 1024, 1024, 1024><<<Gw2, B256, 0, stream>>>(
          h1, wt, 0, g2a_b2, 0, nullptr, bbuf, 256,
          nullptr, nullptr, 256);
      TR(out_W + (long)t * 262144 + 2 * 65536, 256, 256);
      gemm_k<EPI_ACC_ADD, 256, 256, 256><<<Gw2, B256, 0, stream>>>(
          bbuf, wt, 0, nullptr, 0, outF32, nullptr, 0,
          nullptr, nullptr, 256);

      for (int s = 0; s < 3; ++s) {
        ln_cat3_k<<<CH / 4, B256, 0, stream>>>(
            agent_x, xC, other_src + (long)s * N_AG + r0,
            oth_ln_s + s * 768, oth_ln_b + s * 768, nbuf);
        TR(oth_w1 + (long)s * 786432, 768, 1024);
        gemm_k<EPI_RELU_BIAS, 768, 768, 768><<<Gw1, B256, 0, stream>>>(
            nbuf, wt, 0, oth_b1 + s * 1024, 0, nullptr, h1, 1024,
            nullptr, nullptr, 1024);
        TR(oth_w2 + (long)s * 262144, 1024, 256);
        gemm_k<EPI_BIAS, 1024, 1024, 1024><<<Gw2, B256, 0, stream>>>(
            h1, wt, 0, oth_b2 + s * 256, 0, nullptr, bbuf, 256,
            nullptr, nullptr, 256);
        TR(out_W + (long)t * 262144 + 3 * 65536, 256, 256);
        gemm_k<EPI_ACC_ADD, 256, 256, 256><<<Gw2, B256, 0, stream>>>(
            bbuf, wt, 0, nullptr, 0, outF32, nullptr, 0,
            nullptr, nullptr, 256);
      }

      ln_ffn_k<<<CH / 4, B256, 0, stream>>>(outF32, ffn_ln_s + t * 256,
                                            ffn_ln_b + t * 256, ybuf, 0);
      TR(ffn_w1 + (long)t * 262144, 256, 1024);
      gemm_k<EPI_BIAS, 256, 256, 256><<<Gw1, B256, 0, stream>>>(
          ybuf, wt, 0, ffn_b1 + t * 1024, 0, nullptr, g_pre, 1024,
          nullptr, nullptr, 1024);
      TR(ffn_w3 + (long)t * 262144, 256, 1024);
      gemm_k<EPI_BIAS, 256, 256, 256><<<Gw1, B256, 0, stream>>>(
          ybuf, wt, 0, ffn_b3 + t * 1024, 0, nullptr, u_pre, 1024,
          nullptr, nullptr, 1024);
      silu_mul_k<<<CH, B256, 0, stream>>>(g_pre, u_pre);
      TR(ffn_w2 + (long)t * 262144, 1024, 256);
      gemm_k<EPI_FINAL, 1024, 1024, 1024><<<Gw2, B256, 0, stream>>>(
          g_pre, wt, 0, ffn_b2 + t * 256, 0, outF32, nullptr, 256,
          xC, outC, 1024);
    }
  }
}

// Round 9
// 830.693 us; speedup vs baseline: 1.1417x; 1.1417x over previous
//
#include <hip/hip_runtime.h>
#include <hip/hip_bf16.h>

typedef __hip_bfloat16 bf16;
typedef __bf16 v8bf __attribute__((ext_vector_type(8)));
typedef float f32x4 __attribute__((ext_vector_type(4)));

#define N_AG 24576
#define N3 8192

struct __align__(8) bf4 { bf16 x, y, z, w; };
__device__ __forceinline__ bf4 mk4(float a, float b, float c, float d) {
  bf4 r{__float2bfloat16(a), __float2bfloat16(b), __float2bfloat16(c), __float2bfloat16(d)};
  return r;
}

// ---------------- epilogue modes ----------------
enum {
  EPI_RELU_BIAS = 0,  // Cout(bf16) = relu(v + bias)
  EPI_BIAS      = 1,  // Cout(bf16) = v + bias
  EPI_ACC_INIT  = 2,  // accbuf(f32) = v + bias
  EPI_ACC_ADD   = 3,  // accbuf(f32) += v + bias
  EPI_FINAL     = 4,  // CoutF(f32) = accbuf + v + bias + resid
  EPI_SILU      = 5,  // Cout(bf16) = silu(v + bias)
  EPI_MUL       = 6,  // Cout(bf16) = (v + bias) * gin[idx]
  EPI_GLU       = 7   // interleaved g/u tiles: Cout(bf16) = silu(g+bg) * (u+bu)
};

// async 16B/lane global->LDS DMA; LDS dest = wave-uniform base + lane*16
__device__ __forceinline__ void gl_lds16(const bf16* g, short* l) {
  __builtin_amdgcn_global_load_lds(
      (const __attribute__((address_space(1))) unsigned int*)g,
      (__attribute__((address_space(3))) unsigned int*)l, 16, 0, 0);
}

// counted-vmcnt leading barrier (64-tile pipeline)
__device__ __forceinline__ void wait_vm_barrier(int pending) {
  if (pending == 4)      asm volatile("s_waitcnt vmcnt(4)\ns_barrier" ::: "memory");
  else if (pending == 2) asm volatile("s_waitcnt vmcnt(2)\ns_barrier" ::: "memory");
  else                   asm volatile("s_waitcnt vmcnt(0)\ns_barrier" ::: "memory");
}
__device__ __forceinline__ void lgkm_barrier() {
  asm volatile("s_waitcnt lgkmcnt(0)\ns_barrier" ::: "memory");
}

// ---------------- 128-tile GEMM core: runtime shapes, 2-buf (R4 structure) ----------------
// PROVEN best for wide-N GEMMs (w1' 53-57us): compact runtime K-loop (no unroll
// -> small code footprint), double-buffered LDS, __syncthreads per step. The
// VALU address arithmetic doubles as latency cover (R5 showed removing it HURT).
// 128x128 tile, BK=32, 4 waves, 4x4 mfma. XOR swizzle chunk c -> c ^ s(r).
template<int EPI>
__device__ __forceinline__
void gemm_body(const bf16* __restrict__ A, int lda,
               const bf16* __restrict__ Bt, int ldb,
               const float* __restrict__ bias,
               float* __restrict__ accbuf,
               bf16* __restrict__ Cout, int ldc,
               const float* __restrict__ resid,
               float* __restrict__ CoutF,
               const bf16* __restrict__ gin,
               int K, int Nc, int row0, int col0)
{
  __shared__ __align__(16) short As[2][128 * 32];
  __shared__ __align__(16) short Bs[2][128 * 32];

  const int tid  = threadIdx.x;
  const int lane = tid & 63;
  const int w    = tid >> 6;
  const int quad = lane >> 4;
  const int l15  = lane & 15;

  f32x4 acc[4][4];
  const f32x4 zero = {0.f, 0.f, 0.f, 0.f};
#pragma unroll
  for (int i = 0; i < 4; ++i)
#pragma unroll
    for (int j = 0; j < 4; ++j) acc[i][j] = zero;

  // staging: wave w rows [w*32, w*32+32); lane i -> (row i>>2, phys chunk i&3)
  const int srow = (w << 5) + (lane >> 2);
  const int ss   = ((lane >> 2) & 3) ^ ((lane >> 4) & 1);   // s(srow), same for srow+16
  const int sc   = ((lane & 3) ^ ss) << 3;                  // global elem offset fetched
  const bf16* aG = A  + (long)(row0 + srow) * lda + sc;
  const bf16* bG = Bt + (long)(col0 + srow) * ldb + sc;
  const int ldsOff = w * 1024;     // wave-uniform LDS base (32 rows * 32 shorts)

  const int wr = (w >> 1) * 64;
  const int wc = (w & 1) * 64;
  const int fs = (l15 & 3) ^ ((l15 >> 2) & 1);   // frag-read swizzle

  // prologue: stage k=0 into buf 0
  gl_lds16(aG,                  As[0] + ldsOff);
  gl_lds16(aG + (long)16 * lda, As[0] + ldsOff + 512);
  gl_lds16(bG,                  Bs[0] + ldsOff);
  gl_lds16(bG + (long)16 * ldb, Bs[0] + ldsOff + 512);
  __syncthreads();

  int cur = 0;
  for (int k0 = 0; k0 < K; k0 += 32) {
    const int nk = k0 + 32;
    if (nk < K) {                      // issue next-step loads first (fly under compute)
      short* An = As[cur ^ 1] + ldsOff;
      short* Bn = Bs[cur ^ 1] + ldsOff;
      gl_lds16(aG + nk,                  An);
      gl_lds16(aG + nk + (long)16 * lda, An + 512);
      gl_lds16(bG + nk,                  Bn);
      gl_lds16(bG + nk + (long)16 * ldb, Bn + 512);
    }
    const short* Ac = As[cur];
    const short* Bc = Bs[cur];
    const int pc = (quad ^ fs) * 8;   // physical chunk elem offset
    v8bf af[4], bfm[4];
#pragma unroll
    for (int i = 0; i < 4; ++i) {
      af[i]  = *(const v8bf*)&Ac[(wr + i * 16 + l15) * 32 + pc];
      bfm[i] = *(const v8bf*)&Bc[(wc + i * 16 + l15) * 32 + pc];
    }
#pragma unroll
    for (int i = 0; i < 4; ++i)
#pragma unroll
      for (int j = 0; j < 4; ++j)
        acc[i][j] = __builtin_amdgcn_mfma_f32_16x16x32_bf16(af[i], bfm[j], acc[i][j], 0, 0, 0);
    __syncthreads();   // drains vmcnt(0): next buf staged; lgkmcnt: reads done
    cur ^= 1;
  }

  if constexpr (EPI == EPI_GLU) {
    // interleaved layout: 32-col blocks = [16 g-cols | 16 u-cols] of same h-cols.
#pragma unroll
    for (int ct = 0; ct < 4; ct += 2) {
      const int colg = col0 + wc + ct * 16 + l15;
      const int hcol = ((colg >> 5) << 4) + (colg & 15);
      const float bg = bias[colg];
      const float bu = bias[colg + 16];
#pragma unroll
      for (int rt = 0; rt < 4; ++rt) {
#pragma unroll
        for (int i = 0; i < 4; ++i) {
          const int row = row0 + wr + rt * 16 + quad * 4 + i;
          const float vg = acc[rt][ct][i] + bg;
          const float vu = acc[rt][ct + 1][i] + bu;
          Cout[(long)row * ldc + hcol] =
              __float2bfloat16(vg / (1.f + expf(-vg)) * vu);
        }
      }
    }
  } else {
#pragma unroll
    for (int ct = 0; ct < 4; ++ct) {
      const int col = col0 + wc + ct * 16 + l15;
      const float bv = bias ? bias[col] : 0.f;
#pragma unroll
      for (int rt = 0; rt < 4; ++rt) {
#pragma unroll
        for (int i = 0; i < 4; ++i) {
          const int row = row0 + wr + rt * 16 + quad * 4 + i;
          float v = acc[rt][ct][i] + bv;
          if constexpr (EPI == EPI_RELU_BIAS) {
            Cout[(long)row * ldc + col] = __float2bfloat16(v > 0.f ? v : 0.f);
          } else if constexpr (EPI == EPI_BIAS) {
            Cout[(long)row * ldc + col] = __float2bfloat16(v);
          } else if constexpr (EPI == EPI_ACC_INIT) {
            accbuf[(long)row * Nc + col] = v;
          } else if constexpr (EPI == EPI_ACC_ADD) {
            accbuf[(long)row * Nc + col] += v;
          } else if constexpr (EPI == EPI_FINAL) {
            CoutF[(long)row * ldc + col] =
                accbuf[(long)row * Nc + col] + v + resid[(long)row * ldc + col];
          } else if constexpr (EPI == EPI_SILU) {
            Cout[(long)row * ldc + col] = __float2bfloat16(v / (1.f + expf(-v)));
          } else {  // EPI_MUL
            const float g = __bfloat162float(gin[(long)row * ldc + col]);
            Cout[(long)row * ldc + col] = __float2bfloat16(v * g);
          }
        }
      }
    }
  }
}

// ---------------- 64x64-tile GEMM core: static K, 3-buf counted-vmcnt (R6) ----------------
// PROVEN best for N=256 GEMMs (R5->R6 -50us): 24 KB LDS -> ~6 blocks/CU, loads
// stay in flight across barriers (vmcnt 4/2), small unrolled body.
template<int EPI, int K, int LDA, int LDB>
__device__ __forceinline__
void gemm64_body(const bf16* __restrict__ A,
                 const bf16* __restrict__ Bt,
                 const float* __restrict__ bias,
                 float* __restrict__ accbuf,
                 bf16* __restrict__ Cout, int ldc,
                 const float* __restrict__ resid,
                 float* __restrict__ CoutF,
                 int Nc, int row0, int col0)
{
  __shared__ __align__(16) short As[3][64 * 32];
  __shared__ __align__(16) short Bs[3][64 * 32];

  const int tid  = threadIdx.x;
  const int lane = tid & 63;
  const int w    = tid >> 6;
  const int quad = lane >> 4;
  const int l15  = lane & 15;

  f32x4 acc[2][2];
  const f32x4 zero = {0.f, 0.f, 0.f, 0.f};
#pragma unroll
  for (int i = 0; i < 2; ++i)
#pragma unroll
    for (int j = 0; j < 2; ++j) acc[i][j] = zero;

  const int srow = (w << 4) + (lane >> 2);
  const int ss   = ((lane >> 2) & 3) ^ ((lane >> 4) & 1);
  const int sc   = ((lane & 3) ^ ss) << 3;
  const bf16* aG = A  + (long)(row0 + srow) * LDA + sc;
  const bf16* bG = Bt + (long)(col0 + srow) * LDB + sc;
  const int ldsOff = w * 512;

  const int wr = (w >> 1) * 32;
  const int wc = (w & 1) * 32;
  const int fs = (l15 & 3) ^ ((l15 >> 2) & 1);

  constexpr int NT = K / 32;

  gl_lds16(aG,      As[0] + ldsOff);
  gl_lds16(bG,      Bs[0] + ldsOff);
  gl_lds16(aG + 32, As[1] + ldsOff);
  gl_lds16(bG + 32, Bs[1] + ldsOff);

#pragma unroll
  for (int t = 0; t < NT; ++t) {
    const int nk = (t + 2) * 32;
    if (t + 2 < NT) {
      gl_lds16(aG + nk, As[(t + 2) % 3] + ldsOff);
      gl_lds16(bG + nk, Bs[(t + 2) % 3] + ldsOff);
    }
    wait_vm_barrier((t + 2 < NT) ? 4 : ((t + 1 < NT) ? 2 : 0));

    const short* Ac = As[t % 3];
    const short* Bc = Bs[t % 3];
    const int pc = (quad ^ fs) * 8;
    v8bf af[2], bfm[2];
#pragma unroll
    for (int i = 0; i < 2; ++i) {
      af[i]  = *(const v8bf*)&Ac[(wr + i * 16 + l15) * 32 + pc];
      bfm[i] = *(const v8bf*)&Bc[(wc + i * 16 + l15) * 32 + pc];
    }
#pragma unroll
    for (int i = 0; i < 2; ++i)
#pragma unroll
      for (int j = 0; j < 2; ++j)
        acc[i][j] = __builtin_amdgcn_mfma_f32_16x16x32_bf16(af[i], bfm[j], acc[i][j], 0, 0, 0);
    lgkm_barrier();
  }

#pragma unroll
  for (int ct = 0; ct < 2; ++ct) {
    const int col = col0 + wc + ct * 16 + l15;
    const float bv = bias ? bias[col] : 0.f;
#pragma unroll
    for (int rt = 0; rt < 2; ++rt) {
#pragma unroll
      for (int i = 0; i < 4; ++i) {
        const int row = row0 + wr + rt * 16 + quad * 4 + i;
        float v = acc[rt][ct][i] + bv;
        if constexpr (EPI == EPI_RELU_BIAS) {
          Cout[(long)row * ldc + col] = __float2bfloat16(v > 0.f ? v : 0.f);
        } else if constexpr (EPI == EPI_BIAS) {
          Cout[(long)row * ldc + col] = __float2bfloat16(v);
        } else if constexpr (EPI == EPI_ACC_INIT) {
          accbuf[(long)row * Nc + col] = v;
        } else if constexpr (EPI == EPI_ACC_ADD) {
          accbuf[(long)row * Nc + col] += v;
        } else if constexpr (EPI == EPI_FINAL) {
          CoutF[(long)row * ldc + col] =
              accbuf[(long)row * Nc + col] + v + resid[(long)row * ldc + col];
        }
      }
    }
  }
}

// 128-tile wrapper (runtime shapes)
template<int EPI>
__global__ __launch_bounds__(256)
void gemm_k(const bf16* __restrict__ A, int lda,
            const bf16* __restrict__ Bt, int ldb, long bTs,
            const float* __restrict__ bias, long biasTs,
            float* __restrict__ accbuf,
            bf16* __restrict__ Cout, int ldc,
            const float* __restrict__ resid,
            float* __restrict__ CoutF,
            const bf16* __restrict__ gin,
            int K, int Nc)
{
  const int row0 = blockIdx.x * 128;
  const int col0 = blockIdx.y * 128;
  const int t    = row0 >> 13;
  gemm_body<EPI>(A, lda, Bt + (long)t * bTs, ldb,
                 bias ? bias + (long)t * biasTs : nullptr,
                 accbuf, Cout, ldc, resid, CoutF, gin, K, Nc, row0, col0);
}

// 64-tile wrapper: grid (M/64, Nc/64)
template<int EPI, int K, int LDA, int LDB>
__global__ __launch_bounds__(256)
void gemm64_k(const bf16* __restrict__ A,
              const bf16* __restrict__ Bt, long bTs,
              const float* __restrict__ bias, long biasTs,
              float* __restrict__ accbuf,
              bf16* __restrict__ Cout, int ldc,
              const float* __restrict__ resid,
              float* __restrict__ CoutF,
              int Nc)
{
  const int row0 = blockIdx.x * 64;
  const int col0 = blockIdx.y * 64;
  const int t    = row0 >> 13;
  gemm64_body<EPI, K, LDA, LDB>(A, Bt + (long)t * bTs,
                                bias ? bias + (long)t * biasTs : nullptr,
                                accbuf, Cout, ldc, resid, CoutF, Nc, row0, col0);
}

// z-batched merged-W2 precompute (64-tile): W2'^T[b][t] = outW_slice(j(b))^T @ w2_b^T
__global__ __launch_bounds__(256)
void w2m_k(const bf16* __restrict__ outwT, const bf16* __restrict__ w2c,
           bf16* __restrict__ w2m)
{
  const int z = blockIdx.z, b = z / 3, t = z % 3;
  const int j = (b == 0) ? 1 : (b == 1) ? 2 : 3;
  gemm64_body<EPI_BIAS, 256, 1024, 256>(
      outwT + (long)t * 262144 + j * 256,
      w2c + (long)b * 262144,
      nullptr, nullptr, w2m + (long)z * 262144, 1024,
      nullptr, nullptr, 1024,
      blockIdx.x * 64, blockIdx.y * 64);
}

// ---------------- weight transpose+cast: src f32 [K,Nc] -> dst bf16 [Nc,K], batched z ----------------
__global__ __launch_bounds__(256)
void transpose_k(const float* __restrict__ src, bf16* __restrict__ dst,
                 int K, int Nc, long sB, long dB)
{
  __shared__ bf16 tile[32][33];
  const int b = blockIdx.z;
  const float* s = src + (long)b * sB;
  bf16* d = dst + (long)b * dB;
  const int kb = blockIdx.y * 32, nb = blockIdx.x * 32;
  const int tx = threadIdx.x & 31, ty = threadIdx.x >> 5;
#pragma unroll
  for (int i = 0; i < 32; i += 8)
    tile[ty + i][tx] = __float2bfloat16(s[(long)(kb + ty + i) * Nc + nb + tx]);
  __syncthreads();
#pragma unroll
  for (int i = 0; i < 32; i += 8)
    d[(long)(nb + ty + i) * K + kb + tx] = tile[tx][ty + i];
}

// ---------------- interleaved FFN w1/w3 transpose: dst bf16 [3][2048,256] ----------------
__global__ __launch_bounds__(256)
void transpose13_k(const float* __restrict__ w1, const float* __restrict__ w3,
                   bf16* __restrict__ dst)
{
  __shared__ bf16 tile[32][33];
  const int t  = blockIdx.z;
  const int n0 = blockIdx.x * 32;
  const int k0 = blockIdx.y * 32;
  const int gi = n0 >> 5;
  const int tx = threadIdx.x & 31, ty = threadIdx.x >> 5;
  const float* src = ((tx & 16) ? w3 : w1) + (long)t * 262144;
  const int c = 16 * gi + (tx & 15);
#pragma unroll
  for (int i = 0; i < 32; i += 8)
    tile[ty + i][tx] = __float2bfloat16(src[(long)(k0 + ty + i) * 1024 + c]);
  __syncthreads();
#pragma unroll
  for (int i = 0; i < 32; i += 8)
    dst[((long)t * 2048 + n0 + ty + i) * 256 + k0 + tx] = tile[tx][ty + i];
}

// ---------------- LN-folded w1: dst[b] (bf16 [1024,512]) from w1 f32 [Kin,1024] ----------------
struct FoldP { const float* w1[5]; const float* ls[5]; };
__global__ __launch_bounds__(256)
void fold_w1_k(FoldP p, bf16* __restrict__ dst)
{
  __shared__ float tile[32][33];
  const int z = blockIdx.z;
  const float* w1 = p.w1[z];
  const float* ls = p.ls[z];
  bf16* d = dst + (long)z * 524288;
  const int n0 = blockIdx.x * 32, i0 = blockIdx.y * 32;
  const int tx = threadIdx.x & 31, ty = threadIdx.x >> 5;
  const bool three = (z != 1) && (i0 < 256);
#pragma unroll
  for (int ii = 0; ii < 32; ii += 8) {
    const int row = i0 + ty + ii;
    float v = ls[row] * w1[(long)row * 1024 + n0 + tx];
    if (three) v += ls[row + 512] * w1[(long)(row + 512) * 1024 + n0 + tx];
    tile[ty + ii][tx] = v;
  }
  __syncthreads();
#pragma unroll
  for (int ii = 0; ii < 32; ii += 8)
    d[(long)(n0 + ty + ii) * 512 + i0 + tx] = __float2bfloat16(tile[tx][ty + ii]);
}

// ---------------- bias-fold precompute (parallelized) ----------------
struct BInitP { const float* b1[5]; const float* fb1; const float* fb3; };
__global__ __launch_bounds__(256)
void binit_k(BInitP p, float* __restrict__ B1F,
             const float* __restrict__ out_b, float* __restrict__ TB,
             float* __restrict__ B13)
{
  const int i = blockIdx.x * 256 + threadIdx.x;
  if (i < 5120) {
    B1F[i] = p.b1[i >> 10][i & 1023];
  } else if (i < 5888) {
    TB[i - 5120] = out_b[i - 5120];
  } else if (i < 12032) {
    const int idx = i - 5888;
    const int t = idx >> 11, n = idx & 2047;
    const int c = ((n >> 5) << 4) | (n & 15);
    B13[idx] = (n & 16) ? p.fb3[t * 1024 + c] : p.fb1[t * 1024 + c];
  }
}

// B1F[z][n] += sum_k lb[k]*w1[k,n]; grid (z=5, ksplit=32)
struct B1P { const float* w1[5]; const float* lb[5]; int kin[5]; };
__global__ __launch_bounds__(256)
void b1f_add_k(B1P p, float* __restrict__ dst)
{
  const int z   = blockIdx.x;
  const int kin = p.kin[z];
  const int kpb = (kin + 31) >> 5;
  const int k0  = blockIdx.y * kpb;
  const int k1  = min(k0 + kpb, kin);
  const float* w1 = p.w1[z];
  const float* lb = p.lb[z];
  const int n = threadIdx.x;
  float a0 = 0.f, a1 = 0.f, a2 = 0.f, a3 = 0.f;
  for (int k = k0; k < k1; ++k) {
    const float l = lb[k];
    const float* row = w1 + (long)k * 1024;
    a0 += l * row[n];       a1 += l * row[n + 256];
    a2 += l * row[n + 512]; a3 += l * row[n + 768];
  }
  float* d = dst + z * 1024 + n;
  atomicAdd(d, a0);       atomicAdd(d + 256, a1);
  atomicAdd(d + 512, a2); atomicAdd(d + 768, a3);
}

// TB[t][h] += b2-vectors through outW slices; grid (t=3, csplit=8)
__global__ __launch_bounds__(256)
void tbias_add_k(const float* __restrict__ outW,
                 const float* __restrict__ l2a_b2, const float* __restrict__ g2a_b2,
                 const float* __restrict__ oth_b2, float* __restrict__ dst)
{
  const int t = blockIdx.x, h = threadIdx.x;
  const float* W = outW + (long)t * 262144;
  const int c0 = blockIdx.y * 32;
  float acc = 0.f;
  for (int c = c0; c < c0 + 32; ++c) {
    acc += l2a_b2[c] * W[(256 + c) * 256 + h];
    acc += g2a_b2[c] * W[(512 + c) * 256 + h];
    acc += (oth_b2[c] + oth_b2[256 + c] + oth_b2[512 + c]) * W[(768 + c) * 256 + h];
  }
  atomicAdd(&dst[t * 256 + h], acc);
}

// ---------------- f32 -> bf16 cast, 4 elems/thread ----------------
__global__ __launch_bounds__(256)
void cast_k(const float* __restrict__ src, bf16* __restrict__ dst)
{
  const long i = (long)blockIdx.x * 256 + threadIdx.x;
  const float4 v = ((const float4*)src)[i];
  ((bf4*)dst)[i] = mk4(v.x, v.y, v.z, v.w);
}

// ---------------- wave-wide reduce (all lanes get totals) ----------------
__device__ __forceinline__ void wave_reduce2(float& s, float& q) {
#pragma unroll
  for (int off = 32; off > 0; off >>= 1) {
    s += __shfl_xor(s, off, 64);
    q += __shfl_xor(q, off, 64);
  }
}

// ---------------- normalized-only LN: writes [fn, xn] (512 bf16) ----------------
template<int THREE>
__global__ __launch_bounds__(256)
void ln_norm_k(const float* __restrict__ feat, const float* __restrict__ x,
               const int* __restrict__ srcIdx, bf16* __restrict__ out)
{
  const int w = threadIdx.x >> 6, lane = threadIdx.x & 63;
  const int r = blockIdx.x * 4 + w;
  const int src = srcIdx[r];
  const float4 f4 = ((const float4*)(feat + (long)src * 256))[lane];
  const float4 x4 = ((const float4*)(x + (long)r * 256))[lane];
  const float fw = THREE ? 2.f : 1.f;
  float s = fw * (f4.x + f4.y + f4.z + f4.w) + (x4.x + x4.y + x4.z + x4.w);
  float q = fw * (f4.x * f4.x + f4.y * f4.y + f4.z * f4.z + f4.w * f4.w) +
            (x4.x * x4.x + x4.y * x4.y + x4.z * x4.z + x4.w * x4.w);
  wave_reduce2(s, q);
  const float rD  = THREE ? (1.f / 768.f) : (1.f / 512.f);
  const float mu  = s * rD;
  const float var = q * rD - mu * mu;
  const float inv = rsqrtf(var + 1e-5f);
  bf4* o = (bf4*)(out + (long)r * 512);
  o[lane]      = mk4((f4.x - mu) * inv, (f4.y - mu) * inv,
                     (f4.z - mu) * inv, (f4.w - mu) * inv);
  o[64 + lane] = mk4((x4.x - mu) * inv, (x4.y - mu) * inv,
                     (x4.z - mu) * inv, (x4.w - mu) * inv);
}

// ---------------- legacy LN kernels (Tier C path) ----------------
__global__ __launch_bounds__(256)
void ln_cat3_k(const float* __restrict__ feat, const float* __restrict__ x,
               const int* __restrict__ srcIdx,
               const float* __restrict__ ls, const float* __restrict__ lb,
               bf16* __restrict__ out)
{
  const int w = threadIdx.x >> 6, lane = threadIdx.x & 63;
  const int r = blockIdx.x * 4 + w;
  const int src = srcIdx[r];
  const float4 f4 = ((const float4*)(feat + (long)src * 256))[lane];
  const float4 x4 = ((const float4*)(x + (long)r * 256))[lane];
  float s = 2.f * (f4.x + f4.y + f4.z + f4.w) + (x4.x + x4.y + x4.z + x4.w);
  float q = 2.f * (f4.x * f4.x + f4.y * f4.y + f4.z * f4.z + f4.w * f4.w) +
            (x4.x * x4.x + x4.y * x4.y + x4.z * x4.z + x4.w * x4.w);
  wave_reduce2(s, q);
  const float mu  = s * (1.f / 768.f);
  const float var = q * (1.f / 768.f) - mu * mu;
  const float inv = rsqrtf(var + 1e-5f);
  const float4 s0 = ((const float4*)ls)[lane],         b0 = ((const float4*)lb)[lane];
  const float4 s1 = ((const float4*)(ls + 256))[lane], b1 = ((const float4*)(lb + 256))[lane];
  const float4 s2 = ((const float4*)(ls + 512))[lane], b2 = ((const float4*)(lb + 512))[lane];
  bf4* o = (bf4*)(out + (long)r * 768);
  o[lane] = mk4((f4.x - mu) * inv * s0.x + b0.x, (f4.y - mu) * inv * s0.y + b0.y,
                (f4.z - mu) * inv * s0.z + b0.z, (f4.w - mu) * inv * s0.w + b0.w);
  o[64 + lane] = mk4((x4.x - mu) * inv * s1.x + b1.x, (x4.y - mu) * inv * s1.y + b1.y,
                     (x4.z - mu) * inv * s1.z + b1.z, (x4.w - mu) * inv * s1.w + b1.w);
  o[128 + lane] = mk4((f4.x - mu) * inv * s2.x + b2.x, (f4.y - mu) * inv * s2.y + b2.y,
                      (f4.z - mu) * inv * s2.z + b2.z, (f4.w - mu) * inv * s2.w + b2.w);
}

__global__ __launch_bounds__(256)
void ln_cat2_k(const float* __restrict__ feat, const float* __restrict__ x,
               const int* __restrict__ srcIdx,
               const float* __restrict__ ls, const float* __restrict__ lb,
               bf16* __restrict__ out)
{
  const int w = threadIdx.x >> 6, lane = threadIdx.x & 63;
  const int r = blockIdx.x * 4 + w;
  const int src = srcIdx[r];
  const float4 f4 = ((const float4*)(feat + (long)src * 256))[lane];
  const float4 x4 = ((const float4*)(x + (long)r * 256))[lane];
  float s = (f4.x + f4.y + f4.z + f4.w) + (x4.x + x4.y + x4.z + x4.w);
  float q = (f4.x * f4.x + f4.y * f4.y + f4.z * f4.z + f4.w * f4.w) +
            (x4.x * x4.x + x4.y * x4.y + x4.z * x4.z + x4.w * x4.w);
  wave_reduce2(s, q);
  const float mu  = s * (1.f / 512.f);
  const float var = q * (1.f / 512.f) - mu * mu;
  const float inv = rsqrtf(var + 1e-5f);
  const float4 s0 = ((const float4*)ls)[lane],         b0 = ((const float4*)lb)[lane];
  const float4 s1 = ((const float4*)(ls + 256))[lane], b1 = ((const float4*)(lb + 256))[lane];
  bf4* o = (bf4*)(out + (long)r * 512);
  o[lane] = mk4((f4.x - mu) * inv * s0.x + b0.x, (f4.y - mu) * inv * s0.y + b0.y,
                (f4.z - mu) * inv * s0.z + b0.z, (f4.w - mu) * inv * s0.w + b0.w);
  o[64 + lane] = mk4((x4.x - mu) * inv * s1.x + b1.x, (x4.y - mu) * inv * s1.y + b1.y,
                     (x4.z - mu) * inv * s1.z + b1.z, (x4.w - mu) * inv * s1.w + b1.w);
}

// ---------------- FFN layernorm width 256: f32 in, bf16 out; one wave per row ----------------
__global__ __launch_bounds__(256)
void ln_ffn_k(const float* __restrict__ ob, const float* __restrict__ ls,
              const float* __restrict__ lb, bf16* __restrict__ y, long lsStride)
{
  const int w = threadIdx.x >> 6, lane = threadIdx.x & 63;
  const int r = blockIdx.x * 4 + w;
  const long po = (long)(r >> 13) * lsStride;
  const float4 v4 = ((const float4*)(ob + (long)r * 256))[lane];
  float s = v4.x + v4.y + v4.z + v4.w;
  float q = v4.x * v4.x + v4.y * v4.y + v4.z * v4.z + v4.w * v4.w;
  wave_reduce2(s, q);
  const float mu  = s * (1.f / 256.f);
  const float var = q * (1.f / 256.f) - mu * mu;
  const float inv = rsqrtf(var + 1e-5f);
  const float4 s0 = ((const float4*)(ls + po))[lane];
  const float4 b0 = ((const float4*)(lb + po))[lane];
  ((bf4*)(y + (long)r * 256))[lane] =
      mk4((v4.x - mu) * inv * s0.x + b0.x, (v4.y - mu) * inv * s0.y + b0.y,
          (v4.z - mu) * inv * s0.z + b0.z, (v4.w - mu) * inv * s0.w + b0.w);
}

// ---------------- g = silu(g) * u, 4 elems/thread (Tier C path) ----------------
__global__ __launch_bounds__(256)
void silu_mul_k(bf16* __restrict__ g, const bf16* __restrict__ u)
{
  const long i = (long)blockIdx.x * 256 + threadIdx.x;
  const bf4 g4 = ((const bf4*)g)[i];
  const bf4 u4 = ((const bf4*)u)[i];
  float a = __bfloat162float(g4.x), b = __bfloat162float(g4.y);
  float c = __bfloat162float(g4.z), d = __bfloat162float(g4.w);
  a = a / (1.f + expf(-a)) * __bfloat162float(u4.x);
  b = b / (1.f + expf(-b)) * __bfloat162float(u4.y);
  c = c / (1.f + expf(-c)) * __bfloat162float(u4.z);
  d = d / (1.f + expf(-d)) * __bfloat162float(u4.w);
  ((bf4*)g)[i] = mk4(a, b, c, d);
}

// ---------------- sentinel fill (diagnostic) ----------------
__global__ __launch_bounds__(256)
void fill_k(float* __restrict__ p, int n)
{
  const int i = blockIdx.x * 256 + threadIdx.x;
  if (i < n) p[i] = 2.0f;
}

// ---------------- host ----------------
extern "C" void kernel_launch(void* const* d_in, const int* in_sizes, int n_in,
                              void* d_out, int out_size, void* d_ws, size_t ws_size,
                              hipStream_t stream)
{
  const float* agent_x  = (const float*)d_in[0];
  const float* lane_x   = (const float*)d_in[1];
  const float* poly_x   = (const float*)d_in[2];
  const int*   l2a_src  = (const int*)d_in[3];
  const int*   g2a_src  = (const int*)d_in[4];
  const int*   other_src= (const int*)d_in[5];
  const float* self_W   = (const float*)d_in[6];
  const float* self_b   = (const float*)d_in[7];
  const float* out_W    = (const float*)d_in[8];
  const float* out_b    = (const float*)d_in[9];
  const float* ffn_ln_s = (const float*)d_in[10];
  const float* ffn_ln_b = (const float*)d_in[11];
  const float* ffn_w1   = (const float*)d_in[12];
  const float* ffn_b1   = (const float*)d_in[13];
  const float* ffn_w2   = (const float*)d_in[14];
  const float* ffn_b2   = (const float*)d_in[15];
  const float* ffn_w3   = (const float*)d_in[16];
  const float* ffn_b3   = (const float*)d_in[17];
  const float* l2a_ln_s = (const float*)d_in[18];
  const float* l2a_ln_b = (const float*)d_in[19];
  const float* l2a_w1   = (const float*)d_in[20];
  const float* l2a_b1   = (const float*)d_in[21];
  const float* l2a_w2   = (const float*)d_in[22];
  const float* l2a_b2   = (const float*)d_in[23];
  const float* g2a_ln_s = (const float*)d_in[24];
  const float* g2a_ln_b = (const float*)d_in[25];
  const float* g2a_w1   = (const float*)d_in[26];
  const float* g2a_b1   = (const float*)d_in[27];
  const float* g2a_w2   = (const float*)d_in[28];
  const float* g2a_b2   = (const float*)d_in[29];
  const float* oth_ln_s = (const float*)d_in[30];
  const float* oth_ln_b = (const float*)d_in[31];
  const float* oth_w1   = (const float*)d_in[32];
  const float* oth_b1   = (const float*)d_in[33];
  const float* oth_w2   = (const float*)d_in[34];
  const float* oth_b2   = (const float*)d_in[35];

  float* outp = (float*)d_out;
  const dim3 B256(256);

  const size_t TIER_A = 135707648;  // full-N layout (fits inside proven 155 MB grant)
  const size_t TIER_C = 12058624;   // chunked fallback

  if (ws_size >= TIER_A) {
    // ============ Tier A: hybrid tiles — 128-tile runtime 2-buf for wide-N,
    // ============ 64-tile static 3-buf counted-vmcnt for N=256 (per-kernel bests) ============
    char* base = (char*)d_ws;
    bf16* wT = (bf16*)base;
    const long SELF_WT = 0,       OUT_WT  = 196608,  FFN_W13T = 983040;  // [3][2048,256]
    const long FFN_W2T = 2555904;
    const long W2C = 3342336,     W1F     = 4653056, W2M      = 7274496;
    float* B1F  = (float*)(base + 22413312L);   // [5][1024] folded w1 bias
    float* TB   = (float*)(base + 22433792L);   // [3][256]  fused out-bias
    float* B13  = (float*)(base + 22436864L);   // [3][2048] interleaved ffn bias
    bf16*  nbuf = (bf16*)(base + 22461440L);    // [N,512]  LN output
    bf16*  h1   = (bf16*)(base + 47627264L);    // [N,1024] w1 out / FFN g*u
    float* oF   = (float*)(base + 97958912L);   // [N,256]  branch accumulator
    bf16*  ybuf = (bf16*)(base + 123124736L);   // [N,256]  self_out / FFN y
    bf16*  xbf  = h1;  // bf16 cast of agent_x (dead before h1 written)

    // ---- weight precompute ----
    auto TRB = [&](const float* s, long dOff, int K, int Nc, long sB, long dB, int b) {
      transpose_k<<<dim3(Nc / 32, K / 32, b), B256, 0, stream>>>(s, wT + dOff, K, Nc, sB, dB);
    };
    TRB(self_W, SELF_WT, 256, 256,  65536, 65536, 3);
    TRB(out_W,  OUT_WT,  1024, 256, 262144, 262144, 3);
    TRB(ffn_w2, FFN_W2T, 1024, 256, 262144, 262144, 3);
    transpose13_k<<<dim3(64, 8, 3), B256, 0, stream>>>(ffn_w1, ffn_w3, wT + FFN_W13T);
    cast_k<<<256, B256, 0, stream>>>(l2a_w2, wT + W2C);
    cast_k<<<256, B256, 0, stream>>>(g2a_w2, wT + W2C + 262144);
    cast_k<<<768, B256, 0, stream>>>(oth_w2, wT + W2C + 524288);

    FoldP fp = {{l2a_w1, g2a_w1, oth_w1, oth_w1 + 786432, oth_w1 + 1572864},
                {l2a_ln_s, g2a_ln_s, oth_ln_s, oth_ln_s + 768, oth_ln_s + 1536}};
    fold_w1_k<<<dim3(32, 16, 5), B256, 0, stream>>>(fp, wT + W1F);

    BInitP ip = {{l2a_b1, g2a_b1, oth_b1, oth_b1 + 1024, oth_b1 + 2048}, ffn_b1, ffn_b3};
    binit_k<<<47, B256, 0, stream>>>(ip, B1F, out_b, TB, B13);
    B1P bp = {{l2a_w1, g2a_w1, oth_w1, oth_w1 + 786432, oth_w1 + 1572864},
              {l2a_ln_b, g2a_ln_b, oth_ln_b, oth_ln_b + 768, oth_ln_b + 1536},
              {768, 512, 768, 768, 768}};
    b1f_add_k<<<dim3(5, 32), B256, 0, stream>>>(bp, B1F);
    tbias_add_k<<<dim3(3, 8), B256, 0, stream>>>(out_W, l2a_b2, g2a_b2, oth_b2, TB);
    w2m_k<<<dim3(4, 16, 15), B256, 0, stream>>>(wT + OUT_WT, wT + W2C, wT + W2M);

    const dim3 G64n2(N_AG / 64, 4);     // N=256 GEMMs (64-tile): 1536 blocks
    const dim3 Gw1(N_AG / 128, 8);      // w1' (128-tile): 1536 blocks
    const dim3 Gglu(N_AG / 128, 16);    // GLU (128-tile): 3072 blocks

    // ---- self branch (ACC_INIT carries all fused biases) ----
    cast_k<<<N_AG / 4, B256, 0, stream>>>(agent_x, xbf);
    gemm64_k<EPI_RELU_BIAS, 256, 256, 256><<<G64n2, B256, 0, stream>>>(
        xbf, wT + SELF_WT, 65536, self_b, 256,
        nullptr, ybuf, 256, nullptr, nullptr, 256);
    gemm64_k<EPI_ACC_INIT, 256, 256, 1024><<<G64n2, B256, 0, stream>>>(
        ybuf, wT + OUT_WT, 262144, TB, 256,
        oF, nullptr, 0, nullptr, nullptr, 256);

    // ---- edge branches: LN -> w1' (128-tile runtime) -> merged-w2' (64-tile) ----
    for (int b = 0; b < 5; ++b) {
      const int* src = (b == 0) ? l2a_src : (b == 1) ? g2a_src
                                          : other_src + (long)(b - 2) * N_AG;
      const float* feat = (b == 0) ? lane_x : (b == 1) ? poly_x : agent_x;
      if (b == 1) ln_norm_k<0><<<N_AG / 4, B256, 0, stream>>>(feat, agent_x, src, nbuf);
      else        ln_norm_k<1><<<N_AG / 4, B256, 0, stream>>>(feat, agent_x, src, nbuf);
      gemm_k<EPI_RELU_BIAS><<<Gw1, B256, 0, stream>>>(
          nbuf, 512, wT + W1F + (long)b * 524288, 512, 0, B1F + b * 1024, 0,
          nullptr, h1, 1024, nullptr, nullptr, nullptr, 512, 1024);
      gemm64_k<EPI_ACC_ADD, 1024, 1024, 1024><<<G64n2, B256, 0, stream>>>(
          h1, wT + W2M + (long)b * 786432, 262144, nullptr, 0,
          oF, nullptr, 0, nullptr, nullptr, 256);
    }

    // ---- FFN: GLU (128-tile runtime), then w2 FINAL (64-tile) ----
    ln_ffn_k<<<N_AG / 4, B256, 0, stream>>>(oF, ffn_ln_s, ffn_ln_b, ybuf, 256);
    gemm_k<EPI_GLU><<<Gglu, B256, 0, stream>>>(
        ybuf, 256, wT + FFN_W13T, 256, 524288, B13, 2048,
        nullptr, h1, 1024, nullptr, nullptr, nullptr, 256, 2048);
    gemm64_k<EPI_FINAL, 1024, 1024, 1024><<<G64n2, B256, 0, stream>>>(
        h1, wT + FFN_W2T, 262144, ffn_b2, 256,
        oF, nullptr, 256, agent_x, outp, 256);
    return;
  }

  if (ws_size < TIER_C) {
    fill_k<<<(out_size + 255) / 256, B256, 0, stream>>>(outp, out_size);
    return;
  }

  // ================= Tier C: chunked path (11.5 MiB) =================
  const int CH = 2048;
  char* base = (char*)d_ws;
  bf16*  wt     = (bf16*)base;
  bf16*  nbuf   = (bf16*)(base + 1572864L);
  bf16*  bbuf   = (bf16*)(base + 4718592L);
  bf16*  h1     = (bf16*)(base + 5767168L);
  float* outF32 = (float*)(base + 9961472L);
  bf16*  ybuf   = (bf16*)(base + 524288L);
  bf16*  xbf    = h1;
  bf16*  g_pre  = h1;
  bf16*  u_pre  = nbuf;

  const dim3 Gw1(CH / 128, 8), Gw2(CH / 128, 2);
  auto TR = [&](const float* s, int K, int Nc) {
    transpose_k<<<dim3(Nc / 32, K / 32), B256, 0, stream>>>(s, wt, K, Nc, 0, 0);
  };

  for (int t = 0; t < 3; ++t) {
    for (int c = 0; c < N3 / CH; ++c) {
      const long r0 = (long)t * N3 + (long)c * CH;
      const float* xC   = agent_x + r0 * 256;
      float*       outC = outp + r0 * 256;

      cast_k<<<CH / 4, B256, 0, stream>>>(xC, xbf);
      TR(self_W + (long)t * 65536, 256, 256);
      gemm_k<EPI_RELU_BIAS><<<Gw2, B256, 0, stream>>>(
          xbf, 256, wt, 256, 0, self_b + t * 256, 0, nullptr, bbuf, 256,
          nullptr, nullptr, nullptr, 256, 256);
      TR(out_W + (long)t * 262144 + 0 * 65536, 256, 256);
      gemm_k<EPI_ACC_INIT><<<Gw2, B256, 0, stream>>>(
          bbuf, 256, wt, 256, 0, out_b + t * 256, 0, outF32, nullptr, 0,
          nullptr, nullptr, nullptr, 256, 256);

      ln_cat3_k<<<CH / 4, B256, 0, stream>>>(lane_x, xC, l2a_src + r0,
                                             l2a_ln_s, l2a_ln_b, nbuf);
      TR(l2a_w1, 768, 1024);
      gemm_k<EPI_RELU_BIAS><<<Gw1, B256, 0, stream>>>(
          nbuf, 768, wt, 768, 0, l2a_b1, 0, nullptr, h1, 1024,
          nullptr, nullptr, nullptr, 768, 1024);
      TR(l2a_w2, 1024, 256);
      gemm_k<EPI_BIAS><<<Gw2, B256, 0, stream>>>(
          h1, 1024, wt, 1024, 0, l2a_b2, 0, nullptr, bbuf, 256,
          nullptr, nullptr, nullptr, 1024, 256);
      TR(out_W + (long)t * 262144 + 1 * 65536, 256, 256);
      gemm_k<EPI_ACC_ADD><<<Gw2, B256, 0, stream>>>(
          bbuf, 256, wt, 256, 0, nullptr, 0, outF32, nullptr, 0,
          nullptr, nullptr, nullptr, 256, 256);

      ln_cat2_k<<<CH / 4, B256, 0, stream>>>(poly_x, xC, g2a_src + r0,
                                             g2a_ln_s, g2a_ln_b, nbuf);
      TR(g2a_w1, 512, 1024);
      gemm_k<EPI_RELU_BIAS><<<Gw1, B256, 0, stream>>>(
          nbuf, 512, wt, 512, 0, g2a_b1, 0, nullptr, h1, 1024,
          nullptr, nullptr, nullptr, 512, 1024);
      TR(g2a_w2, 1024, 256);
      gemm_k<EPI_BIAS><<<Gw2, B256, 0, stream>>>(
          h1, 1024, wt, 1024, 0, g2a_b2, 0, nullptr, bbuf, 256,
          nullptr, nullptr, nullptr, 1024, 256);
      TR(out_W + (long)t * 262144 + 2 * 65536, 256, 256);
      gemm_k<EPI_ACC_ADD><<<Gw2, B256, 0, stream>>>(
          bbuf, 256, wt, 256, 0, nullptr, 0, outF32, nullptr, 0,
          nullptr, nullptr, nullptr, 256, 256);

      for (int s = 0; s < 3; ++s) {
        ln_cat3_k<<<CH / 4, B256, 0, stream>>>(
            agent_x, xC, other_src + (long)s * N_AG + r0,
            oth_ln_s + s * 768, oth_ln_b + s * 768, nbuf);
        TR(oth_w1 + (long)s * 786432, 768, 1024);
        gemm_k<EPI_RELU_BIAS><<<Gw1, B256, 0, stream>>>(
            nbuf, 768, wt, 768, 0, oth_b1 + s * 1024, 0, nullptr, h1, 1024,
            nullptr, nullptr, nullptr, 768, 1024);
        TR(oth_w2 + (long)s * 262144, 1024, 256);
        gemm_k<EPI_BIAS><<<Gw2, B256, 0, stream>>>(
            h1, 1024, wt, 1024, 0, oth_b2 + s * 256, 0, nullptr, bbuf, 256,
            nullptr, nullptr, nullptr, 1024, 256);
        TR(out_W + (long)t * 262144 + 3 * 65536, 256, 256);
        gemm_k<EPI_ACC_ADD><<<Gw2, B256, 0, stream>>>(
            bbuf, 256, wt, 256, 0, nullptr, 0, outF32, nullptr, 0,
            nullptr, nullptr, nullptr, 256, 256);
      }

      ln_ffn_k<<<CH / 4, B256, 0, stream>>>(outF32, ffn_ln_s + t * 256,
                                            ffn_ln_b + t * 256, ybuf, 0);
      TR(ffn_w1 + (long)t * 262144, 256, 1024);
      gemm_k<EPI_BIAS><<<Gw1, B256, 0, stream>>>(
          ybuf, 256, wt, 256, 0, ffn_b1 + t * 1024, 0, nullptr, g_pre, 1024,
          nullptr, nullptr, nullptr, 256, 1024);
      TR(ffn_w3 + (long)t * 262144, 256, 1024);
      gemm_k<EPI_BIAS><<<Gw1, B256, 0, stream>>>(
          ybuf, 256, wt, 256, 0, ffn_b3 + t * 1024, 0, nullptr, u_pre, 1024,
          nullptr, nullptr, nullptr, 256, 1024);
      silu_mul_k<<<CH, B256, 0, stream>>>(g_pre, u_pre);
      TR(ffn_w2 + (long)t * 262144, 1024, 256);
      gemm_k<EPI_FINAL><<<Gw2, B256, 0, stream>>>(
          g_pre, 1024, wt, 1024, 0, ffn_b2 + t * 256, 0, outF32, nullptr, 256,
          xC, outC, nullptr, 1024, 256);
    }
  }
}

// Round 10
// 820.015 us; speedup vs baseline: 1.1566x; 1.0130x over previous
//
#include <hip/hip_runtime.h>
#include <hip/hip_bf16.h>

typedef __hip_bfloat16 bf16;
typedef __bf16 v8bf __attribute__((ext_vector_type(8)));
typedef float f32x4 __attribute__((ext_vector_type(4)));

#define N_AG 24576
#define N3 8192

struct __align__(8) bf4 { bf16 x, y, z, w; };
__device__ __forceinline__ bf4 mk4(float a, float b, float c, float d) {
  bf4 r{__float2bfloat16(a), __float2bfloat16(b), __float2bfloat16(c), __float2bfloat16(d)};
  return r;
}

// ---------------- epilogue modes ----------------
enum {
  EPI_RELU_BIAS = 0,  // Cout(bf16) = relu(v + bias)
  EPI_BIAS      = 1,  // Cout(bf16) = v + bias
  EPI_ACC_INIT  = 2,  // accbuf(f32) = v + bias
  EPI_ACC_ADD   = 3,  // accbuf(f32) += v + bias
  EPI_FINAL     = 4,  // CoutF(f32) = accbuf + v + bias + resid
  EPI_SILU      = 5,  // Cout(bf16) = silu(v + bias)
  EPI_MUL       = 6,  // Cout(bf16) = (v + bias) * gin[idx]
  EPI_GLU       = 7   // interleaved g/u tiles: Cout(bf16) = silu(g+bg) * (u+bu)
};

// async 16B/lane global->LDS DMA; LDS dest = wave-uniform base + lane*16
__device__ __forceinline__ void gl_lds16(const bf16* g, short* l) {
  __builtin_amdgcn_global_load_lds(
      (const __attribute__((address_space(1))) unsigned int*)g,
      (__attribute__((address_space(3))) unsigned int*)l, 16, 0, 0);
}

// ---------------- 128-tile GEMM core: runtime shapes, 2-buf (806-proven) ----------------
// Best measured for wide-N GEMMs (w1' 53-57us). Compact runtime K-loop; the
// VALU address arithmetic doubles as latency cover (static unroll HURT, R5/R6).
template<int EPI>
__device__ __forceinline__
void gemm_body(const bf16* __restrict__ A, int lda,
               const bf16* __restrict__ Bt, int ldb,
               const float* __restrict__ bias,
               float* __restrict__ accbuf,
               bf16* __restrict__ Cout, int ldc,
               const float* __restrict__ resid,
               float* __restrict__ CoutF,
               const bf16* __restrict__ gin,
               int K, int Nc, int row0, int col0)
{
  __shared__ __align__(16) short As[2][128 * 32];
  __shared__ __align__(16) short Bs[2][128 * 32];

  const int tid  = threadIdx.x;
  const int lane = tid & 63;
  const int w    = tid >> 6;
  const int quad = lane >> 4;
  const int l15  = lane & 15;

  f32x4 acc[4][4];
  const f32x4 zero = {0.f, 0.f, 0.f, 0.f};
#pragma unroll
  for (int i = 0; i < 4; ++i)
#pragma unroll
    for (int j = 0; j < 4; ++j) acc[i][j] = zero;

  // staging: wave w rows [w*32, w*32+32); lane i -> (row i>>2, phys chunk i&3)
  const int srow = (w << 5) + (lane >> 2);
  const int ss   = ((lane >> 2) & 3) ^ ((lane >> 4) & 1);   // s(srow), same for srow+16
  const int sc   = ((lane & 3) ^ ss) << 3;                  // global elem offset fetched
  const bf16* aG = A  + (long)(row0 + srow) * lda + sc;
  const bf16* bG = Bt + (long)(col0 + srow) * ldb + sc;
  const int ldsOff = w * 1024;

  const int wr = (w >> 1) * 64;
  const int wc = (w & 1) * 64;
  const int fs = (l15 & 3) ^ ((l15 >> 2) & 1);   // frag-read swizzle

  gl_lds16(aG,                  As[0] + ldsOff);
  gl_lds16(aG + (long)16 * lda, As[0] + ldsOff + 512);
  gl_lds16(bG,                  Bs[0] + ldsOff);
  gl_lds16(bG + (long)16 * ldb, Bs[0] + ldsOff + 512);
  __syncthreads();

  int cur = 0;
  for (int k0 = 0; k0 < K; k0 += 32) {
    const int nk = k0 + 32;
    if (nk < K) {
      short* An = As[cur ^ 1] + ldsOff;
      short* Bn = Bs[cur ^ 1] + ldsOff;
      gl_lds16(aG + nk,                  An);
      gl_lds16(aG + nk + (long)16 * lda, An + 512);
      gl_lds16(bG + nk,                  Bn);
      gl_lds16(bG + nk + (long)16 * ldb, Bn + 512);
    }
    const short* Ac = As[cur];
    const short* Bc = Bs[cur];
    const int pc = (quad ^ fs) * 8;
    v8bf af[4], bfm[4];
#pragma unroll
    for (int i = 0; i < 4; ++i) {
      af[i]  = *(const v8bf*)&Ac[(wr + i * 16 + l15) * 32 + pc];
      bfm[i] = *(const v8bf*)&Bc[(wc + i * 16 + l15) * 32 + pc];
    }
#pragma unroll
    for (int i = 0; i < 4; ++i)
#pragma unroll
      for (int j = 0; j < 4; ++j)
        acc[i][j] = __builtin_amdgcn_mfma_f32_16x16x32_bf16(af[i], bfm[j], acc[i][j], 0, 0, 0);
    __syncthreads();
    cur ^= 1;
  }

  if constexpr (EPI == EPI_GLU) {
    // interleaved layout: 32-col blocks = [16 g-cols | 16 u-cols] of same h-cols.
#pragma unroll
    for (int ct = 0; ct < 4; ct += 2) {
      const int colg = col0 + wc + ct * 16 + l15;
      const int hcol = ((colg >> 5) << 4) + (colg & 15);
      const float bg = bias[colg];
      const float bu = bias[colg + 16];
#pragma unroll
      for (int rt = 0; rt < 4; ++rt) {
#pragma unroll
        for (int i = 0; i < 4; ++i) {
          const int row = row0 + wr + rt * 16 + quad * 4 + i;
          const float vg = acc[rt][ct][i] + bg;
          const float vu = acc[rt][ct + 1][i] + bu;
          Cout[(long)row * ldc + hcol] =
              __float2bfloat16(vg / (1.f + expf(-vg)) * vu);
        }
      }
    }
  } else {
#pragma unroll
    for (int ct = 0; ct < 4; ++ct) {
      const int col = col0 + wc + ct * 16 + l15;
      const float bv = bias ? bias[col] : 0.f;
#pragma unroll
      for (int rt = 0; rt < 4; ++rt) {
#pragma unroll
        for (int i = 0; i < 4; ++i) {
          const int row = row0 + wr + rt * 16 + quad * 4 + i;
          float v = acc[rt][ct][i] + bv;
          if constexpr (EPI == EPI_RELU_BIAS) {
            Cout[(long)row * ldc + col] = __float2bfloat16(v > 0.f ? v : 0.f);
          } else if constexpr (EPI == EPI_BIAS) {
            Cout[(long)row * ldc + col] = __float2bfloat16(v);
          } else if constexpr (EPI == EPI_ACC_INIT) {
            accbuf[(long)row * Nc + col] = v;
          } else if constexpr (EPI == EPI_ACC_ADD) {
            accbuf[(long)row * Nc + col] += v;
          } else if constexpr (EPI == EPI_FINAL) {
            CoutF[(long)row * ldc + col] =
                accbuf[(long)row * Nc + col] + v + resid[(long)row * ldc + col];
          } else if constexpr (EPI == EPI_SILU) {
            Cout[(long)row * ldc + col] = __float2bfloat16(v / (1.f + expf(-v)));
          } else {  // EPI_MUL
            const float g = __bfloat162float(gin[(long)row * ldc + col]);
            Cout[(long)row * ldc + col] = __float2bfloat16(v * g);
          }
        }
      }
    }
  }
}

// ---------------- 64x64-tile GEMM core: runtime shapes, 2-buf (806-proven) ----------------
// Best measured for N=256 GEMMs: 16 KB LDS -> ~8 blocks/CU, cross-block TLP.
template<int EPI>
__device__ __forceinline__
void gemm64_body(const bf16* __restrict__ A, int lda,
                 const bf16* __restrict__ Bt, int ldb,
                 const float* __restrict__ bias,
                 float* __restrict__ accbuf,
                 bf16* __restrict__ Cout, int ldc,
                 const float* __restrict__ resid,
                 float* __restrict__ CoutF,
                 int K, int Nc, int row0, int col0)
{
  __shared__ __align__(16) short As[2][64 * 32];
  __shared__ __align__(16) short Bs[2][64 * 32];

  const int tid  = threadIdx.x;
  const int lane = tid & 63;
  const int w    = tid >> 6;
  const int quad = lane >> 4;
  const int l15  = lane & 15;

  f32x4 acc[2][2];
  const f32x4 zero = {0.f, 0.f, 0.f, 0.f};
#pragma unroll
  for (int i = 0; i < 2; ++i)
#pragma unroll
    for (int j = 0; j < 2; ++j) acc[i][j] = zero;

  const int srow = (w << 4) + (lane >> 2);
  const int ss   = ((lane >> 2) & 3) ^ ((lane >> 4) & 1);
  const int sc   = ((lane & 3) ^ ss) << 3;
  const bf16* aG = A  + (long)(row0 + srow) * lda + sc;
  const bf16* bG = Bt + (long)(col0 + srow) * ldb + sc;
  const int ldsOff = w * 512;

  const int wr = (w >> 1) * 32;
  const int wc = (w & 1) * 32;
  const int fs = (l15 & 3) ^ ((l15 >> 2) & 1);

  gl_lds16(aG, As[0] + ldsOff);
  gl_lds16(bG, Bs[0] + ldsOff);
  __syncthreads();

  int cur = 0;
  for (int k0 = 0; k0 < K; k0 += 32) {
    const int nk = k0 + 32;
    if (nk < K) {
      gl_lds16(aG + nk, As[cur ^ 1] + ldsOff);
      gl_lds16(bG + nk, Bs[cur ^ 1] + ldsOff);
    }
    const short* Ac = As[cur];
    const short* Bc = Bs[cur];
    const int pc = (quad ^ fs) * 8;
    v8bf af[2], bfm[2];
#pragma unroll
    for (int i = 0; i < 2; ++i) {
      af[i]  = *(const v8bf*)&Ac[(wr + i * 16 + l15) * 32 + pc];
      bfm[i] = *(const v8bf*)&Bc[(wc + i * 16 + l15) * 32 + pc];
    }
#pragma unroll
    for (int i = 0; i < 2; ++i)
#pragma unroll
      for (int j = 0; j < 2; ++j)
        acc[i][j] = __builtin_amdgcn_mfma_f32_16x16x32_bf16(af[i], bfm[j], acc[i][j], 0, 0, 0);
    __syncthreads();
    cur ^= 1;
  }

#pragma unroll
  for (int ct = 0; ct < 2; ++ct) {
    const int col = col0 + wc + ct * 16 + l15;
    const float bv = bias ? bias[col] : 0.f;
#pragma unroll
    for (int rt = 0; rt < 2; ++rt) {
#pragma unroll
      for (int i = 0; i < 4; ++i) {
        const int row = row0 + wr + rt * 16 + quad * 4 + i;
        float v = acc[rt][ct][i] + bv;
        if constexpr (EPI == EPI_RELU_BIAS) {
          Cout[(long)row * ldc + col] = __float2bfloat16(v > 0.f ? v : 0.f);
        } else if constexpr (EPI == EPI_BIAS) {
          Cout[(long)row * ldc + col] = __float2bfloat16(v);
        } else if constexpr (EPI == EPI_ACC_INIT) {
          accbuf[(long)row * Nc + col] = v;
        } else if constexpr (EPI == EPI_ACC_ADD) {
          accbuf[(long)row * Nc + col] += v;
        } else if constexpr (EPI == EPI_FINAL) {
          CoutF[(long)row * Nc + col] =
              accbuf[(long)row * Nc + col] + v + resid[(long)row * Nc + col];
        }
      }
    }
  }
}

// 128-tile wrapper
template<int EPI>
__global__ __launch_bounds__(256)
void gemm_k(const bf16* __restrict__ A, int lda,
            const bf16* __restrict__ Bt, int ldb, long bTs,
            const float* __restrict__ bias, long biasTs,
            float* __restrict__ accbuf,
            bf16* __restrict__ Cout, int ldc,
            const float* __restrict__ resid,
            float* __restrict__ CoutF,
            const bf16* __restrict__ gin,
            int K, int Nc)
{
  const int row0 = blockIdx.x * 128;
  const int col0 = blockIdx.y * 128;
  const int t    = row0 >> 13;
  gemm_body<EPI>(A, lda, Bt + (long)t * bTs, ldb,
                 bias ? bias + (long)t * biasTs : nullptr,
                 accbuf, Cout, ldc, resid, CoutF, gin, K, Nc, row0, col0);
}

// 64-tile wrapper: grid (M/64, Nc/64)
template<int EPI>
__global__ __launch_bounds__(256)
void gemm64_k(const bf16* __restrict__ A, int lda,
              const bf16* __restrict__ Bt, int ldb, long bTs,
              const float* __restrict__ bias, long biasTs,
              float* __restrict__ accbuf,
              bf16* __restrict__ Cout, int ldc,
              const float* __restrict__ resid,
              float* __restrict__ CoutF,
              int K, int Nc)
{
  const int row0 = blockIdx.x * 64;
  const int col0 = blockIdx.y * 64;
  const int t    = row0 >> 13;
  gemm64_body<EPI>(A, lda, Bt + (long)t * bTs, ldb,
                   bias ? bias + (long)t * biasTs : nullptr,
                   accbuf, Cout, ldc, resid, CoutF, K, Nc, row0, col0);
}

// z-batched merged-W2 precompute (64-tile): W2'^T = outW_slice(j(b))^T @ w2_b^T
// b==0 (l2a) writes into the [256][1280] merged self+branch0 block (cols 256+).
__global__ __launch_bounds__(256)
void w2m_k(const bf16* __restrict__ outwT, const bf16* __restrict__ w2c,
           bf16* __restrict__ w2mg, bf16* __restrict__ w2m)
{
  const int z = blockIdx.z, b = z / 3, t = z % 3;
  const int j = (b == 0) ? 1 : (b == 1) ? 2 : 3;   // outW concat slice per branch
  bf16* dst;
  int ldc;
  if (b == 0) { dst = w2mg + (long)t * 327680 + 256; ldc = 1280; }
  else        { dst = w2m + (long)((b - 1) * 3 + t) * 262144; ldc = 1024; }
  gemm64_body<EPI_BIAS>(outwT + (long)t * 262144 + j * 256, 1024,
                        w2c + (long)b * 262144, 256,
                        nullptr, nullptr, dst, ldc,
                        nullptr, nullptr, 256, 1024,
                        blockIdx.x * 64, blockIdx.y * 64);
}

// copy outW j=0 slice into merged block cols 0-255: W2MG[t][col][k] = outWT[t][col][k]
__global__ __launch_bounds__(256)
void selfw_k(const bf16* __restrict__ outwT, bf16* __restrict__ w2mg)
{
  const int i = blockIdx.x * 256 + threadIdx.x;   // 196608 total
  const int t = i >> 16, rem = i & 65535;
  const int col = rem >> 8, k = rem & 255;
  w2mg[(long)t * 327680 + (long)col * 1280 + k] =
      outwT[(long)t * 262144 + (long)col * 1024 + k];
}

// ---------------- weight transpose+cast: src f32 [K,Nc] -> dst bf16 [Nc,K], batched z ----------------
__global__ __launch_bounds__(256)
void transpose_k(const float* __restrict__ src, bf16* __restrict__ dst,
                 int K, int Nc, long sB, long dB)
{
  __shared__ bf16 tile[32][33];
  const int b = blockIdx.z;
  const float* s = src + (long)b * sB;
  bf16* d = dst + (long)b * dB;
  const int kb = blockIdx.y * 32, nb = blockIdx.x * 32;
  const int tx = threadIdx.x & 31, ty = threadIdx.x >> 5;
#pragma unroll
  for (int i = 0; i < 32; i += 8)
    tile[ty + i][tx] = __float2bfloat16(s[(long)(kb + ty + i) * Nc + nb + tx]);
  __syncthreads();
#pragma unroll
  for (int i = 0; i < 32; i += 8)
    d[(long)(nb + ty + i) * K + kb + tx] = tile[tx][ty + i];
}

// ---------------- interleaved FFN w1/w3 transpose: dst bf16 [3][2048,256] ----------------
__global__ __launch_bounds__(256)
void transpose13_k(const float* __restrict__ w1, const float* __restrict__ w3,
                   bf16* __restrict__ dst)
{
  __shared__ bf16 tile[32][33];
  const int t  = blockIdx.z;
  const int n0 = blockIdx.x * 32;
  const int k0 = blockIdx.y * 32;
  const int gi = n0 >> 5;
  const int tx = threadIdx.x & 31, ty = threadIdx.x >> 5;
  const float* src = ((tx & 16) ? w3 : w1) + (long)t * 262144;
  const int c = 16 * gi + (tx & 15);
#pragma unroll
  for (int i = 0; i < 32; i += 8)
    tile[ty + i][tx] = __float2bfloat16(src[(long)(k0 + ty + i) * 1024 + c]);
  __syncthreads();
#pragma unroll
  for (int i = 0; i < 32; i += 8)
    dst[((long)t * 2048 + n0 + ty + i) * 256 + k0 + tx] = tile[tx][ty + i];
}

// ---------------- LN-folded w1: dst[b] (bf16 [1024,512]) from w1 f32 [Kin,1024] ----------------
struct FoldP { const float* w1[5]; const float* ls[5]; };
__global__ __launch_bounds__(256)
void fold_w1_k(FoldP p, bf16* __restrict__ dst)
{
  __shared__ float tile[32][33];
  const int z = blockIdx.z;
  const float* w1 = p.w1[z];
  const float* ls = p.ls[z];
  bf16* d = dst + (long)z * 524288;
  const int n0 = blockIdx.x * 32, i0 = blockIdx.y * 32;
  const int tx = threadIdx.x & 31, ty = threadIdx.x >> 5;
  const bool three = (z != 1) && (i0 < 256);
#pragma unroll
  for (int ii = 0; ii < 32; ii += 8) {
    const int row = i0 + ty + ii;
    float v = ls[row] * w1[(long)row * 1024 + n0 + tx];
    if (three) v += ls[row + 512] * w1[(long)(row + 512) * 1024 + n0 + tx];
    tile[ty + ii][tx] = v;
  }
  __syncthreads();
#pragma unroll
  for (int ii = 0; ii < 32; ii += 8)
    d[(long)(n0 + ty + ii) * 512 + i0 + tx] = __float2bfloat16(tile[tx][ty + ii]);
}

// ---------------- bias-fold precompute (parallelized) ----------------
struct BInitP { const float* b1[5]; const float* fb1; const float* fb3; };
__global__ __launch_bounds__(256)
void binit_k(BInitP p, float* __restrict__ B1F,
             const float* __restrict__ out_b, float* __restrict__ TB,
             float* __restrict__ B13)
{
  const int i = blockIdx.x * 256 + threadIdx.x;
  if (i < 5120) {
    B1F[i] = p.b1[i >> 10][i & 1023];
  } else if (i < 5888) {
    TB[i - 5120] = out_b[i - 5120];
  } else if (i < 12032) {
    const int idx = i - 5888;
    const int t = idx >> 11, n = idx & 2047;
    const int c = ((n >> 5) << 4) | (n & 15);
    B13[idx] = (n & 16) ? p.fb3[t * 1024 + c] : p.fb1[t * 1024 + c];
  }
}

// B1F[z][n] += sum_k lb[k]*w1[k,n]; grid (z=5, ksplit=32)
struct B1P { const float* w1[5]; const float* lb[5]; int kin[5]; };
__global__ __launch_bounds__(256)
void b1f_add_k(B1P p, float* __restrict__ dst)
{
  const int z   = blockIdx.x;
  const int kin = p.kin[z];
  const int kpb = (kin + 31) >> 5;
  const int k0  = blockIdx.y * kpb;
  const int k1  = min(k0 + kpb, kin);
  const float* w1 = p.w1[z];
  const float* lb = p.lb[z];
  const int n = threadIdx.x;
  float a0 = 0.f, a1 = 0.f, a2 = 0.f, a3 = 0.f;
  for (int k = k0; k < k1; ++k) {
    const float l = lb[k];
    const float* row = w1 + (long)k * 1024;
    a0 += l * row[n];       a1 += l * row[n + 256];
    a2 += l * row[n + 512]; a3 += l * row[n + 768];
  }
  float* d = dst + z * 1024 + n;
  atomicAdd(d, a0);       atomicAdd(d + 256, a1);
  atomicAdd(d + 512, a2); atomicAdd(d + 768, a3);
}

// TB[t][h] += b2-vectors through outW slices; grid (t=3, csplit=8)
__global__ __launch_bounds__(256)
void tbias_add_k(const float* __restrict__ outW,
                 const float* __restrict__ l2a_b2, const float* __restrict__ g2a_b2,
                 const float* __restrict__ oth_b2, float* __restrict__ dst)
{
  const int t = blockIdx.x, h = threadIdx.x;
  const float* W = outW + (long)t * 262144;
  const int c0 = blockIdx.y * 32;
  float acc = 0.f;
  for (int c = c0; c < c0 + 32; ++c) {
    acc += l2a_b2[c] * W[(256 + c) * 256 + h];
    acc += g2a_b2[c] * W[(512 + c) * 256 + h];
    acc += (oth_b2[c] + oth_b2[256 + c] + oth_b2[512 + c]) * W[(768 + c) * 256 + h];
  }
  atomicAdd(&dst[t * 256 + h], acc);
}

// ---------------- f32 -> bf16 cast, 4 elems/thread ----------------
__global__ __launch_bounds__(256)
void cast_k(const float* __restrict__ src, bf16* __restrict__ dst)
{
  const long i = (long)blockIdx.x * 256 + threadIdx.x;
  const float4 v = ((const float4*)src)[i];
  ((bf4*)dst)[i] = mk4(v.x, v.y, v.z, v.w);
}

// ---------------- wave-wide reduce (all lanes get totals) ----------------
__device__ __forceinline__ void wave_reduce2(float& s, float& q) {
#pragma unroll
  for (int off = 32; off > 0; off >>= 1) {
    s += __shfl_xor(s, off, 64);
    q += __shfl_xor(q, off, 64);
  }
}

// ---------------- normalized-only LN: writes [fn, xn] (512 bf16) ----------------
template<int THREE>
__global__ __launch_bounds__(256)
void ln_norm_k(const float* __restrict__ feat, const float* __restrict__ x,
               const int* __restrict__ srcIdx, bf16* __restrict__ out)
{
  const int w = threadIdx.x >> 6, lane = threadIdx.x & 63;
  const int r = blockIdx.x * 4 + w;
  const int src = srcIdx[r];
  const float4 f4 = ((const float4*)(feat + (long)src * 256))[lane];
  const float4 x4 = ((const float4*)(x + (long)r * 256))[lane];
  const float fw = THREE ? 2.f : 1.f;
  float s = fw * (f4.x + f4.y + f4.z + f4.w) + (x4.x + x4.y + x4.z + x4.w);
  float q = fw * (f4.x * f4.x + f4.y * f4.y + f4.z * f4.z + f4.w * f4.w) +
            (x4.x * x4.x + x4.y * x4.y + x4.z * x4.z + x4.w * x4.w);
  wave_reduce2(s, q);
  const float rD  = THREE ? (1.f / 768.f) : (1.f / 512.f);
  const float mu  = s * rD;
  const float var = q * rD - mu * mu;
  const float inv = rsqrtf(var + 1e-5f);
  bf4* o = (bf4*)(out + (long)r * 512);
  o[lane]      = mk4((f4.x - mu) * inv, (f4.y - mu) * inv,
                     (f4.z - mu) * inv, (f4.w - mu) * inv);
  o[64 + lane] = mk4((x4.x - mu) * inv, (x4.y - mu) * inv,
                     (x4.z - mu) * inv, (x4.w - mu) * inv);
}

// ---------------- legacy LN kernels (Tier C path) ----------------
__global__ __launch_bounds__(256)
void ln_cat3_k(const float* __restrict__ feat, const float* __restrict__ x,
               const int* __restrict__ srcIdx,
               const float* __restrict__ ls, const float* __restrict__ lb,
               bf16* __restrict__ out)
{
  const int w = threadIdx.x >> 6, lane = threadIdx.x & 63;
  const int r = blockIdx.x * 4 + w;
  const int src = srcIdx[r];
  const float4 f4 = ((const float4*)(feat + (long)src * 256))[lane];
  const float4 x4 = ((const float4*)(x + (long)r * 256))[lane];
  float s = 2.f * (f4.x + f4.y + f4.z + f4.w) + (x4.x + x4.y + x4.z + x4.w);
  float q = 2.f * (f4.x * f4.x + f4.y * f4.y + f4.z * f4.z + f4.w * f4.w) +
            (x4.x * x4.x + x4.y * x4.y + x4.z * x4.z + x4.w * x4.w);
  wave_reduce2(s, q);
  const float mu  = s * (1.f / 768.f);
  const float var = q * (1.f / 768.f) - mu * mu;
  const float inv = rsqrtf(var + 1e-5f);
  const float4 s0 = ((const float4*)ls)[lane],         b0 = ((const float4*)lb)[lane];
  const float4 s1 = ((const float4*)(ls + 256))[lane], b1 = ((const float4*)(lb + 256))[lane];
  const float4 s2 = ((const float4*)(ls + 512))[lane], b2 = ((const float4*)(lb + 512))[lane];
  bf4* o = (bf4*)(out + (long)r * 768);
  o[lane] = mk4((f4.x - mu) * inv * s0.x + b0.x, (f4.y - mu) * inv * s0.y + b0.y,
                (f4.z - mu) * inv * s0.z + b0.z, (f4.w - mu) * inv * s0.w + b0.w);
  o[64 + lane] = mk4((x4.x - mu) * inv * s1.x + b1.x, (x4.y - mu) * inv * s1.y + b1.y,
                     (x4.z - mu) * inv * s1.z + b1.z, (x4.w - mu) * inv * s1.w + b1.w);
  o[128 + lane] = mk4((f4.x - mu) * inv * s2.x + b2.x, (f4.y - mu) * inv * s2.y + b2.y,
                      (f4.z - mu) * inv * s2.z + b2.z, (f4.w - mu) * inv * s2.w + b2.w);
}

__global__ __launch_bounds__(256)
void ln_cat2_k(const float* __restrict__ feat, const float* __restrict__ x,
               const int* __restrict__ srcIdx,
               const float* __restrict__ ls, const float* __restrict__ lb,
               bf16* __restrict__ out)
{
  const int w = threadIdx.x >> 6, lane = threadIdx.x & 63;
  const int r = blockIdx.x * 4 + w;
  const int src = srcIdx[r];
  const float4 f4 = ((const float4*)(feat + (long)src * 256))[lane];
  const float4 x4 = ((const float4*)(x + (long)r * 256))[lane];
  float s = (f4.x + f4.y + f4.z + f4.w) + (x4.x + x4.y + x4.z + x4.w);
  float q = (f4.x * f4.x + f4.y * f4.y + f4.z * f4.z + f4.w * f4.w) +
            (x4.x * x4.x + x4.y * x4.y + x4.z * x4.z + x4.w * x4.w);
  wave_reduce2(s, q);
  const float mu  = s * (1.f / 512.f);
  const float var = q * (1.f / 512.f) - mu * mu;
  const float inv = rsqrtf(var + 1e-5f);
  const float4 s0 = ((const float4*)ls)[lane],         b0 = ((const float4*)lb)[lane];
  const float4 s1 = ((const float4*)(ls + 256))[lane], b1 = ((const float4*)(lb + 256))[lane];
  bf4* o = (bf4*)(out + (long)r * 512);
  o[lane] = mk4((f4.x - mu) * inv * s0.x + b0.x, (f4.y - mu) * inv * s0.y + b0.y,
                (f4.z - mu) * inv * s0.z + b0.z, (f4.w - mu) * inv * s0.w + b0.w);
  o[64 + lane] = mk4((x4.x - mu) * inv * s1.x + b1.x, (x4.y - mu) * inv * s1.y + b1.y,
                     (x4.z - mu) * inv * s1.z + b1.z, (x4.w - mu) * inv * s1.w + b1.w);
}

// ---------------- FFN layernorm width 256: f32 in, bf16 out; one wave per row ----------------
// ldy = output row stride (elements) so y can live inside the merged [.,1280] region.
__global__ __launch_bounds__(256)
void ln_ffn_k(const float* __restrict__ ob, const float* __restrict__ ls,
              const float* __restrict__ lb, bf16* __restrict__ y,
              long lsStride, int ldy)
{
  const int w = threadIdx.x >> 6, lane = threadIdx.x & 63;
  const int r = blockIdx.x * 4 + w;
  const long po = (long)(r >> 13) * lsStride;
  const float4 v4 = ((const float4*)(ob + (long)r * 256))[lane];
  float s = v4.x + v4.y + v4.z + v4.w;
  float q = v4.x * v4.x + v4.y * v4.y + v4.z * v4.z + v4.w * v4.w;
  wave_reduce2(s, q);
  const float mu  = s * (1.f / 256.f);
  const float var = q * (1.f / 256.f) - mu * mu;
  const float inv = rsqrtf(var + 1e-5f);
  const float4 s0 = ((const float4*)(ls + po))[lane];
  const float4 b0 = ((const float4*)(lb + po))[lane];
  ((bf4*)(y + (long)r * ldy))[lane] =
      mk4((v4.x - mu) * inv * s0.x + b0.x, (v4.y - mu) * inv * s0.y + b0.y,
          (v4.z - mu) * inv * s0.z + b0.z, (v4.w - mu) * inv * s0.w + b0.w);
}

// ---------------- g = silu(g) * u, 4 elems/thread (Tier C path) ----------------
__global__ __launch_bounds__(256)
void silu_mul_k(bf16* __restrict__ g, const bf16* __restrict__ u)
{
  const long i = (long)blockIdx.x * 256 + threadIdx.x;
  const bf4 g4 = ((const bf4*)g)[i];
  const bf4 u4 = ((const bf4*)u)[i];
  float a = __bfloat162float(g4.x), b = __bfloat162float(g4.y);
  float c = __bfloat162float(g4.z), d = __bfloat162float(g4.w);
  a = a / (1.f + expf(-a)) * __bfloat162float(u4.x);
  b = b / (1.f + expf(-b)) * __bfloat162float(u4.y);
  c = c / (1.f + expf(-c)) * __bfloat162float(u4.z);
  d = d / (1.f + expf(-d)) * __bfloat162float(u4.w);
  ((bf4*)g)[i] = mk4(a, b, c, d);
}

// ---------------- sentinel fill (diagnostic) ----------------
__global__ __launch_bounds__(256)
void fill_k(float* __restrict__ p, int n)
{
  const int i = blockIdx.x * 256 + threadIdx.x;
  if (i < n) p[i] = 2.0f;
}

// ---------------- host ----------------
extern "C" void kernel_launch(void* const* d_in, const int* in_sizes, int n_in,
                              void* d_out, int out_size, void* d_ws, size_t ws_size,
                              hipStream_t stream)
{
  const float* agent_x  = (const float*)d_in[0];
  const float* lane_x   = (const float*)d_in[1];
  const float* poly_x   = (const float*)d_in[2];
  const int*   l2a_src  = (const int*)d_in[3];
  const int*   g2a_src  = (const int*)d_in[4];
  const int*   other_src= (const int*)d_in[5];
  const float* self_W   = (const float*)d_in[6];
  const float* self_b   = (const float*)d_in[7];
  const float* out_W    = (const float*)d_in[8];
  const float* out_b    = (const float*)d_in[9];
  const float* ffn_ln_s = (const float*)d_in[10];
  const float* ffn_ln_b = (const float*)d_in[11];
  const float* ffn_w1   = (const float*)d_in[12];
  const float* ffn_b1   = (const float*)d_in[13];
  const float* ffn_w2   = (const float*)d_in[14];
  const float* ffn_b2   = (const float*)d_in[15];
  const float* ffn_w3   = (const float*)d_in[16];
  const float* ffn_b3   = (const float*)d_in[17];
  const float* l2a_ln_s = (const float*)d_in[18];
  const float* l2a_ln_b = (const float*)d_in[19];
  const float* l2a_w1   = (const float*)d_in[20];
  const float* l2a_b1   = (const float*)d_in[21];
  const float* l2a_w2   = (const float*)d_in[22];
  const float* l2a_b2   = (const float*)d_in[23];
  const float* g2a_ln_s = (const float*)d_in[24];
  const float* g2a_ln_b = (const float*)d_in[25];
  const float* g2a_w1   = (const float*)d_in[26];
  const float* g2a_b1   = (const float*)d_in[27];
  const float* g2a_w2   = (const float*)d_in[28];
  const float* g2a_b2   = (const float*)d_in[29];
  const float* oth_ln_s = (const float*)d_in[30];
  const float* oth_ln_b = (const float*)d_in[31];
  const float* oth_w1   = (const float*)d_in[32];
  const float* oth_b1   = (const float*)d_in[33];
  const float* oth_w2   = (const float*)d_in[34];
  const float* oth_b2   = (const float*)d_in[35];

  float* outp = (float*)d_out;
  const dim3 B256(256);

  const size_t TIER_A = 136108032;  // merged-M layout (fits proven 155 MB grant)
  const size_t TIER_C = 12058624;   // chunked fallback

  if (ws_size >= TIER_A) {
    // ===== Tier A (806-proven bodies): 128-tile runtime 2-buf wide-N, 64-tile
    // ===== runtime 2-buf N=256; NEW: self+branch0 K=1280 merged accumulation.
    char* base = (char*)d_ws;
    bf16* wT = (bf16*)base;
    // elem offsets within weight block
    const long SELF_WT = 0,       OUT_WT  = 196608,  FFN_W13T = 983040;
    const long FFN_W2T = 2555904, W2C = 3342336,     W1F      = 4653056;
    const long W2MG = 7274496;    // [3][256][1280] merged self+branch0 Bt
    const long W2M  = 8257536;    // [4][3][256][1024] branches 1-4
    float* B1F  = (float*)(base + 22806528L);   // [5][1024] folded w1 bias
    float* TB   = (float*)(base + 22827008L);   // [3][256]  fused out-bias
    float* B13  = (float*)(base + 22830080L);   // [3][2048] interleaved ffn bias
    bf16*  nbuf = (bf16*)(base + 22854656L);    // [N,512]  LN output / xbf scratch
    bf16*  M    = (bf16*)(base + 48020480L);    // [N,1280]: cols 0-255 self/y, 256-1279 h1/g*u
    float* oF   = (float*)(base + 110935040L);  // [N,256]  branch accumulator
    bf16*  xbf  = nbuf;  // bf16 cast of agent_x (nbuf dead until first ln_norm)

    // ---- weight precompute ----
    auto TRB = [&](const float* s, long dOff, int K, int Nc, long sB, long dB, int b) {
      transpose_k<<<dim3(Nc / 32, K / 32, b), B256, 0, stream>>>(s, wT + dOff, K, Nc, sB, dB);
    };
    TRB(self_W, SELF_WT, 256, 256,  65536, 65536, 3);
    TRB(out_W,  OUT_WT,  1024, 256, 262144, 262144, 3);
    TRB(ffn_w2, FFN_W2T, 1024, 256, 262144, 262144, 3);
    transpose13_k<<<dim3(64, 8, 3), B256, 0, stream>>>(ffn_w1, ffn_w3, wT + FFN_W13T);
    cast_k<<<256, B256, 0, stream>>>(l2a_w2, wT + W2C);
    cast_k<<<256, B256, 0, stream>>>(g2a_w2, wT + W2C + 262144);
    cast_k<<<768, B256, 0, stream>>>(oth_w2, wT + W2C + 524288);

    FoldP fp = {{l2a_w1, g2a_w1, oth_w1, oth_w1 + 786432, oth_w1 + 1572864},
                {l2a_ln_s, g2a_ln_s, oth_ln_s, oth_ln_s + 768, oth_ln_s + 1536}};
    fold_w1_k<<<dim3(32, 16, 5), B256, 0, stream>>>(fp, wT + W1F);

    BInitP ip = {{l2a_b1, g2a_b1, oth_b1, oth_b1 + 1024, oth_b1 + 2048}, ffn_b1, ffn_b3};
    binit_k<<<47, B256, 0, stream>>>(ip, B1F, out_b, TB, B13);
    B1P bp = {{l2a_w1, g2a_w1, oth_w1, oth_w1 + 786432, oth_w1 + 1572864},
              {l2a_ln_b, g2a_ln_b, oth_ln_b, oth_ln_b + 768, oth_ln_b + 1536},
              {768, 512, 768, 768, 768}};
    b1f_add_k<<<dim3(5, 32), B256, 0, stream>>>(bp, B1F);
    tbias_add_k<<<dim3(3, 8), B256, 0, stream>>>(out_W, l2a_b2, g2a_b2, oth_b2, TB);
    selfw_k<<<768, B256, 0, stream>>>(wT + OUT_WT, wT + W2MG);
    w2m_k<<<dim3(4, 16, 15), B256, 0, stream>>>(wT + OUT_WT, wT + W2C,
                                                wT + W2MG, wT + W2M);

    const dim3 G64n2(N_AG / 64, 4);     // N=256 GEMMs (64-tile): 1536 blocks
    const dim3 Gw1(N_AG / 128, 8);      // w1' (128-tile): 1536 blocks
    const dim3 Gglu(N_AG / 128, 16);    // GLU (128-tile): 3072 blocks

    // ---- self branch: relu output into M cols 0-255 (ldc 1280) ----
    cast_k<<<N_AG / 4, B256, 0, stream>>>(agent_x, xbf);
    gemm64_k<EPI_RELU_BIAS><<<G64n2, B256, 0, stream>>>(
        xbf, 256, wT + SELF_WT, 256, 65536, self_b, 256,
        nullptr, M, 1280, nullptr, nullptr, 256, 256);

    // ---- edge branches: LN -> w1' (128-tile, writes M cols 256+) -> ACC ----
    for (int b = 0; b < 5; ++b) {
      const int* src = (b == 0) ? l2a_src : (b == 1) ? g2a_src
                                          : other_src + (long)(b - 2) * N_AG;
      const float* feat = (b == 0) ? lane_x : (b == 1) ? poly_x : agent_x;
      if (b == 1) ln_norm_k<0><<<N_AG / 4, B256, 0, stream>>>(feat, agent_x, src, nbuf);
      else        ln_norm_k<1><<<N_AG / 4, B256, 0, stream>>>(feat, agent_x, src, nbuf);
      gemm_k<EPI_RELU_BIAS><<<Gw1, B256, 0, stream>>>(
          nbuf, 512, wT + W1F + (long)b * 524288, 512, 0, B1F + b * 1024, 0,
          nullptr, M + 256, 1280, nullptr, nullptr, nullptr, 512, 1024);
      if (b == 0) {
        // merged self+branch0 accumulation, K=1280 (bias TB carries all folded b2's)
        gemm64_k<EPI_ACC_INIT><<<G64n2, B256, 0, stream>>>(
            M, 1280, wT + W2MG, 1280, 327680, TB, 256,
            oF, nullptr, 0, nullptr, nullptr, 1280, 256);
      } else {
        gemm64_k<EPI_ACC_ADD><<<G64n2, B256, 0, stream>>>(
            M + 256, 1280, wT + W2M + (long)(b - 1) * 786432, 1024, 262144,
            nullptr, 0, oF, nullptr, 0, nullptr, nullptr, 1024, 256);
      }
    }

    // ---- FFN: y into M cols 0-255; GLU writes g*u into cols 256-1279; FINAL ----
    ln_ffn_k<<<N_AG / 4, B256, 0, stream>>>(oF, ffn_ln_s, ffn_ln_b, M, 256, 1280);
    gemm_k<EPI_GLU><<<Gglu, B256, 0, stream>>>(
        M, 1280, wT + FFN_W13T, 256, 524288, B13, 2048,
        nullptr, M + 256, 1280, nullptr, nullptr, nullptr, 256, 2048);
    gemm64_k<EPI_FINAL><<<G64n2, B256, 0, stream>>>(
        M + 256, 1280, wT + FFN_W2T, 1024, 262144, ffn_b2, 256,
        oF, nullptr, 0, agent_x, outp, 1024, 256);
    return;
  }

  if (ws_size < TIER_C) {
    fill_k<<<(out_size + 255) / 256, B256, 0, stream>>>(outp, out_size);
    return;
  }

  // ================= Tier C: chunked path (11.5 MiB) =================
  const int CH = 2048;
  char* base = (char*)d_ws;
  bf16*  wt     = (bf16*)base;
  bf16*  nbuf   = (bf16*)(base + 1572864L);
  bf16*  bbuf   = (bf16*)(base + 4718592L);
  bf16*  h1     = (bf16*)(base + 5767168L);
  float* outF32 = (float*)(base + 9961472L);
  bf16*  ybuf   = (bf16*)(base + 524288L);
  bf16*  xbf    = h1;
  bf16*  g_pre  = h1;
  bf16*  u_pre  = nbuf;

  const dim3 Gw1(CH / 128, 8), Gw2(CH / 128, 2);
  auto TR = [&](const float* s, int K, int Nc) {
    transpose_k<<<dim3(Nc / 32, K / 32), B256, 0, stream>>>(s, wt, K, Nc, 0, 0);
  };

  for (int t = 0; t < 3; ++t) {
    for (int c = 0; c < N3 / CH; ++c) {
      const long r0 = (long)t * N3 + (long)c * CH;
      const float* xC   = agent_x + r0 * 256;
      float*       outC = outp + r0 * 256;

      cast_k<<<CH / 4, B256, 0, stream>>>(xC, xbf);
      TR(self_W + (long)t * 65536, 256, 256);
      gemm_k<EPI_RELU_BIAS><<<Gw2, B256, 0, stream>>>(
          xbf, 256, wt, 256, 0, self_b + t * 256, 0, nullptr, bbuf, 256,
          nullptr, nullptr, nullptr, 256, 256);
      TR(out_W + (long)t * 262144 + 0 * 65536, 256, 256);
      gemm_k<EPI_ACC_INIT><<<Gw2, B256, 0, stream>>>(
          bbuf, 256, wt, 256, 0, out_b + t * 256, 0, outF32, nullptr, 0,
          nullptr, nullptr, nullptr, 256, 256);

      ln_cat3_k<<<CH / 4, B256, 0, stream>>>(lane_x, xC, l2a_src + r0,
                                             l2a_ln_s, l2a_ln_b, nbuf);
      TR(l2a_w1, 768, 1024);
      gemm_k<EPI_RELU_BIAS><<<Gw1, B256, 0, stream>>>(
          nbuf, 768, wt, 768, 0, l2a_b1, 0, nullptr, h1, 1024,
          nullptr, nullptr, nullptr, 768, 1024);
      TR(l2a_w2, 1024, 256);
      gemm_k<EPI_BIAS><<<Gw2, B256, 0, stream>>>(
          h1, 1024, wt, 1024, 0, l2a_b2, 0, nullptr, bbuf, 256,
          nullptr, nullptr, nullptr, 1024, 256);
      TR(out_W + (long)t * 262144 + 1 * 65536, 256, 256);
      gemm_k<EPI_ACC_ADD><<<Gw2, B256, 0, stream>>>(
          bbuf, 256, wt, 256, 0, nullptr, 0, outF32, nullptr, 0,
          nullptr, nullptr, nullptr, 256, 256);

      ln_cat2_k<<<CH / 4, B256, 0, stream>>>(poly_x, xC, g2a_src + r0,
                                             g2a_ln_s, g2a_ln_b, nbuf);
      TR(g2a_w1, 512, 1024);
      gemm_k<EPI_RELU_BIAS><<<Gw1, B256, 0, stream>>>(
          nbuf, 512, wt, 512, 0, g2a_b1, 0, nullptr, h1, 1024,
          nullptr, nullptr, nullptr, 512, 1024);
      TR(g2a_w2, 1024, 256);
      gemm_k<EPI_BIAS><<<Gw2, B256, 0, stream>>>(
          h1, 1024, wt, 1024, 0, g2a_b2, 0, nullptr, bbuf, 256,
          nullptr, nullptr, nullptr, 1024, 256);
      TR(out_W + (long)t * 262144 + 2 * 65536, 256, 256);
      gemm_k<EPI_ACC_ADD><<<Gw2, B256, 0, stream>>>(
          bbuf, 256, wt, 256, 0, nullptr, 0, outF32, nullptr, 0,
          nullptr, nullptr, nullptr, 256, 256);

      for (int s = 0; s < 3; ++s) {
        ln_cat3_k<<<CH / 4, B256, 0, stream>>>(
            agent_x, xC, other_src + (long)s * N_AG + r0,
            oth_ln_s + s * 768, oth_ln_b + s * 768, nbuf);
        TR(oth_w1 + (long)s * 786432, 768, 1024);
        gemm_k<EPI_RELU_BIAS><<<Gw1, B256, 0, stream>>>(
            nbuf, 768, wt, 768, 0, oth_b1 + s * 1024, 0, nullptr, h1, 1024,
            nullptr, nullptr, nullptr, 768, 1024);
        TR(oth_w2 + (long)s * 262144, 1024, 256);
        gemm_k<EPI_BIAS><<<Gw2, B256, 0, stream>>>(
            h1, 1024, wt, 1024, 0, oth_b2 + s * 256, 0, nullptr, bbuf, 256,
            nullptr, nullptr, nullptr, 1024, 256);
        TR(out_W + (long)t * 262144 + 3 * 65536, 256, 256);
        gemm_k<EPI_ACC_ADD><<<Gw2, B256, 0, stream>>>(
            bbuf, 256, wt, 256, 0, nullptr, 0, outF32, nullptr, 0,
            nullptr, nullptr, nullptr, 256, 256);
      }

      ln_ffn_k<<<CH / 4, B256, 0, stream>>>(outF32, ffn_ln_s + t * 256,
                                            ffn_ln_b + t * 256, ybuf, 0, 256);
      TR(ffn_w1 + (long)t * 262144, 256, 1024);
      gemm_k<EPI_BIAS><<<Gw1, B256, 0, stream>>>(
          ybuf, 256, wt, 256, 0, ffn_b1 + t * 1024, 0, nullptr, g_pre, 1024,
          nullptr, nullptr, nullptr, 256, 1024);
      TR(ffn_w3 + (long)t * 262144, 256, 1024);
      gemm_k<EPI_BIAS><<<Gw1, B256, 0, stream>>>(
          ybuf, 256, wt, 256, 0, ffn_b3 + t * 1024, 0, nullptr, u_pre, 1024,
          nullptr, nullptr, nullptr, 256, 1024);
      silu_mul_k<<<CH, B256, 0, stream>>>(g_pre, u_pre);
      TR(ffn_w2 + (long)t * 262144, 1024, 256);
      gemm_k<EPI_FINAL><<<Gw2, B256, 0, stream>>>(
          g_pre, 1024, wt, 1024, 0, ffn_b2 + t * 256, 0, outF32, nullptr, 256,
          xC, outC, nullptr, 1024, 256);
    }
  }
}

// Round 11
// 811.659 us; speedup vs baseline: 1.1685x; 1.0103x over previous
//
#include <hip/hip_runtime.h>
#include <hip/hip_bf16.h>

typedef __hip_bfloat16 bf16;
typedef __bf16 v8bf __attribute__((ext_vector_type(8)));
typedef float f32x4 __attribute__((ext_vector_type(4)));

#define N_AG 24576
#define N3 8192

struct __align__(8) bf4 { bf16 x, y, z, w; };
__device__ __forceinline__ bf4 mk4(float a, float b, float c, float d) {
  bf4 r{__float2bfloat16(a), __float2bfloat16(b), __float2bfloat16(c), __float2bfloat16(d)};
  return r;
}

// ---------------- epilogue modes ----------------
enum {
  EPI_RELU_BIAS = 0,  // Cout(bf16) = relu(v + bias)
  EPI_BIAS      = 1,  // Cout(bf16) = v + bias
  EPI_ACC_INIT  = 2,  // accbuf(f32) = v + bias
  EPI_ACC_ADD   = 3,  // accbuf(f32) += v + bias
  EPI_FINAL     = 4,  // CoutF(f32) = accbuf + v + bias + resid
  EPI_SILU      = 5,  // Cout(bf16) = silu(v + bias)
  EPI_MUL       = 6,  // Cout(bf16) = (v + bias) * gin[idx]
  EPI_GLU       = 7   // interleaved g/u tiles: Cout(bf16) = silu(g+bg) * (u+bu)
};

// async 16B/lane global->LDS DMA; LDS dest = wave-uniform base + lane*16
__device__ __forceinline__ void gl_lds16(const bf16* g, short* l) {
  __builtin_amdgcn_global_load_lds(
      (const __attribute__((address_space(1))) unsigned int*)g,
      (__attribute__((address_space(3))) unsigned int*)l, 16, 0, 0);
}

// ---------------- 128-tile GEMM core: runtime shapes, 2-buf ----------------
// R10: register-trimmed (single live B-fragment; pairs with __launch_bounds__
// (256,4) on wrappers -> <=128 regs/wave -> 4 blocks/CU vs previous ~2; the
// occupancy cap (acc 64 + frags) was the binding constraint across R2-R9:
// every schedule variant pinned at Occ 26% / 54us.
template<int EPI>
__device__ __forceinline__
void gemm_body(const bf16* __restrict__ A, int lda,
               const bf16* __restrict__ Bt, int ldb,
               const float* __restrict__ bias,
               float* __restrict__ accbuf,
               bf16* __restrict__ Cout, int ldc,
               const float* __restrict__ resid,
               float* __restrict__ CoutF,
               const bf16* __restrict__ gin,
               int K, int Nc, int row0, int col0)
{
  __shared__ __align__(16) short As[2][128 * 32];
  __shared__ __align__(16) short Bs[2][128 * 32];

  const int tid  = threadIdx.x;
  const int lane = tid & 63;
  const int w    = tid >> 6;
  const int quad = lane >> 4;
  const int l15  = lane & 15;

  f32x4 acc[4][4];
  const f32x4 zero = {0.f, 0.f, 0.f, 0.f};
#pragma unroll
  for (int i = 0; i < 4; ++i)
#pragma unroll
    for (int j = 0; j < 4; ++j) acc[i][j] = zero;

  // staging: wave w rows [w*32, w*32+32); lane i -> (row i>>2, phys chunk i&3)
  const int srow = (w << 5) + (lane >> 2);
  const int ss   = ((lane >> 2) & 3) ^ ((lane >> 4) & 1);   // s(srow), same for srow+16
  const int sc   = ((lane & 3) ^ ss) << 3;                  // global elem offset fetched
  const bf16* aG = A  + (long)(row0 + srow) * lda + sc;
  const bf16* bG = Bt + (long)(col0 + srow) * ldb + sc;
  const int ldsOff = w * 1024;

  const int wr = (w >> 1) * 64;
  const int wc = (w & 1) * 64;
  const int fs = (l15 & 3) ^ ((l15 >> 2) & 1);   // frag-read swizzle

  gl_lds16(aG,                  As[0] + ldsOff);
  gl_lds16(aG + (long)16 * lda, As[0] + ldsOff + 512);
  gl_lds16(bG,                  Bs[0] + ldsOff);
  gl_lds16(bG + (long)16 * ldb, Bs[0] + ldsOff + 512);
  __syncthreads();

  int cur = 0;
  for (int k0 = 0; k0 < K; k0 += 32) {
    const int nk = k0 + 32;
    if (nk < K) {
      short* An = As[cur ^ 1] + ldsOff;
      short* Bn = Bs[cur ^ 1] + ldsOff;
      gl_lds16(aG + nk,                  An);
      gl_lds16(aG + nk + (long)16 * lda, An + 512);
      gl_lds16(bG + nk,                  Bn);
      gl_lds16(bG + nk + (long)16 * ldb, Bn + 512);
    }
    const short* Ac = As[cur];
    const short* Bc = Bs[cur];
    const int pc = (quad ^ fs) * 8;
    v8bf af[4];
#pragma unroll
    for (int i = 0; i < 4; ++i)
      af[i] = *(const v8bf*)&Ac[(wr + i * 16 + l15) * 32 + pc];
#pragma unroll
    for (int j = 0; j < 4; ++j) {
      const v8bf bj = *(const v8bf*)&Bc[(wc + j * 16 + l15) * 32 + pc];
#pragma unroll
      for (int i = 0; i < 4; ++i)
        acc[i][j] = __builtin_amdgcn_mfma_f32_16x16x32_bf16(af[i], bj, acc[i][j], 0, 0, 0);
    }
    __syncthreads();
    cur ^= 1;
  }

  if constexpr (EPI == EPI_GLU) {
    // interleaved layout: 32-col blocks = [16 g-cols | 16 u-cols] of same h-cols.
#pragma unroll
    for (int ct = 0; ct < 4; ct += 2) {
      const int colg = col0 + wc + ct * 16 + l15;
      const int hcol = ((colg >> 5) << 4) + (colg & 15);
      const float bg = bias[colg];
      const float bu = bias[colg + 16];
#pragma unroll
      for (int rt = 0; rt < 4; ++rt) {
#pragma unroll
        for (int i = 0; i < 4; ++i) {
          const int row = row0 + wr + rt * 16 + quad * 4 + i;
          const float vg = acc[rt][ct][i] + bg;
          const float vu = acc[rt][ct + 1][i] + bu;
          Cout[(long)row * ldc + hcol] =
              __float2bfloat16(vg / (1.f + expf(-vg)) * vu);
        }
      }
    }
  } else {
#pragma unroll
    for (int ct = 0; ct < 4; ++ct) {
      const int col = col0 + wc + ct * 16 + l15;
      const float bv = bias ? bias[col] : 0.f;
#pragma unroll
      for (int rt = 0; rt < 4; ++rt) {
#pragma unroll
        for (int i = 0; i < 4; ++i) {
          const int row = row0 + wr + rt * 16 + quad * 4 + i;
          float v = acc[rt][ct][i] + bv;
          if constexpr (EPI == EPI_RELU_BIAS) {
            Cout[(long)row * ldc + col] = __float2bfloat16(v > 0.f ? v : 0.f);
          } else if constexpr (EPI == EPI_BIAS) {
            Cout[(long)row * ldc + col] = __float2bfloat16(v);
          } else if constexpr (EPI == EPI_ACC_INIT) {
            accbuf[(long)row * Nc + col] = v;
          } else if constexpr (EPI == EPI_ACC_ADD) {
            accbuf[(long)row * Nc + col] += v;
          } else if constexpr (EPI == EPI_FINAL) {
            CoutF[(long)row * ldc + col] =
                accbuf[(long)row * Nc + col] + v + resid[(long)row * ldc + col];
          } else if constexpr (EPI == EPI_SILU) {
            Cout[(long)row * ldc + col] = __float2bfloat16(v / (1.f + expf(-v)));
          } else {  // EPI_MUL
            const float g = __bfloat162float(gin[(long)row * ldc + col]);
            Cout[(long)row * ldc + col] = __float2bfloat16(v * g);
          }
        }
      }
    }
  }
}

// ---------------- 64x64-tile GEMM core: runtime shapes, 2-buf (806-proven) ----------------
template<int EPI>
__device__ __forceinline__
void gemm64_body(const bf16* __restrict__ A, int lda,
                 const bf16* __restrict__ Bt, int ldb,
                 const float* __restrict__ bias,
                 float* __restrict__ accbuf,
                 bf16* __restrict__ Cout, int ldc,
                 const float* __restrict__ resid,
                 float* __restrict__ CoutF,
                 int K, int Nc, int row0, int col0)
{
  __shared__ __align__(16) short As[2][64 * 32];
  __shared__ __align__(16) short Bs[2][64 * 32];

  const int tid  = threadIdx.x;
  const int lane = tid & 63;
  const int w    = tid >> 6;
  const int quad = lane >> 4;
  const int l15  = lane & 15;

  f32x4 acc[2][2];
  const f32x4 zero = {0.f, 0.f, 0.f, 0.f};
#pragma unroll
  for (int i = 0; i < 2; ++i)
#pragma unroll
    for (int j = 0; j < 2; ++j) acc[i][j] = zero;

  const int srow = (w << 4) + (lane >> 2);
  const int ss   = ((lane >> 2) & 3) ^ ((lane >> 4) & 1);
  const int sc   = ((lane & 3) ^ ss) << 3;
  const bf16* aG = A  + (long)(row0 + srow) * lda + sc;
  const bf16* bG = Bt + (long)(col0 + srow) * ldb + sc;
  const int ldsOff = w * 512;

  const int wr = (w >> 1) * 32;
  const int wc = (w & 1) * 32;
  const int fs = (l15 & 3) ^ ((l15 >> 2) & 1);

  gl_lds16(aG, As[0] + ldsOff);
  gl_lds16(bG, Bs[0] + ldsOff);
  __syncthreads();

  int cur = 0;
  for (int k0 = 0; k0 < K; k0 += 32) {
    const int nk = k0 + 32;
    if (nk < K) {
      gl_lds16(aG + nk, As[cur ^ 1] + ldsOff);
      gl_lds16(bG + nk, Bs[cur ^ 1] + ldsOff);
    }
    const short* Ac = As[cur];
    const short* Bc = Bs[cur];
    const int pc = (quad ^ fs) * 8;
    v8bf af[2], bfm[2];
#pragma unroll
    for (int i = 0; i < 2; ++i) {
      af[i]  = *(const v8bf*)&Ac[(wr + i * 16 + l15) * 32 + pc];
      bfm[i] = *(const v8bf*)&Bc[(wc + i * 16 + l15) * 32 + pc];
    }
#pragma unroll
    for (int i = 0; i < 2; ++i)
#pragma unroll
      for (int j = 0; j < 2; ++j)
        acc[i][j] = __builtin_amdgcn_mfma_f32_16x16x32_bf16(af[i], bfm[j], acc[i][j], 0, 0, 0);
    __syncthreads();
    cur ^= 1;
  }

#pragma unroll
  for (int ct = 0; ct < 2; ++ct) {
    const int col = col0 + wc + ct * 16 + l15;
    const float bv = bias ? bias[col] : 0.f;
#pragma unroll
    for (int rt = 0; rt < 2; ++rt) {
#pragma unroll
      for (int i = 0; i < 4; ++i) {
        const int row = row0 + wr + rt * 16 + quad * 4 + i;
        float v = acc[rt][ct][i] + bv;
        if constexpr (EPI == EPI_RELU_BIAS) {
          Cout[(long)row * ldc + col] = __float2bfloat16(v > 0.f ? v : 0.f);
        } else if constexpr (EPI == EPI_BIAS) {
          Cout[(long)row * ldc + col] = __float2bfloat16(v);
        } else if constexpr (EPI == EPI_ACC_INIT) {
          accbuf[(long)row * Nc + col] = v;
        } else if constexpr (EPI == EPI_ACC_ADD) {
          accbuf[(long)row * Nc + col] += v;
        } else if constexpr (EPI == EPI_FINAL) {
          CoutF[(long)row * Nc + col] =
              accbuf[(long)row * Nc + col] + v + resid[(long)row * Nc + col];
        }
      }
    }
  }
}

// 128-tile wrapper: (256,4) -> register allocator must fit 4 waves/EU (<=128 regs)
template<int EPI>
__global__ __launch_bounds__(256, 4)
void gemm_k(const bf16* __restrict__ A, int lda,
            const bf16* __restrict__ Bt, int ldb, long bTs,
            const float* __restrict__ bias, long biasTs,
            float* __restrict__ accbuf,
            bf16* __restrict__ Cout, int ldc,
            const float* __restrict__ resid,
            float* __restrict__ CoutF,
            const bf16* __restrict__ gin,
            int K, int Nc)
{
  const int row0 = blockIdx.x * 128;
  const int col0 = blockIdx.y * 128;
  const int t    = row0 >> 13;
  gemm_body<EPI>(A, lda, Bt + (long)t * bTs, ldb,
                 bias ? bias + (long)t * biasTs : nullptr,
                 accbuf, Cout, ldc, resid, CoutF, gin, K, Nc, row0, col0);
}

// 64-tile wrapper: grid (M/64, Nc/64)
template<int EPI>
__global__ __launch_bounds__(256)
void gemm64_k(const bf16* __restrict__ A, int lda,
              const bf16* __restrict__ Bt, int ldb, long bTs,
              const float* __restrict__ bias, long biasTs,
              float* __restrict__ accbuf,
              bf16* __restrict__ Cout, int ldc,
              const float* __restrict__ resid,
              float* __restrict__ CoutF,
              int K, int Nc)
{
  const int row0 = blockIdx.x * 64;
  const int col0 = blockIdx.y * 64;
  const int t    = row0 >> 13;
  gemm64_body<EPI>(A, lda, Bt + (long)t * bTs, ldb,
                   bias ? bias + (long)t * biasTs : nullptr,
                   accbuf, Cout, ldc, resid, CoutF, K, Nc, row0, col0);
}

// z-batched merged-W2 precompute (64-tile): W2'^T = outW_slice(j(b))^T @ w2_b^T
// b==0 (l2a) writes into the [256][1280] merged self+branch0 block (cols 256+).
__global__ __launch_bounds__(256)
void w2m_k(const bf16* __restrict__ outwT, const bf16* __restrict__ w2c,
           bf16* __restrict__ w2mg, bf16* __restrict__ w2m)
{
  const int z = blockIdx.z, b = z / 3, t = z % 3;
  const int j = (b == 0) ? 1 : (b == 1) ? 2 : 3;   // outW concat slice per branch
  bf16* dst;
  int ldc;
  if (b == 0) { dst = w2mg + (long)t * 327680 + 256; ldc = 1280; }
  else        { dst = w2m + (long)((b - 1) * 3 + t) * 262144; ldc = 1024; }
  gemm64_body<EPI_BIAS>(outwT + (long)t * 262144 + j * 256, 1024,
                        w2c + (long)b * 262144, 256,
                        nullptr, nullptr, dst, ldc,
                        nullptr, nullptr, 256, 1024,
                        blockIdx.x * 64, blockIdx.y * 64);
}

// copy outW j=0 slice into merged block cols 0-255
__global__ __launch_bounds__(256)
void selfw_k(const bf16* __restrict__ outwT, bf16* __restrict__ w2mg)
{
  const int i = blockIdx.x * 256 + threadIdx.x;   // 196608 total
  const int t = i >> 16, rem = i & 65535;
  const int col = rem >> 8, k = rem & 255;
  w2mg[(long)t * 327680 + (long)col * 1280 + k] =
      outwT[(long)t * 262144 + (long)col * 1024 + k];
}

// ---------------- weight transpose+cast: src f32 [K,Nc] -> dst bf16 [Nc,K], batched z ----------------
__global__ __launch_bounds__(256)
void transpose_k(const float* __restrict__ src, bf16* __restrict__ dst,
                 int K, int Nc, long sB, long dB)
{
  __shared__ bf16 tile[32][33];
  const int b = blockIdx.z;
  const float* s = src + (long)b * sB;
  bf16* d = dst + (long)b * dB;
  const int kb = blockIdx.y * 32, nb = blockIdx.x * 32;
  const int tx = threadIdx.x & 31, ty = threadIdx.x >> 5;
#pragma unroll
  for (int i = 0; i < 32; i += 8)
    tile[ty + i][tx] = __float2bfloat16(s[(long)(kb + ty + i) * Nc + nb + tx]);
  __syncthreads();
#pragma unroll
  for (int i = 0; i < 32; i += 8)
    d[(long)(nb + ty + i) * K + kb + tx] = tile[tx][ty + i];
}

// ---------------- interleaved FFN w1/w3 transpose: dst bf16 [3][2048,256] ----------------
__global__ __launch_bounds__(256)
void transpose13_k(const float* __restrict__ w1, const float* __restrict__ w3,
                   bf16* __restrict__ dst)
{
  __shared__ bf16 tile[32][33];
  const int t  = blockIdx.z;
  const int n0 = blockIdx.x * 32;
  const int k0 = blockIdx.y * 32;
  const int gi = n0 >> 5;
  const int tx = threadIdx.x & 31, ty = threadIdx.x >> 5;
  const float* src = ((tx & 16) ? w3 : w1) + (long)t * 262144;
  const int c = 16 * gi + (tx & 15);
#pragma unroll
  for (int i = 0; i < 32; i += 8)
    tile[ty + i][tx] = __float2bfloat16(src[(long)(k0 + ty + i) * 1024 + c]);
  __syncthreads();
#pragma unroll
  for (int i = 0; i < 32; i += 8)
    dst[((long)t * 2048 + n0 + ty + i) * 256 + k0 + tx] = tile[tx][ty + i];
}

// ---------------- LN-folded w1: dst[b] (bf16 [1024,512]) from w1 f32 [Kin,1024] ----------------
struct FoldP { const float* w1[5]; const float* ls[5]; };
__global__ __launch_bounds__(256)
void fold_w1_k(FoldP p, bf16* __restrict__ dst)
{
  __shared__ float tile[32][33];
  const int z = blockIdx.z;
  const float* w1 = p.w1[z];
  const float* ls = p.ls[z];
  bf16* d = dst + (long)z * 524288;
  const int n0 = blockIdx.x * 32, i0 = blockIdx.y * 32;
  const int tx = threadIdx.x & 31, ty = threadIdx.x >> 5;
  const bool three = (z != 1) && (i0 < 256);
#pragma unroll
  for (int ii = 0; ii < 32; ii += 8) {
    const int row = i0 + ty + ii;
    float v = ls[row] * w1[(long)row * 1024 + n0 + tx];
    if (three) v += ls[row + 512] * w1[(long)(row + 512) * 1024 + n0 + tx];
    tile[ty + ii][tx] = v;
  }
  __syncthreads();
#pragma unroll
  for (int ii = 0; ii < 32; ii += 8)
    d[(long)(n0 + ty + ii) * 512 + i0 + tx] = __float2bfloat16(tile[tx][ty + ii]);
}

// ---------------- bias-fold precompute (parallelized) ----------------
struct BInitP { const float* b1[5]; const float* fb1; const float* fb3; };
__global__ __launch_bounds__(256)
void binit_k(BInitP p, float* __restrict__ B1F,
             const float* __restrict__ out_b, float* __restrict__ TB,
             float* __restrict__ B13)
{
  const int i = blockIdx.x * 256 + threadIdx.x;
  if (i < 5120) {
    B1F[i] = p.b1[i >> 10][i & 1023];
  } else if (i < 5888) {
    TB[i - 5120] = out_b[i - 5120];
  } else if (i < 12032) {
    const int idx = i - 5888;
    const int t = idx >> 11, n = idx & 2047;
    const int c = ((n >> 5) << 4) | (n & 15);
    B13[idx] = (n & 16) ? p.fb3[t * 1024 + c] : p.fb1[t * 1024 + c];
  }
}

// B1F[z][n] += sum_k lb[k]*w1[k,n]; grid (z=5, ksplit=32)
struct B1P { const float* w1[5]; const float* lb[5]; int kin[5]; };
__global__ __launch_bounds__(256)
void b1f_add_k(B1P p, float* __restrict__ dst)
{
  const int z   = blockIdx.x;
  const int kin = p.kin[z];
  const int kpb = (kin + 31) >> 5;
  const int k0  = blockIdx.y * kpb;
  const int k1  = min(k0 + kpb, kin);
  const float* w1 = p.w1[z];
  const float* lb = p.lb[z];
  const int n = threadIdx.x;
  float a0 = 0.f, a1 = 0.f, a2 = 0.f, a3 = 0.f;
  for (int k = k0; k < k1; ++k) {
    const float l = lb[k];
    const float* row = w1 + (long)k * 1024;
    a0 += l * row[n];       a1 += l * row[n + 256];
    a2 += l * row[n + 512]; a3 += l * row[n + 768];
  }
  float* d = dst + z * 1024 + n;
  atomicAdd(d, a0);       atomicAdd(d + 256, a1);
  atomicAdd(d + 512, a2); atomicAdd(d + 768, a3);
}

// TB[t][h] += b2-vectors through outW slices; grid (t=3, csplit=8)
__global__ __launch_bounds__(256)
void tbias_add_k(const float* __restrict__ outW,
                 const float* __restrict__ l2a_b2, const float* __restrict__ g2a_b2,
                 const float* __restrict__ oth_b2, float* __restrict__ dst)
{
  const int t = blockIdx.x, h = threadIdx.x;
  const float* W = outW + (long)t * 262144;
  const int c0 = blockIdx.y * 32;
  float acc = 0.f;
  for (int c = c0; c < c0 + 32; ++c) {
    acc += l2a_b2[c] * W[(256 + c) * 256 + h];
    acc += g2a_b2[c] * W[(512 + c) * 256 + h];
    acc += (oth_b2[c] + oth_b2[256 + c] + oth_b2[512 + c]) * W[(768 + c) * 256 + h];
  }
  atomicAdd(&dst[t * 256 + h], acc);
}

// ---------------- f32 -> bf16 cast, 4 elems/thread ----------------
__global__ __launch_bounds__(256)
void cast_k(const float* __restrict__ src, bf16* __restrict__ dst)
{
  const long i = (long)blockIdx.x * 256 + threadIdx.x;
  const float4 v = ((const float4*)src)[i];
  ((bf4*)dst)[i] = mk4(v.x, v.y, v.z, v.w);
}

// ---------------- wave-wide reduce (all lanes get totals) ----------------
__device__ __forceinline__ void wave_reduce2(float& s, float& q) {
#pragma unroll
  for (int off = 32; off > 0; off >>= 1) {
    s += __shfl_xor(s, off, 64);
    q += __shfl_xor(q, off, 64);
  }
}

// ---------------- normalized-only LN: writes [fn, xn] (512 bf16) ----------------
template<int THREE>
__global__ __launch_bounds__(256)
void ln_norm_k(const float* __restrict__ feat, const float* __restrict__ x,
               const int* __restrict__ srcIdx, bf16* __restrict__ out)
{
  const int w = threadIdx.x >> 6, lane = threadIdx.x & 63;
  const int r = blockIdx.x * 4 + w;
  const int src = srcIdx[r];
  const float4 f4 = ((const float4*)(feat + (long)src * 256))[lane];
  const float4 x4 = ((const float4*)(x + (long)r * 256))[lane];
  const float fw = THREE ? 2.f : 1.f;
  float s = fw * (f4.x + f4.y + f4.z + f4.w) + (x4.x + x4.y + x4.z + x4.w);
  float q = fw * (f4.x * f4.x + f4.y * f4.y + f4.z * f4.z + f4.w * f4.w) +
            (x4.x * x4.x + x4.y * x4.y + x4.z * x4.z + x4.w * x4.w);
  wave_reduce2(s, q);
  const float rD  = THREE ? (1.f / 768.f) : (1.f / 512.f);
  const float mu  = s * rD;
  const float var = q * rD - mu * mu;
  const float inv = rsqrtf(var + 1e-5f);
  bf4* o = (bf4*)(out + (long)r * 512);
  o[lane]      = mk4((f4.x - mu) * inv, (f4.y - mu) * inv,
                     (f4.z - mu) * inv, (f4.w - mu) * inv);
  o[64 + lane] = mk4((x4.x - mu) * inv, (x4.y - mu) * inv,
                     (x4.z - mu) * inv, (x4.w - mu) * inv);
}

// ---------------- legacy LN kernels (Tier C path) ----------------
__global__ __launch_bounds__(256)
void ln_cat3_k(const float* __restrict__ feat, const float* __restrict__ x,
               const int* __restrict__ srcIdx,
               const float* __restrict__ ls, const float* __restrict__ lb,
               bf16* __restrict__ out)
{
  const int w = threadIdx.x >> 6, lane = threadIdx.x & 63;
  const int r = blockIdx.x * 4 + w;
  const int src = srcIdx[r];
  const float4 f4 = ((const float4*)(feat + (long)src * 256))[lane];
  const float4 x4 = ((const float4*)(x + (long)r * 256))[lane];
  float s = 2.f * (f4.x + f4.y + f4.z + f4.w) + (x4.x + x4.y + x4.z + x4.w);
  float q = 2.f * (f4.x * f4.x + f4.y * f4.y + f4.z * f4.z + f4.w * f4.w) +
            (x4.x * x4.x + x4.y * x4.y + x4.z * x4.z + x4.w * x4.w);
  wave_reduce2(s, q);
  const float mu  = s * (1.f / 768.f);
  const float var = q * (1.f / 768.f) - mu * mu;
  const float inv = rsqrtf(var + 1e-5f);
  const float4 s0 = ((const float4*)ls)[lane],         b0 = ((const float4*)lb)[lane];
  const float4 s1 = ((const float4*)(ls + 256))[lane], b1 = ((const float4*)(lb + 256))[lane];
  const float4 s2 = ((const float4*)(ls + 512))[lane], b2 = ((const float4*)(lb + 512))[lane];
  bf4* o = (bf4*)(out + (long)r * 768);
  o[lane] = mk4((f4.x - mu) * inv * s0.x + b0.x, (f4.y - mu) * inv * s0.y + b0.y,
                (f4.z - mu) * inv * s0.z + b0.z, (f4.w - mu) * inv * s0.w + b0.w);
  o[64 + lane] = mk4((x4.x - mu) * inv * s1.x + b1.x, (x4.y - mu) * inv * s1.y + b1.y,
                     (x4.z - mu) * inv * s1.z + b1.z, (x4.w - mu) * inv * s1.w + b1.w);
  o[128 + lane] = mk4((f4.x - mu) * inv * s2.x + b2.x, (f4.y - mu) * inv * s2.y + b2.y,
                      (f4.z - mu) * inv * s2.z + b2.z, (f4.w - mu) * inv * s2.w + b2.w);
}

__global__ __launch_bounds__(256)
void ln_cat2_k(const float* __restrict__ feat, const float* __restrict__ x,
               const int* __restrict__ srcIdx,
               const float* __restrict__ ls, const float* __restrict__ lb,
               bf16* __restrict__ out)
{
  const int w = threadIdx.x >> 6, lane = threadIdx.x & 63;
  const int r = blockIdx.x * 4 + w;
  const int src = srcIdx[r];
  const float4 f4 = ((const float4*)(feat + (long)src * 256))[lane];
  const float4 x4 = ((const float4*)(x + (long)r * 256))[lane];
  float s = (f4.x + f4.y + f4.z + f4.w) + (x4.x + x4.y + x4.z + x4.w);
  float q = (f4.x * f4.x + f4.y * f4.y + f4.z * f4.z + f4.w * f4.w) +
            (x4.x * x4.x + x4.y * x4.y + x4.z * x4.z + x4.w * x4.w);
  wave_reduce2(s, q);
  const float mu  = s * (1.f / 512.f);
  const float var = q * (1.f / 512.f) - mu * mu;
  const float inv = rsqrtf(var + 1e-5f);
  const float4 s0 = ((const float4*)ls)[lane],         b0 = ((const float4*)lb)[lane];
  const float4 s1 = ((const float4*)(ls + 256))[lane], b1 = ((const float4*)(lb + 256))[lane];
  bf4* o = (bf4*)(out + (long)r * 512);
  o[lane] = mk4((f4.x - mu) * inv * s0.x + b0.x, (f4.y - mu) * inv * s0.y + b0.y,
                (f4.z - mu) * inv * s0.z + b0.z, (f4.w - mu) * inv * s0.w + b0.w);
  o[64 + lane] = mk4((x4.x - mu) * inv * s1.x + b1.x, (x4.y - mu) * inv * s1.y + b1.y,
                     (x4.z - mu) * inv * s1.z + b1.z, (x4.w - mu) * inv * s1.w + b1.w);
}

// ---------------- FFN layernorm width 256: f32 in, bf16 out; one wave per row ----------------
// ldy = output row stride (elements) so y can live inside the merged [.,1280] region.
__global__ __launch_bounds__(256)
void ln_ffn_k(const float* __restrict__ ob, const float* __restrict__ ls,
              const float* __restrict__ lb, bf16* __restrict__ y,
              long lsStride, int ldy)
{
  const int w = threadIdx.x >> 6, lane = threadIdx.x & 63;
  const int r = blockIdx.x * 4 + w;
  const long po = (long)(r >> 13) * lsStride;
  const float4 v4 = ((const float4*)(ob + (long)r * 256))[lane];
  float s = v4.x + v4.y + v4.z + v4.w;
  float q = v4.x * v4.x + v4.y * v4.y + v4.z * v4.z + v4.w * v4.w;
  wave_reduce2(s, q);
  const float mu  = s * (1.f / 256.f);
  const float var = q * (1.f / 256.f) - mu * mu;
  const float inv = rsqrtf(var + 1e-5f);
  const float4 s0 = ((const float4*)(ls + po))[lane];
  const float4 b0 = ((const float4*)(lb + po))[lane];
  ((bf4*)(y + (long)r * ldy))[lane] =
      mk4((v4.x - mu) * inv * s0.x + b0.x, (v4.y - mu) * inv * s0.y + b0.y,
          (v4.z - mu) * inv * s0.z + b0.z, (v4.w - mu) * inv * s0.w + b0.w);
}

// ---------------- g = silu(g) * u, 4 elems/thread (Tier C path) ----------------
__global__ __launch_bounds__(256)
void silu_mul_k(bf16* __restrict__ g, const bf16* __restrict__ u)
{
  const long i = (long)blockIdx.x * 256 + threadIdx.x;
  const bf4 g4 = ((const bf4*)g)[i];
  const bf4 u4 = ((const bf4*)u)[i];
  float a = __bfloat162float(g4.x), b = __bfloat162float(g4.y);
  float c = __bfloat162float(g4.z), d = __bfloat162float(g4.w);
  a = a / (1.f + expf(-a)) * __bfloat162float(u4.x);
  b = b / (1.f + expf(-b)) * __bfloat162float(u4.y);
  c = c / (1.f + expf(-c)) * __bfloat162float(u4.z);
  d = d / (1.f + expf(-d)) * __bfloat162float(u4.w);
  ((bf4*)g)[i] = mk4(a, b, c, d);
}

// ---------------- sentinel fill (diagnostic) ----------------
__global__ __launch_bounds__(256)
void fill_k(float* __restrict__ p, int n)
{
  const int i = blockIdx.x * 256 + threadIdx.x;
  if (i < n) p[i] = 2.0f;
}

// ---------------- host ----------------
extern "C" void kernel_launch(void* const* d_in, const int* in_sizes, int n_in,
                              void* d_out, int out_size, void* d_ws, size_t ws_size,
                              hipStream_t stream)
{
  const float* agent_x  = (const float*)d_in[0];
  const float* lane_x   = (const float*)d_in[1];
  const float* poly_x   = (const float*)d_in[2];
  const int*   l2a_src  = (const int*)d_in[3];
  const int*   g2a_src  = (const int*)d_in[4];
  const int*   other_src= (const int*)d_in[5];
  const float* self_W   = (const float*)d_in[6];
  const float* self_b   = (const float*)d_in[7];
  const float* out_W    = (const float*)d_in[8];
  const float* out_b    = (const float*)d_in[9];
  const float* ffn_ln_s = (const float*)d_in[10];
  const float* ffn_ln_b = (const float*)d_in[11];
  const float* ffn_w1   = (const float*)d_in[12];
  const float* ffn_b1   = (const float*)d_in[13];
  const float* ffn_w2   = (const float*)d_in[14];
  const float* ffn_b2   = (const float*)d_in[15];
  const float* ffn_w3   = (const float*)d_in[16];
  const float* ffn_b3   = (const float*)d_in[17];
  const float* l2a_ln_s = (const float*)d_in[18];
  const float* l2a_ln_b = (const float*)d_in[19];
  const float* l2a_w1   = (const float*)d_in[20];
  const float* l2a_b1   = (const float*)d_in[21];
  const float* l2a_w2   = (const float*)d_in[22];
  const float* l2a_b2   = (const float*)d_in[23];
  const float* g2a_ln_s = (const float*)d_in[24];
  const float* g2a_ln_b = (const float*)d_in[25];
  const float* g2a_w1   = (const float*)d_in[26];
  const float* g2a_b1   = (const float*)d_in[27];
  const float* g2a_w2   = (const float*)d_in[28];
  const float* g2a_b2   = (const float*)d_in[29];
  const float* oth_ln_s = (const float*)d_in[30];
  const float* oth_ln_b = (const float*)d_in[31];
  const float* oth_w1   = (const float*)d_in[32];
  const float* oth_b1   = (const float*)d_in[33];
  const float* oth_w2   = (const float*)d_in[34];
  const float* oth_b2   = (const float*)d_in[35];

  float* outp = (float*)d_out;
  const dim3 B256(256);

  const size_t TIER_A = 136108032;  // merged-M layout (fits proven 155 MB grant)
  const size_t TIER_C = 12058624;   // chunked fallback

  if (ws_size >= TIER_A) {
    // ===== Tier A: merged-M (R9) + register-trimmed 128-tile (R10) =====
    char* base = (char*)d_ws;
    bf16* wT = (bf16*)base;
    const long SELF_WT = 0,       OUT_WT  = 196608,  FFN_W13T = 983040;
    const long FFN_W2T = 2555904, W2C = 3342336,     W1F      = 4653056;
    const long W2MG = 7274496;    // [3][256][1280] merged self+branch0 Bt
    const long W2M  = 8257536;    // [4][3][256][1024] branches 1-4
    float* B1F  = (float*)(base + 22806528L);   // [5][1024] folded w1 bias
    float* TB   = (float*)(base + 22827008L);   // [3][256]  fused out-bias
    float* B13  = (float*)(base + 22830080L);   // [3][2048] interleaved ffn bias
    bf16*  nbuf = (bf16*)(base + 22854656L);    // [N,512]  LN output / xbf scratch
    bf16*  M    = (bf16*)(base + 48020480L);    // [N,1280]: cols 0-255 self/y, 256-1279 h1/g*u
    float* oF   = (float*)(base + 110935040L);  // [N,256]  branch accumulator
    bf16*  xbf  = nbuf;  // bf16 cast of agent_x (nbuf dead until first ln_norm)

    // ---- weight precompute ----
    auto TRB = [&](const float* s, long dOff, int K, int Nc, long sB, long dB, int b) {
      transpose_k<<<dim3(Nc / 32, K / 32, b), B256, 0, stream>>>(s, wT + dOff, K, Nc, sB, dB);
    };
    TRB(self_W, SELF_WT, 256, 256,  65536, 65536, 3);
    TRB(out_W,  OUT_WT,  1024, 256, 262144, 262144, 3);
    TRB(ffn_w2, FFN_W2T, 1024, 256, 262144, 262144, 3);
    transpose13_k<<<dim3(64, 8, 3), B256, 0, stream>>>(ffn_w1, ffn_w3, wT + FFN_W13T);
    cast_k<<<256, B256, 0, stream>>>(l2a_w2, wT + W2C);
    cast_k<<<256, B256, 0, stream>>>(g2a_w2, wT + W2C + 262144);
    cast_k<<<768, B256, 0, stream>>>(oth_w2, wT + W2C + 524288);

    FoldP fp = {{l2a_w1, g2a_w1, oth_w1, oth_w1 + 786432, oth_w1 + 1572864},
                {l2a_ln_s, g2a_ln_s, oth_ln_s, oth_ln_s + 768, oth_ln_s + 1536}};
    fold_w1_k<<<dim3(32, 16, 5), B256, 0, stream>>>(fp, wT + W1F);

    BInitP ip = {{l2a_b1, g2a_b1, oth_b1, oth_b1 + 1024, oth_b1 + 2048}, ffn_b1, ffn_b3};
    binit_k<<<47, B256, 0, stream>>>(ip, B1F, out_b, TB, B13);
    B1P bp = {{l2a_w1, g2a_w1, oth_w1, oth_w1 + 786432, oth_w1 + 1572864},
              {l2a_ln_b, g2a_ln_b, oth_ln_b, oth_ln_b + 768, oth_ln_b + 1536},
              {768, 512, 768, 768, 768}};
    b1f_add_k<<<dim3(5, 32), B256, 0, stream>>>(bp, B1F);
    tbias_add_k<<<dim3(3, 8), B256, 0, stream>>>(out_W, l2a_b2, g2a_b2, oth_b2, TB);
    selfw_k<<<768, B256, 0, stream>>>(wT + OUT_WT, wT + W2MG);
    w2m_k<<<dim3(4, 16, 15), B256, 0, stream>>>(wT + OUT_WT, wT + W2C,
                                                wT + W2MG, wT + W2M);

    const dim3 G64n2(N_AG / 64, 4);     // N=256 GEMMs (64-tile): 1536 blocks
    const dim3 Gw1(N_AG / 128, 8);      // w1' (128-tile): 1536 blocks
    const dim3 Gglu(N_AG / 128, 16);    // GLU (128-tile): 3072 blocks

    // ---- self branch: relu output into M cols 0-255 (ldc 1280) ----
    cast_k<<<N_AG / 4, B256, 0, stream>>>(agent_x, xbf);
    gemm64_k<EPI_RELU_BIAS><<<G64n2, B256, 0, stream>>>(
        xbf, 256, wT + SELF_WT, 256, 65536, self_b, 256,
        nullptr, M, 1280, nullptr, nullptr, 256, 256);

    // ---- edge branches: LN -> w1' (128-tile, writes M cols 256+) -> ACC ----
    for (int b = 0; b < 5; ++b) {
      const int* src = (b == 0) ? l2a_src : (b == 1) ? g2a_src
                                          : other_src + (long)(b - 2) * N_AG;
      const float* feat = (b == 0) ? lane_x : (b == 1) ? poly_x : agent_x;
      if (b == 1) ln_norm_k<0><<<N_AG / 4, B256, 0, stream>>>(feat, agent_x, src, nbuf);
      else        ln_norm_k<1><<<N_AG / 4, B256, 0, stream>>>(feat, agent_x, src, nbuf);
      gemm_k<EPI_RELU_BIAS><<<Gw1, B256, 0, stream>>>(
          nbuf, 512, wT + W1F + (long)b * 524288, 512, 0, B1F + b * 1024, 0,
          nullptr, M + 256, 1280, nullptr, nullptr, nullptr, 512, 1024);
      if (b == 0) {
        // merged self+branch0 accumulation, K=1280 (TB carries all folded biases)
        gemm64_k<EPI_ACC_INIT><<<G64n2, B256, 0, stream>>>(
            M, 1280, wT + W2MG, 1280, 327680, TB, 256,
            oF, nullptr, 0, nullptr, nullptr, 1280, 256);
      } else {
        gemm64_k<EPI_ACC_ADD><<<G64n2, B256, 0, stream>>>(
            M + 256, 1280, wT + W2M + (long)(b - 1) * 786432, 1024, 262144,
            nullptr, 0, oF, nullptr, 0, nullptr, nullptr, 1024, 256);
      }
    }

    // ---- FFN: y into M cols 0-255; GLU writes g*u into cols 256-1279; FINAL ----
    ln_ffn_k<<<N_AG / 4, B256, 0, stream>>>(oF, ffn_ln_s, ffn_ln_b, M, 256, 1280);
    gemm_k<EPI_GLU><<<Gglu, B256, 0, stream>>>(
        M, 1280, wT + FFN_W13T, 256, 524288, B13, 2048,
        nullptr, M + 256, 1280, nullptr, nullptr, nullptr, 256, 2048);
    gemm64_k<EPI_FINAL><<<G64n2, B256, 0, stream>>>(
        M + 256, 1280, wT + FFN_W2T, 1024, 262144, ffn_b2, 256,
        oF, nullptr, 0, agent_x, outp, 1024, 256);
    return;
  }

  if (ws_size < TIER_C) {
    fill_k<<<(out_size + 255) / 256, B256, 0, stream>>>(outp, out_size);
    return;
  }

  // ================= Tier C: chunked path (11.5 MiB) =================
  const int CH = 2048;
  char* base = (char*)d_ws;
  bf16*  wt     = (bf16*)base;
  bf16*  nbuf   = (bf16*)(base + 1572864L);
  bf16*  bbuf   = (bf16*)(base + 4718592L);
  bf16*  h1     = (bf16*)(base + 5767168L);
  float* outF32 = (float*)(base + 9961472L);
  bf16*  ybuf   = (bf16*)(base + 524288L);
  bf16*  xbf    = h1;
  bf16*  g_pre  = h1;
  bf16*  u_pre  = nbuf;

  const dim3 Gw1(CH / 128, 8), Gw2(CH / 128, 2);
  auto TR = [&](const float* s, int K, int Nc) {
    transpose_k<<<dim3(Nc / 32, K / 32), B256, 0, stream>>>(s, wt, K, Nc, 0, 0);
  };

  for (int t = 0; t < 3; ++t) {
    for (int c = 0; c < N3 / CH; ++c) {
      const long r0 = (long)t * N3 + (long)c * CH;
      const float* xC   = agent_x + r0 * 256;
      float*       outC = outp + r0 * 256;

      cast_k<<<CH / 4, B256, 0, stream>>>(xC, xbf);
      TR(self_W + (long)t * 65536, 256, 256);
      gemm_k<EPI_RELU_BIAS><<<Gw2, B256, 0, stream>>>(
          xbf, 256, wt, 256, 0, self_b + t * 256, 0, nullptr, bbuf, 256,
          nullptr, nullptr, nullptr, 256, 256);
      TR(out_W + (long)t * 262144 + 0 * 65536, 256, 256);
      gemm_k<EPI_ACC_INIT><<<Gw2, B256, 0, stream>>>(
          bbuf, 256, wt, 256, 0, out_b + t * 256, 0, outF32, nullptr, 0,
          nullptr, nullptr, nullptr, 256, 256);

      ln_cat3_k<<<CH / 4, B256, 0, stream>>>(lane_x, xC, l2a_src + r0,
                                             l2a_ln_s, l2a_ln_b, nbuf);
      TR(l2a_w1, 768, 1024);
      gemm_k<EPI_RELU_BIAS><<<Gw1, B256, 0, stream>>>(
          nbuf, 768, wt, 768, 0, l2a_b1, 0, nullptr, h1, 1024,
          nullptr, nullptr, nullptr, 768, 1024);
      TR(l2a_w2, 1024, 256);
      gemm_k<EPI_BIAS><<<Gw2, B256, 0, stream>>>(
          h1, 1024, wt, 1024, 0, l2a_b2, 0, nullptr, bbuf, 256,
          nullptr, nullptr, nullptr, 1024, 256);
      TR(out_W + (long)t * 262144 + 1 * 65536, 256, 256);
      gemm_k<EPI_ACC_ADD><<<Gw2, B256, 0, stream>>>(
          bbuf, 256, wt, 256, 0, nullptr, 0, outF32, nullptr, 0,
          nullptr, nullptr, nullptr, 256, 256);

      ln_cat2_k<<<CH / 4, B256, 0, stream>>>(poly_x, xC, g2a_src + r0,
                                             g2a_ln_s, g2a_ln_b, nbuf);
      TR(g2a_w1, 512, 1024);
      gemm_k<EPI_RELU_BIAS><<<Gw1, B256, 0, stream>>>(
          nbuf, 512, wt, 512, 0, g2a_b1, 0, nullptr, h1, 1024,
          nullptr, nullptr, nullptr, 512, 1024);
      TR(g2a_w2, 1024, 256);
      gemm_k<EPI_BIAS><<<Gw2, B256, 0, stream>>>(
          h1, 1024, wt, 1024, 0, g2a_b2, 0, nullptr, bbuf, 256,
          nullptr, nullptr, nullptr, 1024, 256);
      TR(out_W + (long)t * 262144 + 2 * 65536, 256, 256);
      gemm_k<EPI_ACC_ADD><<<Gw2, B256, 0, stream>>>(
          bbuf, 256, wt, 256, 0, nullptr, 0, outF32, nullptr, 0,
          nullptr, nullptr, nullptr, 256, 256);

      for (int s = 0; s < 3; ++s) {
        ln_cat3_k<<<CH / 4, B256, 0, stream>>>(
            agent_x, xC, other_src + (long)s * N_AG + r0,
            oth_ln_s + s * 768, oth_ln_b + s * 768, nbuf);
        TR(oth_w1 + (long)s * 786432, 768, 1024);
        gemm_k<EPI_RELU_BIAS><<<Gw1, B256, 0, stream>>>(
            nbuf, 768, wt, 768, 0, oth_b1 + s * 1024, 0, nullptr, h1, 1024,
            nullptr, nullptr, nullptr, 768, 1024);
        TR(oth_w2 + (long)s * 262144, 1024, 256);
        gemm_k<EPI_BIAS><<<Gw2, B256, 0, stream>>>(
            h1, 1024, wt, 1024, 0, oth_b2 + s * 256, 0, nullptr, bbuf, 256,
            nullptr, nullptr, nullptr, 1024, 256);
        TR(out_W + (long)t * 262144 + 3 * 65536, 256, 256);
        gemm_k<EPI_ACC_ADD><<<Gw2, B256, 0, stream>>>(
            bbuf, 256, wt, 256, 0, nullptr, 0, outF32, nullptr, 0,
            nullptr, nullptr, nullptr, 256, 256);
      }

      ln_ffn_k<<<CH / 4, B256, 0, stream>>>(outF32, ffn_ln_s + t * 256,
                                            ffn_ln_b + t * 256, ybuf, 0, 256);
      TR(ffn_w1 + (long)t * 262144, 256, 1024);
      gemm_k<EPI_BIAS><<<Gw1, B256, 0, stream>>>(
          ybuf, 256, wt, 256, 0, ffn_b1 + t * 1024, 0, nullptr, g_pre, 1024,
          nullptr, nullptr, nullptr, 256, 1024);
      TR(ffn_w3 + (long)t * 262144, 256, 1024);
      gemm_k<EPI_BIAS><<<Gw1, B256, 0, stream>>>(
          ybuf, 256, wt, 256, 0, ffn_b3 + t * 1024, 0, nullptr, u_pre, 1024,
          nullptr, nullptr, nullptr, 256, 1024);
      silu_mul_k<<<CH, B256, 0, stream>>>(g_pre, u_pre);
      TR(ffn_w2 + (long)t * 262144, 1024, 256);
      gemm_k<EPI_FINAL><<<Gw2, B256, 0, stream>>>(
          g_pre, 1024, wt, 1024, 0, ffn_b2 + t * 256, 0, outF32, nullptr, 256,
          xC, outC, nullptr, 1024, 256);
    }
  }
}

// Round 12
// 787.541 us; speedup vs baseline: 1.2043x; 1.0306x over previous
//
#include <hip/hip_runtime.h>
#include <hip/hip_bf16.h>

typedef __hip_bfloat16 bf16;
typedef __bf16 v8bf __attribute__((ext_vector_type(8)));
typedef float f32x4 __attribute__((ext_vector_type(4)));

#define N_AG 24576
#define N3 8192

struct __align__(8) bf4 { bf16 x, y, z, w; };
__device__ __forceinline__ bf4 mk4(float a, float b, float c, float d) {
  bf4 r{__float2bfloat16(a), __float2bfloat16(b), __float2bfloat16(c), __float2bfloat16(d)};
  return r;
}

// ---------------- epilogue modes ----------------
enum {
  EPI_RELU_BIAS = 0,  // Cout(bf16) = relu(v + bias)
  EPI_BIAS      = 1,  // Cout(bf16) = v + bias
  EPI_ACC_INIT  = 2,  // accbuf(f32) = v + bias
  EPI_ACC_ADD   = 3,  // accbuf(f32) += v + bias
  EPI_FINAL     = 4,  // CoutF(f32) = accbuf + v + bias + resid
  EPI_SILU      = 5,  // Cout(bf16) = silu(v + bias)
  EPI_MUL       = 6,  // Cout(bf16) = (v + bias) * gin[idx]
  EPI_GLU       = 7   // interleaved g/u tiles: Cout(bf16) = silu(g+bg) * (u+bu)
};

// async 16B/lane global->LDS DMA; LDS dest = wave-uniform base + lane*16
__device__ __forceinline__ void gl_lds16(const bf16* g, short* l) {
  __builtin_amdgcn_global_load_lds(
      (const __attribute__((address_space(1))) unsigned int*)g,
      (__attribute__((address_space(3))) unsigned int*)l, 16, 0, 0);
}

// ---------------- 128-tile GEMM core: runtime shapes, 2-buf (806-proven, R11 revert) ----------------
// Best measured for wide-N GEMMs (w1' 53-57us). Two live B-fragments restored:
// R10's single-B variant serialized MFMAs (54.5 -> 64us). Do not touch.
template<int EPI>
__device__ __forceinline__
void gemm_body(const bf16* __restrict__ A, int lda,
               const bf16* __restrict__ Bt, int ldb,
               const float* __restrict__ bias,
               float* __restrict__ accbuf,
               bf16* __restrict__ Cout, int ldc,
               const float* __restrict__ resid,
               float* __restrict__ CoutF,
               const bf16* __restrict__ gin,
               int K, int Nc, int row0, int col0)
{
  __shared__ __align__(16) short As[2][128 * 32];
  __shared__ __align__(16) short Bs[2][128 * 32];

  const int tid  = threadIdx.x;
  const int lane = tid & 63;
  const int w    = tid >> 6;
  const int quad = lane >> 4;
  const int l15  = lane & 15;

  f32x4 acc[4][4];
  const f32x4 zero = {0.f, 0.f, 0.f, 0.f};
#pragma unroll
  for (int i = 0; i < 4; ++i)
#pragma unroll
    for (int j = 0; j < 4; ++j) acc[i][j] = zero;

  // staging: wave w rows [w*32, w*32+32); lane i -> (row i>>2, phys chunk i&3)
  const int srow = (w << 5) + (lane >> 2);
  const int ss   = ((lane >> 2) & 3) ^ ((lane >> 4) & 1);   // s(srow), same for srow+16
  const int sc   = ((lane & 3) ^ ss) << 3;                  // global elem offset fetched
  const bf16* aG = A  + (long)(row0 + srow) * lda + sc;
  const bf16* bG = Bt + (long)(col0 + srow) * ldb + sc;
  const int ldsOff = w * 1024;

  const int wr = (w >> 1) * 64;
  const int wc = (w & 1) * 64;
  const int fs = (l15 & 3) ^ ((l15 >> 2) & 1);   // frag-read swizzle

  gl_lds16(aG,                  As[0] + ldsOff);
  gl_lds16(aG + (long)16 * lda, As[0] + ldsOff + 512);
  gl_lds16(bG,                  Bs[0] + ldsOff);
  gl_lds16(bG + (long)16 * ldb, Bs[0] + ldsOff + 512);
  __syncthreads();

  int cur = 0;
  for (int k0 = 0; k0 < K; k0 += 32) {
    const int nk = k0 + 32;
    if (nk < K) {
      short* An = As[cur ^ 1] + ldsOff;
      short* Bn = Bs[cur ^ 1] + ldsOff;
      gl_lds16(aG + nk,                  An);
      gl_lds16(aG + nk + (long)16 * lda, An + 512);
      gl_lds16(bG + nk,                  Bn);
      gl_lds16(bG + nk + (long)16 * ldb, Bn + 512);
    }
    const short* Ac = As[cur];
    const short* Bc = Bs[cur];
    const int pc = (quad ^ fs) * 8;
    v8bf af[4], bfm[4];
#pragma unroll
    for (int i = 0; i < 4; ++i) {
      af[i]  = *(const v8bf*)&Ac[(wr + i * 16 + l15) * 32 + pc];
      bfm[i] = *(const v8bf*)&Bc[(wc + i * 16 + l15) * 32 + pc];
    }
#pragma unroll
    for (int i = 0; i < 4; ++i)
#pragma unroll
      for (int j = 0; j < 4; ++j)
        acc[i][j] = __builtin_amdgcn_mfma_f32_16x16x32_bf16(af[i], bfm[j], acc[i][j], 0, 0, 0);
    __syncthreads();
    cur ^= 1;
  }

  if constexpr (EPI == EPI_GLU) {
    // interleaved layout: 32-col blocks = [16 g-cols | 16 u-cols] of same h-cols.
#pragma unroll
    for (int ct = 0; ct < 4; ct += 2) {
      const int colg = col0 + wc + ct * 16 + l15;
      const int hcol = ((colg >> 5) << 4) + (colg & 15);
      const float bg = bias[colg];
      const float bu = bias[colg + 16];
#pragma unroll
      for (int rt = 0; rt < 4; ++rt) {
#pragma unroll
        for (int i = 0; i < 4; ++i) {
          const int row = row0 + wr + rt * 16 + quad * 4 + i;
          const float vg = acc[rt][ct][i] + bg;
          const float vu = acc[rt][ct + 1][i] + bu;
          Cout[(long)row * ldc + hcol] =
              __float2bfloat16(vg / (1.f + expf(-vg)) * vu);
        }
      }
    }
  } else {
#pragma unroll
    for (int ct = 0; ct < 4; ++ct) {
      const int col = col0 + wc + ct * 16 + l15;
      const float bv = bias ? bias[col] : 0.f;
#pragma unroll
      for (int rt = 0; rt < 4; ++rt) {
#pragma unroll
        for (int i = 0; i < 4; ++i) {
          const int row = row0 + wr + rt * 16 + quad * 4 + i;
          float v = acc[rt][ct][i] + bv;
          if constexpr (EPI == EPI_RELU_BIAS) {
            Cout[(long)row * ldc + col] = __float2bfloat16(v > 0.f ? v : 0.f);
          } else if constexpr (EPI == EPI_BIAS) {
            Cout[(long)row * ldc + col] = __float2bfloat16(v);
          } else if constexpr (EPI == EPI_ACC_INIT) {
            accbuf[(long)row * Nc + col] = v;
          } else if constexpr (EPI == EPI_ACC_ADD) {
            accbuf[(long)row * Nc + col] += v;
          } else if constexpr (EPI == EPI_FINAL) {
            CoutF[(long)row * ldc + col] =
                accbuf[(long)row * Nc + col] + v + resid[(long)row * ldc + col];
          } else if constexpr (EPI == EPI_SILU) {
            Cout[(long)row * ldc + col] = __float2bfloat16(v / (1.f + expf(-v)));
          } else {  // EPI_MUL
            const float g = __bfloat162float(gin[(long)row * ldc + col]);
            Cout[(long)row * ldc + col] = __float2bfloat16(v * g);
          }
        }
      }
    }
  }
}

// ---------------- 64x128-tile GEMM core (R11): N=256 K>=1024 GEMMs ----------------
// Halves A-panel re-reads vs 64x64 (2 col passes, not 4): ACC family was
// A-refetch-bound (~200MB re-read + 50MB oF RMW ~ measured 50us). 4 waves
// (2M x 2N), each 32x64 -> acc[2][4]. LDS 24KB, ~80 VGPR -> ~6 blocks/CU.
// A staged by the 64-tile pattern, B by the 128-tile pattern (both proven).
template<int EPI>
__device__ __forceinline__
void gemm64x128_body(const bf16* __restrict__ A, int lda,
                     const bf16* __restrict__ Bt, int ldb,
                     const float* __restrict__ bias,
                     float* __restrict__ accbuf,
                     bf16* __restrict__ Cout, int ldc,
                     const float* __restrict__ resid,
                     float* __restrict__ CoutF,
                     int K, int Nc, int row0, int col0)
{
  __shared__ __align__(16) short As[2][64 * 32];
  __shared__ __align__(16) short Bs[2][128 * 32];

  const int tid  = threadIdx.x;
  const int lane = tid & 63;
  const int w    = tid >> 6;
  const int quad = lane >> 4;
  const int l15  = lane & 15;

  f32x4 acc[2][4];
  const f32x4 zero = {0.f, 0.f, 0.f, 0.f};
#pragma unroll
  for (int i = 0; i < 2; ++i)
#pragma unroll
    for (int j = 0; j < 4; ++j) acc[i][j] = zero;

  const int ss = ((lane >> 2) & 3) ^ ((lane >> 4) & 1);   // s(row), row low bits = lane>>2
  const int sc = ((lane & 3) ^ ss) << 3;
  // A: wave w rows [w*16, w*16+16)  (64 rows total, 1 load/thread)
  const int srowA = (w << 4) + (lane >> 2);
  const bf16* aG = A + (long)(row0 + srowA) * lda + sc;
  // B: wave w rows [w*32, w*32+32)  (128 rows total, 2 loads/thread)
  const int srowB = (w << 5) + (lane >> 2);
  const bf16* bG = Bt + (long)(col0 + srowB) * ldb + sc;
  const int aOff = w * 512;    // 16 rows * 32 shorts
  const int bOff = w * 1024;   // 32 rows * 32 shorts

  const int wr = (w >> 1) * 32;   // 2 row groups of 32
  const int wc = (w & 1) * 64;    // 2 col groups of 64
  const int fs = (l15 & 3) ^ ((l15 >> 2) & 1);

  gl_lds16(aG,                  As[0] + aOff);
  gl_lds16(bG,                  Bs[0] + bOff);
  gl_lds16(bG + (long)16 * ldb, Bs[0] + bOff + 512);
  __syncthreads();

  int cur = 0;
  for (int k0 = 0; k0 < K; k0 += 32) {
    const int nk = k0 + 32;
    if (nk < K) {
      gl_lds16(aG + nk,                  As[cur ^ 1] + aOff);
      gl_lds16(bG + nk,                  Bs[cur ^ 1] + bOff);
      gl_lds16(bG + nk + (long)16 * ldb, Bs[cur ^ 1] + bOff + 512);
    }
    const short* Ac = As[cur];
    const short* Bc = Bs[cur];
    const int pc = (quad ^ fs) * 8;
    v8bf af[2], bfm[4];
#pragma unroll
    for (int i = 0; i < 2; ++i)
      af[i] = *(const v8bf*)&Ac[(wr + i * 16 + l15) * 32 + pc];
#pragma unroll
    for (int j = 0; j < 4; ++j)
      bfm[j] = *(const v8bf*)&Bc[(wc + j * 16 + l15) * 32 + pc];
#pragma unroll
    for (int i = 0; i < 2; ++i)
#pragma unroll
      for (int j = 0; j < 4; ++j)
        acc[i][j] = __builtin_amdgcn_mfma_f32_16x16x32_bf16(af[i], bfm[j], acc[i][j], 0, 0, 0);
    __syncthreads();
    cur ^= 1;
  }

#pragma unroll
  for (int ct = 0; ct < 4; ++ct) {
    const int col = col0 + wc + ct * 16 + l15;
    const float bv = bias ? bias[col] : 0.f;
#pragma unroll
    for (int rt = 0; rt < 2; ++rt) {
#pragma unroll
      for (int i = 0; i < 4; ++i) {
        const int row = row0 + wr + rt * 16 + quad * 4 + i;
        float v = acc[rt][ct][i] + bv;
        if constexpr (EPI == EPI_RELU_BIAS) {
          Cout[(long)row * ldc + col] = __float2bfloat16(v > 0.f ? v : 0.f);
        } else if constexpr (EPI == EPI_BIAS) {
          Cout[(long)row * ldc + col] = __float2bfloat16(v);
        } else if constexpr (EPI == EPI_ACC_INIT) {
          accbuf[(long)row * Nc + col] = v;
        } else if constexpr (EPI == EPI_ACC_ADD) {
          accbuf[(long)row * Nc + col] += v;
        } else if constexpr (EPI == EPI_FINAL) {
          CoutF[(long)row * Nc + col] =
              accbuf[(long)row * Nc + col] + v + resid[(long)row * Nc + col];
        }
      }
    }
  }
}

// ---------------- 64x64-tile GEMM core: runtime shapes, 2-buf (w2m precompute) ----------------
template<int EPI>
__device__ __forceinline__
void gemm64_body(const bf16* __restrict__ A, int lda,
                 const bf16* __restrict__ Bt, int ldb,
                 const float* __restrict__ bias,
                 float* __restrict__ accbuf,
                 bf16* __restrict__ Cout, int ldc,
                 const float* __restrict__ resid,
                 float* __restrict__ CoutF,
                 int K, int Nc, int row0, int col0)
{
  __shared__ __align__(16) short As[2][64 * 32];
  __shared__ __align__(16) short Bs[2][64 * 32];

  const int tid  = threadIdx.x;
  const int lane = tid & 63;
  const int w    = tid >> 6;
  const int quad = lane >> 4;
  const int l15  = lane & 15;

  f32x4 acc[2][2];
  const f32x4 zero = {0.f, 0.f, 0.f, 0.f};
#pragma unroll
  for (int i = 0; i < 2; ++i)
#pragma unroll
    for (int j = 0; j < 2; ++j) acc[i][j] = zero;

  const int srow = (w << 4) + (lane >> 2);
  const int ss   = ((lane >> 2) & 3) ^ ((lane >> 4) & 1);
  const int sc   = ((lane & 3) ^ ss) << 3;
  const bf16* aG = A  + (long)(row0 + srow) * lda + sc;
  const bf16* bG = Bt + (long)(col0 + srow) * ldb + sc;
  const int ldsOff = w * 512;

  const int wr = (w >> 1) * 32;
  const int wc = (w & 1) * 32;
  const int fs = (l15 & 3) ^ ((l15 >> 2) & 1);

  gl_lds16(aG, As[0] + ldsOff);
  gl_lds16(bG, Bs[0] + ldsOff);
  __syncthreads();

  int cur = 0;
  for (int k0 = 0; k0 < K; k0 += 32) {
    const int nk = k0 + 32;
    if (nk < K) {
      gl_lds16(aG + nk, As[cur ^ 1] + ldsOff);
      gl_lds16(bG + nk, Bs[cur ^ 1] + ldsOff);
    }
    const short* Ac = As[cur];
    const short* Bc = Bs[cur];
    const int pc = (quad ^ fs) * 8;
    v8bf af[2], bfm[2];
#pragma unroll
    for (int i = 0; i < 2; ++i) {
      af[i]  = *(const v8bf*)&Ac[(wr + i * 16 + l15) * 32 + pc];
      bfm[i] = *(const v8bf*)&Bc[(wc + i * 16 + l15) * 32 + pc];
    }
#pragma unroll
    for (int i = 0; i < 2; ++i)
#pragma unroll
      for (int j = 0; j < 2; ++j)
        acc[i][j] = __builtin_amdgcn_mfma_f32_16x16x32_bf16(af[i], bfm[j], acc[i][j], 0, 0, 0);
    __syncthreads();
    cur ^= 1;
  }

#pragma unroll
  for (int ct = 0; ct < 2; ++ct) {
    const int col = col0 + wc + ct * 16 + l15;
    const float bv = bias ? bias[col] : 0.f;
#pragma unroll
    for (int rt = 0; rt < 2; ++rt) {
#pragma unroll
      for (int i = 0; i < 4; ++i) {
        const int row = row0 + wr + rt * 16 + quad * 4 + i;
        float v = acc[rt][ct][i] + bv;
        if constexpr (EPI == EPI_RELU_BIAS) {
          Cout[(long)row * ldc + col] = __float2bfloat16(v > 0.f ? v : 0.f);
        } else if constexpr (EPI == EPI_BIAS) {
          Cout[(long)row * ldc + col] = __float2bfloat16(v);
        } else if constexpr (EPI == EPI_ACC_INIT) {
          accbuf[(long)row * Nc + col] = v;
        } else if constexpr (EPI == EPI_ACC_ADD) {
          accbuf[(long)row * Nc + col] += v;
        } else if constexpr (EPI == EPI_FINAL) {
          CoutF[(long)row * Nc + col] =
              accbuf[(long)row * Nc + col] + v + resid[(long)row * Nc + col];
        }
      }
    }
  }
}

// 128-tile wrapper
template<int EPI>
__global__ __launch_bounds__(256)
void gemm_k(const bf16* __restrict__ A, int lda,
            const bf16* __restrict__ Bt, int ldb, long bTs,
            const float* __restrict__ bias, long biasTs,
            float* __restrict__ accbuf,
            bf16* __restrict__ Cout, int ldc,
            const float* __restrict__ resid,
            float* __restrict__ CoutF,
            const bf16* __restrict__ gin,
            int K, int Nc)
{
  const int row0 = blockIdx.x * 128;
  const int col0 = blockIdx.y * 128;
  const int t    = row0 >> 13;
  gemm_body<EPI>(A, lda, Bt + (long)t * bTs, ldb,
                 bias ? bias + (long)t * biasTs : nullptr,
                 accbuf, Cout, ldc, resid, CoutF, gin, K, Nc, row0, col0);
}

// 64x128-tile wrapper: grid (M/64, Nc/128)
template<int EPI>
__global__ __launch_bounds__(256)
void gemm64x128_k(const bf16* __restrict__ A, int lda,
                  const bf16* __restrict__ Bt, int ldb, long bTs,
                  const float* __restrict__ bias, long biasTs,
                  float* __restrict__ accbuf,
                  bf16* __restrict__ Cout, int ldc,
                  const float* __restrict__ resid,
                  float* __restrict__ CoutF,
                  int K, int Nc)
{
  const int row0 = blockIdx.x * 64;
  const int col0 = blockIdx.y * 128;
  const int t    = row0 >> 13;
  gemm64x128_body<EPI>(A, lda, Bt + (long)t * bTs, ldb,
                       bias ? bias + (long)t * biasTs : nullptr,
                       accbuf, Cout, ldc, resid, CoutF, K, Nc, row0, col0);
}

// z-batched merged-W2 precompute (64-tile): W2'^T = outW_slice(j(b))^T @ w2_b^T
// b==0 (l2a) writes into the [256][1280] merged self+branch0 block (cols 256+).
__global__ __launch_bounds__(256)
void w2m_k(const bf16* __restrict__ outwT, const bf16* __restrict__ w2c,
           bf16* __restrict__ w2mg, bf16* __restrict__ w2m)
{
  const int z = blockIdx.z, b = z / 3, t = z % 3;
  const int j = (b == 0) ? 1 : (b == 1) ? 2 : 3;   // outW concat slice per branch
  bf16* dst;
  int ldc;
  if (b == 0) { dst = w2mg + (long)t * 327680 + 256; ldc = 1280; }
  else        { dst = w2m + (long)((b - 1) * 3 + t) * 262144; ldc = 1024; }
  gemm64_body<EPI_BIAS>(outwT + (long)t * 262144 + j * 256, 1024,
                        w2c + (long)b * 262144, 256,
                        nullptr, nullptr, dst, ldc,
                        nullptr, nullptr, 256, 1024,
                        blockIdx.x * 64, blockIdx.y * 64);
}

// copy outW j=0 slice into merged block cols 0-255
__global__ __launch_bounds__(256)
void selfw_k(const bf16* __restrict__ outwT, bf16* __restrict__ w2mg)
{
  const int i = blockIdx.x * 256 + threadIdx.x;   // 196608 total
  const int t = i >> 16, rem = i & 65535;
  const int col = rem >> 8, k = rem & 255;
  w2mg[(long)t * 327680 + (long)col * 1280 + k] =
      outwT[(long)t * 262144 + (long)col * 1024 + k];
}

// ---------------- weight transpose+cast: src f32 [K,Nc] -> dst bf16 [Nc,K], batched z ----------------
__global__ __launch_bounds__(256)
void transpose_k(const float* __restrict__ src, bf16* __restrict__ dst,
                 int K, int Nc, long sB, long dB)
{
  __shared__ bf16 tile[32][33];
  const int b = blockIdx.z;
  const float* s = src + (long)b * sB;
  bf16* d = dst + (long)b * dB;
  const int kb = blockIdx.y * 32, nb = blockIdx.x * 32;
  const int tx = threadIdx.x & 31, ty = threadIdx.x >> 5;
#pragma unroll
  for (int i = 0; i < 32; i += 8)
    tile[ty + i][tx] = __float2bfloat16(s[(long)(kb + ty + i) * Nc + nb + tx]);
  __syncthreads();
#pragma unroll
  for (int i = 0; i < 32; i += 8)
    d[(long)(nb + ty + i) * K + kb + tx] = tile[tx][ty + i];
}

// ---------------- interleaved FFN w1/w3 transpose: dst bf16 [3][2048,256] ----------------
__global__ __launch_bounds__(256)
void transpose13_k(const float* __restrict__ w1, const float* __restrict__ w3,
                   bf16* __restrict__ dst)
{
  __shared__ bf16 tile[32][33];
  const int t  = blockIdx.z;
  const int n0 = blockIdx.x * 32;
  const int k0 = blockIdx.y * 32;
  const int gi = n0 >> 5;
  const int tx = threadIdx.x & 31, ty = threadIdx.x >> 5;
  const float* src = ((tx & 16) ? w3 : w1) + (long)t * 262144;
  const int c = 16 * gi + (tx & 15);
#pragma unroll
  for (int i = 0; i < 32; i += 8)
    tile[ty + i][tx] = __float2bfloat16(src[(long)(k0 + ty + i) * 1024 + c]);
  __syncthreads();
#pragma unroll
  for (int i = 0; i < 32; i += 8)
    dst[((long)t * 2048 + n0 + ty + i) * 256 + k0 + tx] = tile[tx][ty + i];
}

// ---------------- LN-folded w1: dst[b] (bf16 [1024,512]) from w1 f32 [Kin,1024] ----------------
struct FoldP { const float* w1[5]; const float* ls[5]; };
__global__ __launch_bounds__(256)
void fold_w1_k(FoldP p, bf16* __restrict__ dst)
{
  __shared__ float tile[32][33];
  const int z = blockIdx.z;
  const float* w1 = p.w1[z];
  const float* ls = p.ls[z];
  bf16* d = dst + (long)z * 524288;
  const int n0 = blockIdx.x * 32, i0 = blockIdx.y * 32;
  const int tx = threadIdx.x & 31, ty = threadIdx.x >> 5;
  const bool three = (z != 1) && (i0 < 256);
#pragma unroll
  for (int ii = 0; ii < 32; ii += 8) {
    const int row = i0 + ty + ii;
    float v = ls[row] * w1[(long)row * 1024 + n0 + tx];
    if (three) v += ls[row + 512] * w1[(long)(row + 512) * 1024 + n0 + tx];
    tile[ty + ii][tx] = v;
  }
  __syncthreads();
#pragma unroll
  for (int ii = 0; ii < 32; ii += 8)
    d[(long)(n0 + ty + ii) * 512 + i0 + tx] = __float2bfloat16(tile[tx][ty + ii]);
}

// ---------------- bias-fold precompute (parallelized) ----------------
struct BInitP { const float* b1[5]; const float* fb1; const float* fb3; };
__global__ __launch_bounds__(256)
void binit_k(BInitP p, float* __restrict__ B1F,
             const float* __restrict__ out_b, float* __restrict__ TB,
             float* __restrict__ B13)
{
  const int i = blockIdx.x * 256 + threadIdx.x;
  if (i < 5120) {
    B1F[i] = p.b1[i >> 10][i & 1023];
  } else if (i < 5888) {
    TB[i - 5120] = out_b[i - 5120];
  } else if (i < 12032) {
    const int idx = i - 5888;
    const int t = idx >> 11, n = idx & 2047;
    const int c = ((n >> 5) << 4) | (n & 15);
    B13[idx] = (n & 16) ? p.fb3[t * 1024 + c] : p.fb1[t * 1024 + c];
  }
}

// B1F[z][n] += sum_k lb[k]*w1[k,n]; grid (z=5, ksplit=32)
struct B1P { const float* w1[5]; const float* lb[5]; int kin[5]; };
__global__ __launch_bounds__(256)
void b1f_add_k(B1P p, float* __restrict__ dst)
{
  const int z   = blockIdx.x;
  const int kin = p.kin[z];
  const int kpb = (kin + 31) >> 5;
  const int k0  = blockIdx.y * kpb;
  const int k1  = min(k0 + kpb, kin);
  const float* w1 = p.w1[z];
  const float* lb = p.lb[z];
  const int n = threadIdx.x;
  float a0 = 0.f, a1 = 0.f, a2 = 0.f, a3 = 0.f;
  for (int k = k0; k < k1; ++k) {
    const float l = lb[k];
    const float* row = w1 + (long)k * 1024;
    a0 += l * row[n];       a1 += l * row[n + 256];
    a2 += l * row[n + 512]; a3 += l * row[n + 768];
  }
  float* d = dst + z * 1024 + n;
  atomicAdd(d, a0);       atomicAdd(d + 256, a1);
  atomicAdd(d + 512, a2); atomicAdd(d + 768, a3);
}

// TB[t][h] += b2-vectors through outW slices; grid (t=3, csplit=8)
__global__ __launch_bounds__(256)
void tbias_add_k(const float* __restrict__ outW,
                 const float* __restrict__ l2a_b2, const float* __restrict__ g2a_b2,
                 const float* __restrict__ oth_b2, float* __restrict__ dst)
{
  const int t = blockIdx.x, h = threadIdx.x;
  const float* W = outW + (long)t * 262144;
  const int c0 = blockIdx.y * 32;
  float acc = 0.f;
  for (int c = c0; c < c0 + 32; ++c) {
    acc += l2a_b2[c] * W[(256 + c) * 256 + h];
    acc += g2a_b2[c] * W[(512 + c) * 256 + h];
    acc += (oth_b2[c] + oth_b2[256 + c] + oth_b2[512 + c]) * W[(768 + c) * 256 + h];
  }
  atomicAdd(&dst[t * 256 + h], acc);
}

// ---------------- f32 -> bf16 cast, 4 elems/thread ----------------
__global__ __launch_bounds__(256)
void cast_k(const float* __restrict__ src, bf16* __restrict__ dst)
{
  const long i = (long)blockIdx.x * 256 + threadIdx.x;
  const float4 v = ((const float4*)src)[i];
  ((bf4*)dst)[i] = mk4(v.x, v.y, v.z, v.w);
}

// ---------------- wave-wide reduce (all lanes get totals) ----------------
__device__ __forceinline__ void wave_reduce2(float& s, float& q) {
#pragma unroll
  for (int off = 32; off > 0; off >>= 1) {
    s += __shfl_xor(s, off, 64);
    q += __shfl_xor(q, off, 64);
  }
}

// ---------------- normalized-only LN: writes [fn, xn] (512 bf16) ----------------
template<int THREE>
__global__ __launch_bounds__(256)
void ln_norm_k(const float* __restrict__ feat, const float* __restrict__ x,
               const int* __restrict__ srcIdx, bf16* __restrict__ out)
{
  const int w = threadIdx.x >> 6, lane = threadIdx.x & 63;
  const int r = blockIdx.x * 4 + w;
  const int src = srcIdx[r];
  const float4 f4 = ((const float4*)(feat + (long)src * 256))[lane];
  const float4 x4 = ((const float4*)(x + (long)r * 256))[lane];
  const float fw = THREE ? 2.f : 1.f;
  float s = fw * (f4.x + f4.y + f4.z + f4.w) + (x4.x + x4.y + x4.z + x4.w);
  float q = fw * (f4.x * f4.x + f4.y * f4.y + f4.z * f4.z + f4.w * f4.w) +
            (x4.x * x4.x + x4.y * x4.y + x4.z * x4.z + x4.w * x4.w);
  wave_reduce2(s, q);
  const float rD  = THREE ? (1.f / 768.f) : (1.f / 512.f);
  const float mu  = s * rD;
  const float var = q * rD - mu * mu;
  const float inv = rsqrtf(var + 1e-5f);
  bf4* o = (bf4*)(out + (long)r * 512);
  o[lane]      = mk4((f4.x - mu) * inv, (f4.y - mu) * inv,
                     (f4.z - mu) * inv, (f4.w - mu) * inv);
  o[64 + lane] = mk4((x4.x - mu) * inv, (x4.y - mu) * inv,
                     (x4.z - mu) * inv, (x4.w - mu) * inv);
}

// ---------------- legacy LN kernels (Tier C path) ----------------
__global__ __launch_bounds__(256)
void ln_cat3_k(const float* __restrict__ feat, const float* __restrict__ x,
               const int* __restrict__ srcIdx,
               const float* __restrict__ ls, const float* __restrict__ lb,
               bf16* __restrict__ out)
{
  const int w = threadIdx.x >> 6, lane = threadIdx.x & 63;
  const int r = blockIdx.x * 4 + w;
  const int src = srcIdx[r];
  const float4 f4 = ((const float4*)(feat + (long)src * 256))[lane];
  const float4 x4 = ((const float4*)(x + (long)r * 256))[lane];
  float s = 2.f * (f4.x + f4.y + f4.z + f4.w) + (x4.x + x4.y + x4.z + x4.w);
  float q = 2.f * (f4.x * f4.x + f4.y * f4.y + f4.z * f4.z + f4.w * f4.w) +
            (x4.x * x4.x + x4.y * x4.y + x4.z * x4.z + x4.w * x4.w);
  wave_reduce2(s, q);
  const float mu  = s * (1.f / 768.f);
  const float var = q * (1.f / 768.f) - mu * mu;
  const float inv = rsqrtf(var + 1e-5f);
  const float4 s0 = ((const float4*)ls)[lane],         b0 = ((const float4*)lb)[lane];
  const float4 s1 = ((const float4*)(ls + 256))[lane], b1 = ((const float4*)(lb + 256))[lane];
  const float4 s2 = ((const float4*)(ls + 512))[lane], b2 = ((const float4*)(lb + 512))[lane];
  bf4* o = (bf4*)(out + (long)r * 768);
  o[lane] = mk4((f4.x - mu) * inv * s0.x + b0.x, (f4.y - mu) * inv * s0.y + b0.y,
                (f4.z - mu) * inv * s0.z + b0.z, (f4.w - mu) * inv * s0.w + b0.w);
  o[64 + lane] = mk4((x4.x - mu) * inv * s1.x + b1.x, (x4.y - mu) * inv * s1.y + b1.y,
                     (x4.z - mu) * inv * s1.z + b1.z, (x4.w - mu) * inv * s1.w + b1.w);
  o[128 + lane] = mk4((f4.x - mu) * inv * s2.x + b2.x, (f4.y - mu) * inv * s2.y + b2.y,
                      (f4.z - mu) * inv * s2.z + b2.z, (f4.w - mu) * inv * s2.w + b2.w);
}

__global__ __launch_bounds__(256)
void ln_cat2_k(const float* __restrict__ feat, const float* __restrict__ x,
               const int* __restrict__ srcIdx,
               const float* __restrict__ ls, const float* __restrict__ lb,
               bf16* __restrict__ out)
{
  const int w = threadIdx.x >> 6, lane = threadIdx.x & 63;
  const int r = blockIdx.x * 4 + w;
  const int src = srcIdx[r];
  const float4 f4 = ((const float4*)(feat + (long)src * 256))[lane];
  const float4 x4 = ((const float4*)(x + (long)r * 256))[lane];
  float s = (f4.x + f4.y + f4.z + f4.w) + (x4.x + x4.y + x4.z + x4.w);
  float q = (f4.x * f4.x + f4.y * f4.y + f4.z * f4.z + f4.w * f4.w) +
            (x4.x * x4.x + x4.y * x4.y + x4.z * x4.z + x4.w * x4.w);
  wave_reduce2(s, q);
  const float mu  = s * (1.f / 512.f);
  const float var = q * (1.f / 512.f) - mu * mu;
  const float inv = rsqrtf(var + 1e-5f);
  const float4 s0 = ((const float4*)ls)[lane],         b0 = ((const float4*)lb)[lane];
  const float4 s1 = ((const float4*)(ls + 256))[lane], b1 = ((const float4*)(lb + 256))[lane];
  bf4* o = (bf4*)(out + (long)r * 512);
  o[lane] = mk4((f4.x - mu) * inv * s0.x + b0.x, (f4.y - mu) * inv * s0.y + b0.y,
                (f4.z - mu) * inv * s0.z + b0.z, (f4.w - mu) * inv * s0.w + b0.w);
  o[64 + lane] = mk4((x4.x - mu) * inv * s1.x + b1.x, (x4.y - mu) * inv * s1.y + b1.y,
                     (x4.z - mu) * inv * s1.z + b1.z, (x4.w - mu) * inv * s1.w + b1.w);
}

// ---------------- FFN layernorm width 256: f32 in, bf16 out; one wave per row ----------------
__global__ __launch_bounds__(256)
void ln_ffn_k(const float* __restrict__ ob, const float* __restrict__ ls,
              const float* __restrict__ lb, bf16* __restrict__ y,
              long lsStride, int ldy)
{
  const int w = threadIdx.x >> 6, lane = threadIdx.x & 63;
  const int r = blockIdx.x * 4 + w;
  const long po = (long)(r >> 13) * lsStride;
  const float4 v4 = ((const float4*)(ob + (long)r * 256))[lane];
  float s = v4.x + v4.y + v4.z + v4.w;
  float q = v4.x * v4.x + v4.y * v4.y + v4.z * v4.z + v4.w * v4.w;
  wave_reduce2(s, q);
  const float mu  = s * (1.f / 256.f);
  const float var = q * (1.f / 256.f) - mu * mu;
  const float inv = rsqrtf(var + 1e-5f);
  const float4 s0 = ((const float4*)(ls + po))[lane];
  const float4 b0 = ((const float4*)(lb + po))[lane];
  ((bf4*)(y + (long)r * ldy))[lane] =
      mk4((v4.x - mu) * inv * s0.x + b0.x, (v4.y - mu) * inv * s0.y + b0.y,
          (v4.z - mu) * inv * s0.z + b0.z, (v4.w - mu) * inv * s0.w + b0.w);
}

// ---------------- g = silu(g) * u, 4 elems/thread (Tier C path) ----------------
__global__ __launch_bounds__(256)
void silu_mul_k(bf16* __restrict__ g, const bf16* __restrict__ u)
{
  const long i = (long)blockIdx.x * 256 + threadIdx.x;
  const bf4 g4 = ((const bf4*)g)[i];
  const bf4 u4 = ((const bf4*)u)[i];
  float a = __bfloat162float(g4.x), b = __bfloat162float(g4.y);
  float c = __bfloat162float(g4.z), d = __bfloat162float(g4.w);
  a = a / (1.f + expf(-a)) * __bfloat162float(u4.x);
  b = b / (1.f + expf(-b)) * __bfloat162float(u4.y);
  c = c / (1.f + expf(-c)) * __bfloat162float(u4.z);
  d = d / (1.f + expf(-d)) * __bfloat162float(u4.w);
  ((bf4*)g)[i] = mk4(a, b, c, d);
}

// ---------------- sentinel fill (diagnostic) ----------------
__global__ __launch_bounds__(256)
void fill_k(float* __restrict__ p, int n)
{
  const int i = blockIdx.x * 256 + threadIdx.x;
  if (i < n) p[i] = 2.0f;
}

// ---------------- host ----------------
extern "C" void kernel_launch(void* const* d_in, const int* in_sizes, int n_in,
                              void* d_out, int out_size, void* d_ws, size_t ws_size,
                              hipStream_t stream)
{
  const float* agent_x  = (const float*)d_in[0];
  const float* lane_x   = (const float*)d_in[1];
  const float* poly_x   = (const float*)d_in[2];
  const int*   l2a_src  = (const int*)d_in[3];
  const int*   g2a_src  = (const int*)d_in[4];
  const int*   other_src= (const int*)d_in[5];
  const float* self_W   = (const float*)d_in[6];
  const float* self_b   = (const float*)d_in[7];
  const float* out_W    = (const float*)d_in[8];
  const float* out_b    = (const float*)d_in[9];
  const float* ffn_ln_s = (const float*)d_in[10];
  const float* ffn_ln_b = (const float*)d_in[11];
  const float* ffn_w1   = (const float*)d_in[12];
  const float* ffn_b1   = (const float*)d_in[13];
  const float* ffn_w2   = (const float*)d_in[14];
  const float* ffn_b2   = (const float*)d_in[15];
  const float* ffn_w3   = (const float*)d_in[16];
  const float* ffn_b3   = (const float*)d_in[17];
  const float* l2a_ln_s = (const float*)d_in[18];
  const float* l2a_ln_b = (const float*)d_in[19];
  const float* l2a_w1   = (const float*)d_in[20];
  const float* l2a_b1   = (const float*)d_in[21];
  const float* l2a_w2   = (const float*)d_in[22];
  const float* l2a_b2   = (const float*)d_in[23];
  const float* g2a_ln_s = (const float*)d_in[24];
  const float* g2a_ln_b = (const float*)d_in[25];
  const float* g2a_w1   = (const float*)d_in[26];
  const float* g2a_b1   = (const float*)d_in[27];
  const float* g2a_w2   = (const float*)d_in[28];
  const float* g2a_b2   = (const float*)d_in[29];
  const float* oth_ln_s = (const float*)d_in[30];
  const float* oth_ln_b = (const float*)d_in[31];
  const float* oth_w1   = (const float*)d_in[32];
  const float* oth_b1   = (const float*)d_in[33];
  const float* oth_w2   = (const float*)d_in[34];
  const float* oth_b2   = (const float*)d_in[35];

  float* outp = (float*)d_out;
  const dim3 B256(256);

  const size_t TIER_A = 136108032;  // merged-M layout (fits proven 155 MB grant)
  const size_t TIER_C = 12058624;   // chunked fallback

  if (ws_size >= TIER_A) {
    // ===== Tier A: merged-M + proven 128-tile (reverted) + 64x128 ACC tiles =====
    char* base = (char*)d_ws;
    bf16* wT = (bf16*)base;
    const long SELF_WT = 0,       OUT_WT  = 196608,  FFN_W13T = 983040;
    const long FFN_W2T = 2555904, W2C = 3342336,     W1F      = 4653056;
    const long W2MG = 7274496;    // [3][256][1280] merged self+branch0 Bt
    const long W2M  = 8257536;    // [4][3][256][1024] branches 1-4
    float* B1F  = (float*)(base + 22806528L);   // [5][1024] folded w1 bias
    float* TB   = (float*)(base + 22827008L);   // [3][256]  fused out-bias
    float* B13  = (float*)(base + 22830080L);   // [3][2048] interleaved ffn bias
    bf16*  nbuf = (bf16*)(base + 22854656L);    // [N,512]  LN output / xbf scratch
    bf16*  M    = (bf16*)(base + 48020480L);    // [N,1280]: cols 0-255 self/y, 256-1279 h1/g*u
    float* oF   = (float*)(base + 110935040L);  // [N,256]  branch accumulator
    bf16*  xbf  = nbuf;  // bf16 cast of agent_x (nbuf dead until first ln_norm)

    // ---- weight precompute ----
    auto TRB = [&](const float* s, long dOff, int K, int Nc, long sB, long dB, int b) {
      transpose_k<<<dim3(Nc / 32, K / 32, b), B256, 0, stream>>>(s, wT + dOff, K, Nc, sB, dB);
    };
    TRB(self_W, SELF_WT, 256, 256,  65536, 65536, 3);
    TRB(out_W,  OUT_WT,  1024, 256, 262144, 262144, 3);
    TRB(ffn_w2, FFN_W2T, 1024, 256, 262144, 262144, 3);
    transpose13_k<<<dim3(64, 8, 3), B256, 0, stream>>>(ffn_w1, ffn_w3, wT + FFN_W13T);
    cast_k<<<256, B256, 0, stream>>>(l2a_w2, wT + W2C);
    cast_k<<<256, B256, 0, stream>>>(g2a_w2, wT + W2C + 262144);
    cast_k<<<768, B256, 0, stream>>>(oth_w2, wT + W2C + 524288);

    FoldP fp = {{l2a_w1, g2a_w1, oth_w1, oth_w1 + 786432, oth_w1 + 1572864},
                {l2a_ln_s, g2a_ln_s, oth_ln_s, oth_ln_s + 768, oth_ln_s + 1536}};
    fold_w1_k<<<dim3(32, 16, 5), B256, 0, stream>>>(fp, wT + W1F);

    BInitP ip = {{l2a_b1, g2a_b1, oth_b1, oth_b1 + 1024, oth_b1 + 2048}, ffn_b1, ffn_b3};
    binit_k<<<47, B256, 0, stream>>>(ip, B1F, out_b, TB, B13);
    B1P bp = {{l2a_w1, g2a_w1, oth_w1, oth_w1 + 786432, oth_w1 + 1572864},
              {l2a_ln_b, g2a_ln_b, oth_ln_b, oth_ln_b + 768, oth_ln_b + 1536},
              {768, 512, 768, 768, 768}};
    b1f_add_k<<<dim3(5, 32), B256, 0, stream>>>(bp, B1F);
    tbias_add_k<<<dim3(3, 8), B256, 0, stream>>>(out_W, l2a_b2, g2a_b2, oth_b2, TB);
    selfw_k<<<768, B256, 0, stream>>>(wT + OUT_WT, wT + W2MG);
    w2m_k<<<dim3(4, 16, 15), B256, 0, stream>>>(wT + OUT_WT, wT + W2C,
                                                wT + W2MG, wT + W2M);

    const dim3 Gacc(N_AG / 64, 2);      // N=256 GEMMs (64x128-tile): 768 blocks
    const dim3 Gw1(N_AG / 128, 8);      // w1' (128-tile): 1536 blocks
    const dim3 Gglu(N_AG / 128, 16);    // GLU (128-tile): 3072 blocks

    // ---- self branch: relu output into M cols 0-255 (ldc 1280) ----
    cast_k<<<N_AG / 4, B256, 0, stream>>>(agent_x, xbf);
    gemm64x128_k<EPI_RELU_BIAS><<<Gacc, B256, 0, stream>>>(
        xbf, 256, wT + SELF_WT, 256, 65536, self_b, 256,
        nullptr, M, 1280, nullptr, nullptr, 256, 256);

    // ---- edge branches: LN -> w1' (128-tile, writes M cols 256+) -> ACC ----
    for (int b = 0; b < 5; ++b) {
      const int* src = (b == 0) ? l2a_src : (b == 1) ? g2a_src
                                          : other_src + (long)(b - 2) * N_AG;
      const float* feat = (b == 0) ? lane_x : (b == 1) ? poly_x : agent_x;
      if (b == 1) ln_norm_k<0><<<N_AG / 4, B256, 0, stream>>>(feat, agent_x, src, nbuf);
      else        ln_norm_k<1><<<N_AG / 4, B256, 0, stream>>>(feat, agent_x, src, nbuf);
      gemm_k<EPI_RELU_BIAS><<<Gw1, B256, 0, stream>>>(
          nbuf, 512, wT + W1F + (long)b * 524288, 512, 0, B1F + b * 1024, 0,
          nullptr, M + 256, 1280, nullptr, nullptr, nullptr, 512, 1024);
      if (b == 0) {
        // merged self+branch0 accumulation, K=1280 (TB carries all folded biases)
        gemm64x128_k<EPI_ACC_INIT><<<Gacc, B256, 0, stream>>>(
            M, 1280, wT + W2MG, 1280, 327680, TB, 256,
            oF, nullptr, 0, nullptr, nullptr, 1280, 256);
      } else {
        gemm64x128_k<EPI_ACC_ADD><<<Gacc, B256, 0, stream>>>(
            M + 256, 1280, wT + W2M + (long)(b - 1) * 786432, 1024, 262144,
            nullptr, 0, oF, nullptr, 0, nullptr, nullptr, 1024, 256);
      }
    }

    // ---- FFN: y into M cols 0-255; GLU writes g*u into cols 256-1279; FINAL ----
    ln_ffn_k<<<N_AG / 4, B256, 0, stream>>>(oF, ffn_ln_s, ffn_ln_b, M, 256, 1280);
    gemm_k<EPI_GLU><<<Gglu, B256, 0, stream>>>(
        M, 1280, wT + FFN_W13T, 256, 524288, B13, 2048,
        nullptr, M + 256, 1280, nullptr, nullptr, nullptr, 256, 2048);
    gemm64x128_k<EPI_FINAL><<<Gacc, B256, 0, stream>>>(
        M + 256, 1280, wT + FFN_W2T, 1024, 262144, ffn_b2, 256,
        oF, nullptr, 0, agent_x, outp, 1024, 256);
    return;
  }

  if (ws_size < TIER_C) {
    fill_k<<<(out_size + 255) / 256, B256, 0, stream>>>(outp, out_size);
    return;
  }

  // ================= Tier C: chunked path (11.5 MiB) =================
  const int CH = 2048;
  char* base = (char*)d_ws;
  bf16*  wt     = (bf16*)base;
  bf16*  nbuf   = (bf16*)(base + 1572864L);
  bf16*  bbuf   = (bf16*)(base + 4718592L);
  bf16*  h1     = (bf16*)(base + 5767168L);
  float* outF32 = (float*)(base + 9961472L);
  bf16*  ybuf   = (bf16*)(base + 524288L);
  bf16*  xbf    = h1;
  bf16*  g_pre  = h1;
  bf16*  u_pre  = nbuf;

  const dim3 Gw1(CH / 128, 8), Gw2(CH / 128, 2);
  auto TR = [&](const float* s, int K, int Nc) {
    transpose_k<<<dim3(Nc / 32, K / 32), B256, 0, stream>>>(s, wt, K, Nc, 0, 0);
  };

  for (int t = 0; t < 3; ++t) {
    for (int c = 0; c < N3 / CH; ++c) {
      const long r0 = (long)t * N3 + (long)c * CH;
      const float* xC   = agent_x + r0 * 256;
      float*       outC = outp + r0 * 256;

      cast_k<<<CH / 4, B256, 0, stream>>>(xC, xbf);
      TR(self_W + (long)t * 65536, 256, 256);
      gemm_k<EPI_RELU_BIAS><<<Gw2, B256, 0, stream>>>(
          xbf, 256, wt, 256, 0, self_b + t * 256, 0, nullptr, bbuf, 256,
          nullptr, nullptr, nullptr, 256, 256);
      TR(out_W + (long)t * 262144 + 0 * 65536, 256, 256);
      gemm_k<EPI_ACC_INIT><<<Gw2, B256, 0, stream>>>(
          bbuf, 256, wt, 256, 0, out_b + t * 256, 0, outF32, nullptr, 0,
          nullptr, nullptr, nullptr, 256, 256);

      ln_cat3_k<<<CH / 4, B256, 0, stream>>>(lane_x, xC, l2a_src + r0,
                                             l2a_ln_s, l2a_ln_b, nbuf);
      TR(l2a_w1, 768, 1024);
      gemm_k<EPI_RELU_BIAS><<<Gw1, B256, 0, stream>>>(
          nbuf, 768, wt, 768, 0, l2a_b1, 0, nullptr, h1, 1024,
          nullptr, nullptr, nullptr, 768, 1024);
      TR(l2a_w2, 1024, 256);
      gemm_k<EPI_BIAS><<<Gw2, B256, 0, stream>>>(
          h1, 1024, wt, 1024, 0, l2a_b2, 0, nullptr, bbuf, 256,
          nullptr, nullptr, nullptr, 1024, 256);
      TR(out_W + (long)t * 262144 + 1 * 65536, 256, 256);
      gemm_k<EPI_ACC_ADD><<<Gw2, B256, 0, stream>>>(
          bbuf, 256, wt, 256, 0, nullptr, 0, outF32, nullptr, 0,
          nullptr, nullptr, nullptr, 256, 256);

      ln_cat2_k<<<CH / 4, B256, 0, stream>>>(poly_x, xC, g2a_src + r0,
                                             g2a_ln_s, g2a_ln_b, nbuf);
      TR(g2a_w1, 512, 1024);
      gemm_k<EPI_RELU_BIAS><<<Gw1, B256, 0, stream>>>(
          nbuf, 512, wt, 512, 0, g2a_b1, 0, nullptr, h1, 1024,
          nullptr, nullptr, nullptr, 512, 1024);
      TR(g2a_w2, 1024, 256);
      gemm_k<EPI_BIAS><<<Gw2, B256, 0, stream>>>(
          h1, 1024, wt, 1024, 0, g2a_b2, 0, nullptr, bbuf, 256,
          nullptr, nullptr, nullptr, 1024, 256);
      TR(out_W + (long)t * 262144 + 2 * 65536, 256, 256);
      gemm_k<EPI_ACC_ADD><<<Gw2, B256, 0, stream>>>(
          bbuf, 256, wt, 256, 0, nullptr, 0, outF32, nullptr, 0,
          nullptr, nullptr, nullptr, 256, 256);

      for (int s = 0; s < 3; ++s) {
        ln_cat3_k<<<CH / 4, B256, 0, stream>>>(
            agent_x, xC, other_src + (long)s * N_AG + r0,
            oth_ln_s + s * 768, oth_ln_b + s * 768, nbuf);
        TR(oth_w1 + (long)s * 786432, 768, 1024);
        gemm_k<EPI_RELU_BIAS><<<Gw1, B256, 0, stream>>>(
            nbuf, 768, wt, 768, 0, oth_b1 + s * 1024, 0, nullptr, h1, 1024,
            nullptr, nullptr, nullptr, 768, 1024);
        TR(oth_w2 + (long)s * 262144, 1024, 256);
        gemm_k<EPI_BIAS><<<Gw2, B256, 0, stream>>>(
            h1, 1024, wt, 1024, 0, oth_b2 + s * 256, 0, nullptr, bbuf, 256,
            nullptr, nullptr, nullptr, 1024, 256);
        TR(out_W + (long)t * 262144 + 3 * 65536, 256, 256);
        gemm_k<EPI_ACC_ADD><<<Gw2, B256, 0, stream>>>(
            bbuf, 256, wt, 256, 0, nullptr, 0, outF32, nullptr, 0,
            nullptr, nullptr, nullptr, 256, 256);
      }

      ln_ffn_k<<<CH / 4, B256, 0, stream>>>(outF32, ffn_ln_s + t * 256,
                                            ffn_ln_b + t * 256, ybuf, 0, 256);
      TR(ffn_w1 + (long)t * 262144, 256, 1024);
      gemm_k<EPI_BIAS><<<Gw1, B256, 0, stream>>>(
          ybuf, 256, wt, 256, 0, ffn_b1 + t * 1024, 0, nullptr, g_pre, 1024,
          nullptr, nullptr, nullptr, 256, 1024);
      TR(ffn_w3 + (long)t * 262144, 256, 1024);
      gemm_k<EPI_BIAS><<<Gw1, B256, 0, stream>>>(
          ybuf, 256, wt, 256, 0, ffn_b3 + t * 1024, 0, nullptr, u_pre, 1024,
          nullptr, nullptr, nullptr, 256, 1024);
      silu_mul_k<<<CH, B256, 0, stream>>>(g_pre, u_pre);
      TR(ffn_w2 + (long)t * 262144, 1024, 256);
      gemm_k<EPI_FINAL><<<Gw2, B256, 0, stream>>>(
          g_pre, 1024, wt, 1024, 0, ffn_b2 + t * 256, 0, outF32, nullptr, 256,
          xC, outC, nullptr, 1024, 256);
    }
  }
}